// Round 1
// baseline (3094.034 us; speedup 1.0000x reference)
//
#include <hip/hip_runtime.h>
#include <math.h>

#define N1 20000
#define NE 320000
#define CIN 256
#define C1 512
#define C2 256
#define K1 10000
#define K2 5000
#define NOUT 128
#define EPSV 1e-5f

static inline unsigned cdiv(unsigned a, unsigned b) { return (a + b - 1) / b; }

// ---------------- fill ----------------
__global__ void fill_f32(float* __restrict__ p, float v, int n) {
    int i = blockIdx.x * blockDim.x + threadIdx.x;
    if (i < n) p[i] = v;
}

// ---------------- GEMM (f32, tiled) ----------------
// C[M,N] = A[M,K] @ B[K,N].  BM=64,BN=64,BK=16, 256 threads, 4x4 per thread.
template <int BM, int BN, int BK>
__global__ void gemm_f32(const float* __restrict__ A, const float* __restrict__ B,
                         float* __restrict__ C, int M, int K, int Nn) {
    __shared__ float As[BK][BM + 1];
    __shared__ float Bs[BK][BN + 1];
    int tx = threadIdx.x % 16, ty = threadIdx.x / 16;
    int bm = blockIdx.x * BM, bn = blockIdx.y * BN;
    float acc[4][4] = {};
    for (int k0 = 0; k0 < K; k0 += BK) {
        for (int t = threadIdx.x; t < BM * BK; t += 256) {
            int m = t / BK, kk = t % BK;
            int gm = bm + m;
            As[kk][m] = (gm < M) ? A[(size_t)gm * K + k0 + kk] : 0.f;
        }
        for (int t = threadIdx.x; t < BK * BN; t += 256) {
            int kk = t / BN, nn = t % BN;
            Bs[kk][nn] = B[(size_t)(k0 + kk) * Nn + bn + nn];
        }
        __syncthreads();
        for (int kk = 0; kk < BK; ++kk) {
            float a[4], b[4];
#pragma unroll
            for (int i = 0; i < 4; ++i) a[i] = As[kk][ty * 4 + i];
#pragma unroll
            for (int j = 0; j < 4; ++j) b[j] = Bs[kk][tx * 4 + j];
#pragma unroll
            for (int i = 0; i < 4; ++i)
#pragma unroll
                for (int j = 0; j < 4; ++j) acc[i][j] += a[i] * b[j];
        }
        __syncthreads();
    }
    for (int i = 0; i < 4; ++i) {
        int gm = bm + ty * 4 + i;
        if (gm >= M) continue;
#pragma unroll
        for (int j = 0; j < 4; ++j)
            C[(size_t)gm * Nn + bn + tx * 4 + j] = acc[i][j];
    }
}

// ---------------- degree ----------------
__global__ void degree_k(const int* __restrict__ dst, const int* __restrict__ mask, int E,
                         float* __restrict__ deg) {
    int e = blockIdx.x * blockDim.x + threadIdx.x;
    if (e >= E) return;
    if (mask && !mask[e]) return;
    atomicAdd(&deg[dst[e]], 1.0f);
}

// ---------------- self-loop init: out = b + (2/deg)*xW ----------------
__global__ void self_loop_init(const float* __restrict__ xW, const float* __restrict__ deg,
                               const float* __restrict__ b, float* __restrict__ out,
                               int n, int C) {
    size_t total = (size_t)n * C;
    for (size_t i = blockIdx.x * (size_t)blockDim.x + threadIdx.x; i < total;
         i += (size_t)gridDim.x * blockDim.x) {
        int row = (int)(i / C);
        int c = (int)(i & (C - 1));
        out[i] = b[c] + (2.0f / deg[row]) * xW[i];
    }
}

// ---------------- edge aggregation: out[dst] += rsqrt(deg_s)*rsqrt(deg_d)*xW[src] ----------------
__global__ void aggregate(const int* __restrict__ src, const int* __restrict__ dst,
                          const int* __restrict__ mask, int E,
                          const float* __restrict__ deg,
                          const float* __restrict__ xW, float* __restrict__ out, int C) {
    int tpe = C >> 2;                       // threads per edge (float4 each)
    int epb = blockDim.x / tpe;             // edges per block
    int e = blockIdx.x * epb + threadIdx.x / tpe;
    if (e >= E) return;
    if (mask && !mask[e]) return;
    int c4 = (threadIdx.x % tpe) << 2;
    int s = src[e], d = dst[e];
    float coef = rsqrtf(deg[s]) * rsqrtf(deg[d]);
    const float4 v = *reinterpret_cast<const float4*>(&xW[(size_t)s * C + c4]);
    float* o = &out[(size_t)d * C + c4];
    atomicAdd(o + 0, coef * v.x);
    atomicAdd(o + 1, coef * v.y);
    atomicAdd(o + 2, coef * v.z);
    atomicAdd(o + 3, coef * v.w);
}

// ---------------- graph-norm: sum & sumsq ----------------
__global__ void reduce_sum_sq(const float* __restrict__ x, size_t n, float* __restrict__ S) {
    float s = 0.f, q = 0.f;
    for (size_t i = blockIdx.x * (size_t)blockDim.x + threadIdx.x; i < n;
         i += (size_t)gridDim.x * blockDim.x) {
        float v = x[i];
        s += v;
        q += v * v;
    }
    __shared__ float ls[256], lq[256];
    ls[threadIdx.x] = s; lq[threadIdx.x] = q;
    __syncthreads();
    for (int off = 128; off > 0; off >>= 1) {
        if ((int)threadIdx.x < off) {
            ls[threadIdx.x] += ls[threadIdx.x + off];
            lq[threadIdx.x] += lq[threadIdx.x + off];
        }
        __syncthreads();
    }
    if (threadIdx.x == 0) {
        atomicAdd(&S[0], ls[0]);
        atomicAdd(&S[1], lq[0]);
    }
}

// ---------------- apply norm + affine + relu (in place) ----------------
__global__ void norm_relu(float* __restrict__ x, size_t n, const float* __restrict__ S,
                          float inv_cnt, const float* __restrict__ w,
                          const float* __restrict__ b, int C) {
    float mean = S[0] * inv_cnt;
    float var = S[1] * inv_cnt - mean * mean;
    float istd = 1.f / (sqrtf(fmaxf(var, 0.f)) + EPSV);
    for (size_t i = blockIdx.x * (size_t)blockDim.x + threadIdx.x; i < n;
         i += (size_t)gridDim.x * blockDim.x) {
        int c = (int)(i & (C - 1));
        float v = (x[i] - mean) * istd * w[c] + b[c];
        x[i] = fmaxf(v, 0.f);
    }
}

// ---------------- per-node scores: r = h.wrel ; score = h.wroot + brel ----------------
__global__ void node_scores(const float* __restrict__ h, int n, int C,
                            const float* __restrict__ wrel, const float* __restrict__ brel,
                            const float* __restrict__ wroot,
                            float* __restrict__ r, float* __restrict__ score) {
    int node = blockIdx.x * (blockDim.x >> 6) + (threadIdx.x >> 6);
    int lane = threadIdx.x & 63;
    if (node >= n) return;
    float sr = 0.f, st = 0.f;
    for (int c = lane; c < C; c += 64) {
        float v = h[(size_t)node * C + c];
        sr += v * wrel[c];
        st += v * wroot[c];
    }
    for (int off = 32; off > 0; off >>= 1) {
        sr += __shfl_down(sr, off);
        st += __shfl_down(st, off);
    }
    if (lane == 0) {
        r[node] = sr;
        score[node] = st + brel[0];
    }
}

// ---------------- scatter score: score[dst] += r[src] (masked) ----------------
__global__ void scatter_score(const int* __restrict__ src, const int* __restrict__ dst,
                              const int* __restrict__ mask, int E,
                              const float* __restrict__ r, float* __restrict__ score) {
    int e = blockIdx.x * blockDim.x + threadIdx.x;
    if (e >= E) return;
    if (mask && !mask[e]) return;
    atomicAdd(&score[dst[e]], r[src[e]]);
}

// ---------------- top-k: keyify + radix select ----------------
__global__ void keyify(const float* __restrict__ score, unsigned* __restrict__ key, int n) {
    int i = blockIdx.x * blockDim.x + threadIdx.x;
    if (i >= n) return;
    unsigned u = __float_as_uint(score[i]);
    key[i] = (u & 0x80000000u) ? ~u : (u | 0x80000000u);
}

__global__ void init_sel(unsigned* __restrict__ sel, unsigned k, unsigned* __restrict__ hist) {
    if (threadIdx.x == 0) { sel[0] = 0u; sel[1] = k; }
    if (threadIdx.x < 256) hist[threadIdx.x] = 0u;
}

__global__ void radix_hist(const unsigned* __restrict__ key, int n,
                           const unsigned* __restrict__ sel, int pass,
                           unsigned* __restrict__ hist) {
    __shared__ unsigned lh[256];
    if (threadIdx.x < 256) lh[threadIdx.x] = 0u;
    __syncthreads();
    unsigned pref = sel[0];
    unsigned msk = pass ? (0xFFFFFFFFu << (32 - 8 * pass)) : 0u;
    int shift = 24 - 8 * pass;
    for (int i = blockIdx.x * blockDim.x + threadIdx.x; i < n; i += gridDim.x * blockDim.x) {
        unsigned u = key[i];
        if (((u ^ pref) & msk) == 0u) atomicAdd(&lh[(u >> shift) & 255u], 1u);
    }
    __syncthreads();
    if (threadIdx.x < 256 && lh[threadIdx.x]) atomicAdd(&hist[threadIdx.x], lh[threadIdx.x]);
}

__global__ void radix_scan(unsigned* __restrict__ sel, unsigned* __restrict__ hist, int pass) {
    if (threadIdx.x == 0) {
        unsigned rem = sel[1];
        unsigned cum = 0u;
        int b = 0;
        for (int bb = 255; bb >= 0; --bb) {
            unsigned h = hist[bb];
            if (cum + h >= rem) { b = bb; break; }
            cum += h;
        }
        sel[0] |= ((unsigned)b) << (24 - 8 * pass);
        sel[1] = rem - cum;
    }
    __syncthreads();
    if (threadIdx.x < 256) hist[threadIdx.x] = 0u;
}

// ---------------- deterministic select + compact (single block) ----------------
__device__ unsigned block_exscan(unsigned* buf, unsigned v) {
    int t = threadIdx.x;
    buf[t] = v;
    __syncthreads();
    for (int off = 1; off < 1024; off <<= 1) {
        unsigned add = (t >= off) ? buf[t - off] : 0u;
        __syncthreads();
        buf[t] += add;
        __syncthreads();
    }
    return buf[t] - v;  // exclusive
}

__global__ void select_compact(const unsigned* __restrict__ key, int n,
                               const unsigned* __restrict__ sel,
                               int* __restrict__ kept, int* __restrict__ inv) {
    __shared__ unsigned buf[1024];
    __shared__ unsigned sbase[2];  // [0]=eq base, [1]=keep base
    unsigned thr = sel[0], tie = sel[1];
    if (threadIdx.x == 0) { sbase[0] = 0u; sbase[1] = 0u; }
    __syncthreads();
    for (int start = 0; start < n; start += 1024) {
        int i = start + (int)threadIdx.x;
        unsigned g = 0u, eq = 0u;
        if (i < n) {
            unsigned u = key[i];
            g = (u > thr) ? 1u : 0u;
            eq = (u == thr) ? 1u : 0u;
        }
        unsigned eq_base = sbase[0];
        unsigned keep_base = sbase[1];
        unsigned eqx = block_exscan(buf, eq);
        unsigned keep = g | (eq & (((eq_base + eqx) < tie) ? 1u : 0u));
        __syncthreads();
        unsigned kx = block_exscan(buf, keep);
        if (i < n) {
            kept[i] = (int)keep;
            inv[i] = (int)(keep_base + kx);
        }
        __syncthreads();
        if (threadIdx.x == 1023) {
            sbase[0] = eq_base + eqx + eq;
            sbase[1] = keep_base + kx + keep;
        }
        __syncthreads();
    }
}

// ---------------- pool apply: hp[inv[i]] = h[i]*tanh(score[i]) for kept ----------------
__global__ void pool_apply(const float* __restrict__ h, const float* __restrict__ score,
                           const int* __restrict__ kept, const int* __restrict__ inv,
                           int n, int C, float* __restrict__ hp) {
    size_t total = (size_t)n * C;
    for (size_t i = blockIdx.x * (size_t)blockDim.x + threadIdx.x; i < total;
         i += (size_t)gridDim.x * blockDim.x) {
        int row = (int)(i / C);
        if (!kept[row]) continue;
        int c = (int)(i & (C - 1));
        hp[(size_t)inv[row] * C + c] = h[i] * tanhf(score[row]);
    }
}

// ---------------- edge relabel ----------------
__global__ void edge_relabel(const int* __restrict__ src, const int* __restrict__ dst, int E,
                             const int* __restrict__ kept, const int* __restrict__ inv,
                             int* __restrict__ src2, int* __restrict__ dst2,
                             int* __restrict__ mask2) {
    int e = blockIdx.x * blockDim.x + threadIdx.x;
    if (e >= E) return;
    int s = src[e], d = dst[e];
    int m = kept[s] & kept[d];
    mask2[e] = m;
    src2[e] = m ? inv[s] : 0;
    dst2[e] = m ? inv[d] : 0;
}

// ---------------- masked weighted column mean: g[c] = invk * sum_kept tanh(score)*h[i,c] --------
__global__ void masked_colmean(const float* __restrict__ h, const float* __restrict__ score,
                               const int* __restrict__ kept, int n, int C, float invk,
                               float* __restrict__ g) {
    int c = blockIdx.x;
    float s = 0.f;
    for (int i = threadIdx.x; i < n; i += blockDim.x)
        if (kept[i]) s += tanhf(score[i]) * h[(size_t)i * C + c];
    __shared__ float ls[256];
    ls[threadIdx.x] = s;
    __syncthreads();
    for (int off = 128; off > 0; off >>= 1) {
        if ((int)threadIdx.x < off) ls[threadIdx.x] += ls[threadIdx.x + off];
        __syncthreads();
    }
    if (threadIdx.x == 0) g[c] = ls[0] * invk;
}

// ---------------- final: out[j] = bf[j] + sum_c g[c]*Wf[c,j] ----------------
__global__ void final_gemv(const float* __restrict__ g, const float* __restrict__ Wf,
                           const float* __restrict__ bf, float* __restrict__ out) {
    int j = threadIdx.x;  // 128
    float s = bf[j];
    for (int c = 0; c < 256; ++c) s += g[c] * Wf[c * NOUT + j];
    out[j] = s;
}

// =======================================================================================
extern "C" void kernel_launch(void* const* d_in, const int* in_sizes, int n_in,
                              void* d_out, int out_size, void* d_ws, size_t ws_size,
                              hipStream_t stream) {
    const float* x      = (const float*)d_in[0];
    const int*   ei     = (const int*)d_in[1];
    const float* W1     = (const float*)d_in[2];
    const float* b1     = (const float*)d_in[3];
    const float* ln1w   = (const float*)d_in[4];
    const float* ln1b   = (const float*)d_in[5];
    const float* p1wrel = (const float*)d_in[6];
    const float* p1brel = (const float*)d_in[7];
    const float* p1wroot= (const float*)d_in[8];
    const float* W2     = (const float*)d_in[9];
    const float* b2     = (const float*)d_in[10];
    const float* ln2w   = (const float*)d_in[11];
    const float* ln2b   = (const float*)d_in[12];
    const float* p2wrel = (const float*)d_in[13];
    const float* p2brel = (const float*)d_in[14];
    const float* p2wroot= (const float*)d_in[15];
    const float* Wf     = (const float*)d_in[16];
    const float* bf     = (const float*)d_in[17];
    float* out = (float*)d_out;
    char* ws = (char*)d_ws;

    const int* src1 = ei;
    const int* dst1 = ei + NE;

    // ---- workspace layout (bytes) ----
    const size_t oA     = 0;                       // 40,960,000 : xW1 ; later h1p/xW2/h2
    const size_t oH1    = 40960000;                // 40,960,000 : h1
    const size_t oSrc2  = 81920000;                // 1,280,000
    const size_t oDst2  = 83200000;
    const size_t oMask2 = 84480000;
    const size_t oDeg   = 85760000;                // 80,000
    const size_t oR     = 85840000;
    const size_t oScore1= 85920000;
    const size_t oKeyu  = 86000000;
    const size_t oKept  = 86080000;
    const size_t oInv   = 86160000;
    const size_t oScore2= 86240000;                // 40,000
    const size_t oKeyu2 = 86280000;
    const size_t oKept2 = 86320000;
    const size_t oInv2  = 86360000;
    const size_t oS     = 86400000;                // 8
    const size_t oHist  = 86400256;                // 1024
    const size_t oSel   = 86401280;                // 8
    const size_t oG     = 86401536;                // 1024

    float* xW1   = (float*)(ws + oA);
    float* h1p   = (float*)(ws + oA);              // reuse after aggregate1
    float* xW2   = (float*)(ws + oA + 20480000);
    float* h2    = (float*)(ws + oA + 30720000);
    float* h1    = (float*)(ws + oH1);
    int*   src2  = (int*)(ws + oSrc2);
    int*   dst2  = (int*)(ws + oDst2);
    int*   mask2 = (int*)(ws + oMask2);
    float* deg   = (float*)(ws + oDeg);
    float* r     = (float*)(ws + oR);
    float* score1= (float*)(ws + oScore1);
    unsigned* keyu  = (unsigned*)(ws + oKeyu);
    int*   kept  = (int*)(ws + oKept);
    int*   inv   = (int*)(ws + oInv);
    float* score2= (float*)(ws + oScore2);
    unsigned* keyu2 = (unsigned*)(ws + oKeyu2);
    int*   kept2 = (int*)(ws + oKept2);
    int*   inv2  = (int*)(ws + oInv2);
    float* S     = (float*)(ws + oS);
    unsigned* hist = (unsigned*)(ws + oHist);
    unsigned* sel  = (unsigned*)(ws + oSel);
    float* g     = (float*)(ws + oG);

    // ================= Stage 1 =================
    gemm_f32<64, 64, 16><<<dim3(cdiv(N1, 64), C1 / 64), 256, 0, stream>>>(x, W1, xW1, N1, CIN, C1);

    fill_f32<<<cdiv(N1, 256), 256, 0, stream>>>(deg, 2.0f, N1);
    degree_k<<<cdiv(NE, 256), 256, 0, stream>>>(dst1, nullptr, NE, deg);
    self_loop_init<<<4096, 256, 0, stream>>>(xW1, deg, b1, h1, N1, C1);
    aggregate<<<cdiv(NE, 2), 256, 0, stream>>>(src1, dst1, nullptr, NE, deg, xW1, h1, C1);

    fill_f32<<<1, 64, 0, stream>>>(S, 0.f, 2);
    reduce_sum_sq<<<2048, 256, 0, stream>>>(h1, (size_t)N1 * C1, S);
    norm_relu<<<2048, 256, 0, stream>>>(h1, (size_t)N1 * C1, S, 1.f / ((float)N1 * C1), ln1w, ln1b, C1);

    node_scores<<<cdiv(N1, 4), 256, 0, stream>>>(h1, N1, C1, p1wrel, p1brel, p1wroot, r, score1);
    scatter_score<<<cdiv(NE, 256), 256, 0, stream>>>(src1, dst1, nullptr, NE, r, score1);

    keyify<<<cdiv(N1, 256), 256, 0, stream>>>(score1, keyu, N1);
    init_sel<<<1, 256, 0, stream>>>(sel, K1, hist);
    for (int pass = 0; pass < 4; ++pass) {
        radix_hist<<<cdiv(N1, 256), 256, 0, stream>>>(keyu, N1, sel, pass, hist);
        radix_scan<<<1, 256, 0, stream>>>(sel, hist, pass);
    }
    select_compact<<<1, 1024, 0, stream>>>(keyu, N1, sel, kept, inv);

    pool_apply<<<4096, 256, 0, stream>>>(h1, score1, kept, inv, N1, C1, h1p);
    edge_relabel<<<cdiv(NE, 256), 256, 0, stream>>>(src1, dst1, NE, kept, inv, src2, dst2, mask2);

    // ================= Stage 2 =================
    gemm_f32<64, 64, 16><<<dim3(cdiv(K1, 64), C2 / 64), 256, 0, stream>>>(h1p, W2, xW2, K1, C1, C2);

    fill_f32<<<cdiv(K1, 256), 256, 0, stream>>>(deg, 2.0f, K1);
    degree_k<<<cdiv(NE, 256), 256, 0, stream>>>(dst2, mask2, NE, deg);
    self_loop_init<<<2048, 256, 0, stream>>>(xW2, deg, b2, h2, K1, C2);
    aggregate<<<cdiv(NE, 4), 256, 0, stream>>>(src2, dst2, mask2, NE, deg, xW2, h2, C2);

    fill_f32<<<1, 64, 0, stream>>>(S, 0.f, 2);
    reduce_sum_sq<<<2048, 256, 0, stream>>>(h2, (size_t)K1 * C2, S);
    norm_relu<<<2048, 256, 0, stream>>>(h2, (size_t)K1 * C2, S, 1.f / ((float)K1 * C2), ln2w, ln2b, C2);

    node_scores<<<cdiv(K1, 4), 256, 0, stream>>>(h2, K1, C2, p2wrel, p2brel, p2wroot, r, score2);
    scatter_score<<<cdiv(NE, 256), 256, 0, stream>>>(src2, dst2, mask2, NE, r, score2);

    keyify<<<cdiv(K1, 256), 256, 0, stream>>>(score2, keyu2, K1);
    init_sel<<<1, 256, 0, stream>>>(sel, K2, hist);
    for (int pass = 0; pass < 4; ++pass) {
        radix_hist<<<cdiv(K1, 256), 256, 0, stream>>>(keyu2, K1, sel, pass, hist);
        radix_scan<<<1, 256, 0, stream>>>(sel, hist, pass);
    }
    select_compact<<<1, 1024, 0, stream>>>(keyu2, K1, sel, kept2, inv2);

    // ================= readout =================
    masked_colmean<<<C2, 256, 0, stream>>>(h2, score2, kept2, K1, C2, 1.f / (float)K2, g);
    final_gemv<<<1, NOUT, 0, stream>>>(g, Wf, bf, out);
}

// Round 2
// 869.671 us; speedup vs baseline: 3.5577x; 3.5577x over previous
//
#include <hip/hip_runtime.h>
#include <math.h>

#define N1 20000
#define NE 320000
#define CIN 256
#define C1 512
#define C2 256
#define K1 10000
#define K2 5000
#define NOUT 128
#define EPSV 1e-5f

static inline unsigned cdiv(unsigned a, unsigned b) { return (a + b - 1) / b; }

// ---------------- fills ----------------
__global__ void fill_f32(float* __restrict__ p, float v, int n) {
    int i = blockIdx.x * blockDim.x + threadIdx.x;
    if (i < n) p[i] = v;
}
__global__ void fill_i32(int* __restrict__ p, int v, int n) {
    int i = blockIdx.x * blockDim.x + threadIdx.x;
    if (i < n) p[i] = v;
}

// ---------------- GEMM (f32, tiled) ----------------
template <int BM, int BN, int BK>
__global__ void gemm_f32(const float* __restrict__ A, const float* __restrict__ B,
                         float* __restrict__ C, int M, int K, int Nn) {
    __shared__ float As[BK][BM + 1];
    __shared__ float Bs[BK][BN + 1];
    int tx = threadIdx.x % 16, ty = threadIdx.x / 16;
    int bm = blockIdx.x * BM, bn = blockIdx.y * BN;
    float acc[4][4] = {};
    for (int k0 = 0; k0 < K; k0 += BK) {
        for (int t = threadIdx.x; t < BM * BK; t += 256) {
            int m = t / BK, kk = t % BK;
            int gm = bm + m;
            As[kk][m] = (gm < M) ? A[(size_t)gm * K + k0 + kk] : 0.f;
        }
        for (int t = threadIdx.x; t < BK * BN; t += 256) {
            int kk = t / BN, nn = t % BN;
            Bs[kk][nn] = B[(size_t)(k0 + kk) * Nn + bn + nn];
        }
        __syncthreads();
        for (int kk = 0; kk < BK; ++kk) {
            float a[4], b[4];
#pragma unroll
            for (int i = 0; i < 4; ++i) a[i] = As[kk][ty * 4 + i];
#pragma unroll
            for (int j = 0; j < 4; ++j) b[j] = Bs[kk][tx * 4 + j];
#pragma unroll
            for (int i = 0; i < 4; ++i)
#pragma unroll
                for (int j = 0; j < 4; ++j) acc[i][j] += a[i] * b[j];
        }
        __syncthreads();
    }
    for (int i = 0; i < 4; ++i) {
        int gm = bm + ty * 4 + i;
        if (gm >= M) continue;
#pragma unroll
        for (int j = 0; j < 4; ++j)
            C[(size_t)gm * Nn + bn + tx * 4 + j] = acc[i][j];
    }
}

// ---------------- CSR build ----------------
__global__ void count_deg(const int* __restrict__ dst, const int* __restrict__ mask, int E,
                          int* __restrict__ cnt) {
    int e = blockIdx.x * blockDim.x + threadIdx.x;
    if (e >= E) return;
    if (mask && !mask[e]) return;
    atomicAdd(&cnt[dst[e]], 1);
}

// single block 1024: exclusive scan of cnt (stored in cursor) -> rowstart, cursor; deg=cnt+2
__global__ void scan_deg(int n, int* __restrict__ cursor, int* __restrict__ rowstart,
                         float* __restrict__ deg) {
    __shared__ int buf[1024];
    __shared__ int sbase;
    if (threadIdx.x == 0) sbase = 0;
    __syncthreads();
    for (int start = 0; start < n; start += 1024) {
        int i = start + (int)threadIdx.x;
        int base = sbase;
        int v = (i < n) ? cursor[i] : 0;
        buf[threadIdx.x] = v;
        __syncthreads();
        for (int off = 1; off < 1024; off <<= 1) {
            int add = ((int)threadIdx.x >= off) ? buf[threadIdx.x - off] : 0;
            __syncthreads();
            buf[threadIdx.x] += add;
            __syncthreads();
        }
        int incl = buf[threadIdx.x];
        int excl = incl - v;
        int total = buf[1023];
        if (i < n) {
            rowstart[i] = base + excl;
            cursor[i] = base + excl;
            deg[i] = (float)v + 2.0f;
        }
        __syncthreads();
        if (threadIdx.x == 0) sbase = base + total;
        __syncthreads();
    }
    if (threadIdx.x == 0) rowstart[n] = sbase;
}

__global__ void csr_scatter(const int* __restrict__ src, const int* __restrict__ dst,
                            const int* __restrict__ mask, int E,
                            int* __restrict__ cursor, int* __restrict__ csr_src) {
    int e = blockIdx.x * blockDim.x + threadIdx.x;
    if (e >= E) return;
    if (mask && !mask[e]) return;
    int pos = atomicAdd(&cursor[dst[e]], 1);
    csr_src[pos] = src[e];
}

// ---------------- fused GCN aggregation (gather, one wave per node) ----------------
// out[i,:] = b + (2/deg_i)*xW[i,:] + sum_{e in CSR[i]} rsqrt(deg_s)*rsqrt(deg_i)*xW[s,:]
template <int C>
__global__ void aggregate_csr(const int* __restrict__ rowstart, const int* __restrict__ csr_src,
                              const float* __restrict__ deg, const float* __restrict__ xW,
                              const float* __restrict__ b, float* __restrict__ out, int n) {
    int node = blockIdx.x * (blockDim.x >> 6) + ((int)threadIdx.x >> 6);
    if (node >= n) return;
    int lane = threadIdx.x & 63;
    int beg = rowstart[node], end = rowstart[node + 1];
    float dg = deg[node];
    float dinv = rsqrtf(dg);
    constexpr int NV = C / 256;  // float4 chunks per lane
    float4 acc[NV];
#pragma unroll
    for (int v = 0; v < NV; ++v) acc[v] = make_float4(0.f, 0.f, 0.f, 0.f);
    for (int j = beg; j < end; ++j) {
        int s = csr_src[j];
        float coef = rsqrtf(deg[s]) * dinv;
        const float4* row = reinterpret_cast<const float4*>(&xW[(size_t)s * C]);
#pragma unroll
        for (int v = 0; v < NV; ++v) {
            float4 t = row[lane + 64 * v];
            acc[v].x += coef * t.x;
            acc[v].y += coef * t.y;
            acc[v].z += coef * t.z;
            acc[v].w += coef * t.w;
        }
    }
    float self = 2.0f / dg;
    const float4* srow = reinterpret_cast<const float4*>(&xW[(size_t)node * C]);
    const float4* brow = reinterpret_cast<const float4*>(b);
    float4* orow = reinterpret_cast<float4*>(&out[(size_t)node * C]);
#pragma unroll
    for (int v = 0; v < NV; ++v) {
        float4 t = srow[lane + 64 * v];
        float4 bb = brow[lane + 64 * v];
        float4 o;
        o.x = acc[v].x + self * t.x + bb.x;
        o.y = acc[v].y + self * t.y + bb.y;
        o.z = acc[v].z + self * t.z + bb.z;
        o.w = acc[v].w + self * t.w + bb.w;
        orow[lane + 64 * v] = o;
    }
}

// ---------------- graph-norm: sum & sumsq ----------------
__global__ void reduce_sum_sq(const float* __restrict__ x, size_t n, float* __restrict__ S) {
    float s = 0.f, q = 0.f;
    for (size_t i = blockIdx.x * (size_t)blockDim.x + threadIdx.x; i < n;
         i += (size_t)gridDim.x * blockDim.x) {
        float v = x[i];
        s += v;
        q += v * v;
    }
    __shared__ float ls[256], lq[256];
    ls[threadIdx.x] = s; lq[threadIdx.x] = q;
    __syncthreads();
    for (int off = 128; off > 0; off >>= 1) {
        if ((int)threadIdx.x < off) {
            ls[threadIdx.x] += ls[threadIdx.x + off];
            lq[threadIdx.x] += lq[threadIdx.x + off];
        }
        __syncthreads();
    }
    if (threadIdx.x == 0) {
        atomicAdd(&S[0], ls[0]);
        atomicAdd(&S[1], lq[0]);
    }
}

// ---------------- apply norm + affine + relu (in place) ----------------
__global__ void norm_relu(float* __restrict__ x, size_t n, const float* __restrict__ S,
                          float inv_cnt, const float* __restrict__ w,
                          const float* __restrict__ b, int C) {
    float mean = S[0] * inv_cnt;
    float var = S[1] * inv_cnt - mean * mean;
    float istd = 1.f / (sqrtf(fmaxf(var, 0.f)) + EPSV);
    for (size_t i = blockIdx.x * (size_t)blockDim.x + threadIdx.x; i < n;
         i += (size_t)gridDim.x * blockDim.x) {
        int c = (int)(i & (C - 1));
        float v = (x[i] - mean) * istd * w[c] + b[c];
        x[i] = fmaxf(v, 0.f);
    }
}

// ---------------- per-node scores: r = h.wrel ; score = h.wroot + brel ----------------
__global__ void node_scores(const float* __restrict__ h, int n, int C,
                            const float* __restrict__ wrel, const float* __restrict__ brel,
                            const float* __restrict__ wroot,
                            float* __restrict__ r, float* __restrict__ score) {
    int node = blockIdx.x * (blockDim.x >> 6) + (threadIdx.x >> 6);
    int lane = threadIdx.x & 63;
    if (node >= n) return;
    float sr = 0.f, st = 0.f;
    for (int c = lane; c < C; c += 64) {
        float v = h[(size_t)node * C + c];
        sr += v * wrel[c];
        st += v * wroot[c];
    }
    for (int off = 32; off > 0; off >>= 1) {
        sr += __shfl_down(sr, off);
        st += __shfl_down(st, off);
    }
    if (lane == 0) {
        r[node] = sr;
        score[node] = st + brel[0];
    }
}

// ---------------- gather score over CSR: score[i] += sum r[src] ----------------
__global__ void gather_score(const int* __restrict__ rowstart, const int* __restrict__ csr_src,
                             const float* __restrict__ r, float* __restrict__ score, int n) {
    int i = blockIdx.x * blockDim.x + threadIdx.x;
    if (i >= n) return;
    float s = 0.f;
    int beg = rowstart[i], end = rowstart[i + 1];
    for (int j = beg; j < end; ++j) s += r[csr_src[j]];
    score[i] += s;
}

// ---------------- top-k: keyify + radix select ----------------
__global__ void keyify(const float* __restrict__ score, unsigned* __restrict__ key, int n) {
    int i = blockIdx.x * blockDim.x + threadIdx.x;
    if (i >= n) return;
    unsigned u = __float_as_uint(score[i]);
    key[i] = (u & 0x80000000u) ? ~u : (u | 0x80000000u);
}

__global__ void init_sel(unsigned* __restrict__ sel, unsigned k, unsigned* __restrict__ hist) {
    if (threadIdx.x == 0) { sel[0] = 0u; sel[1] = k; }
    if (threadIdx.x < 256) hist[threadIdx.x] = 0u;
}

__global__ void radix_hist(const unsigned* __restrict__ key, int n,
                           const unsigned* __restrict__ sel, int pass,
                           unsigned* __restrict__ hist) {
    __shared__ unsigned lh[256];
    if (threadIdx.x < 256) lh[threadIdx.x] = 0u;
    __syncthreads();
    unsigned pref = sel[0];
    unsigned msk = pass ? (0xFFFFFFFFu << (32 - 8 * pass)) : 0u;
    int shift = 24 - 8 * pass;
    for (int i = blockIdx.x * blockDim.x + threadIdx.x; i < n; i += gridDim.x * blockDim.x) {
        unsigned u = key[i];
        if (((u ^ pref) & msk) == 0u) atomicAdd(&lh[(u >> shift) & 255u], 1u);
    }
    __syncthreads();
    if (threadIdx.x < 256 && lh[threadIdx.x]) atomicAdd(&hist[threadIdx.x], lh[threadIdx.x]);
}

__global__ void radix_scan(unsigned* __restrict__ sel, unsigned* __restrict__ hist, int pass) {
    if (threadIdx.x == 0) {
        unsigned rem = sel[1];
        unsigned cum = 0u;
        int b = 0;
        for (int bb = 255; bb >= 0; --bb) {
            unsigned h = hist[bb];
            if (cum + h >= rem) { b = bb; break; }
            cum += h;
        }
        sel[0] |= ((unsigned)b) << (24 - 8 * pass);
        sel[1] = rem - cum;
    }
    __syncthreads();
    if (threadIdx.x < 256) hist[threadIdx.x] = 0u;
}

// ---------------- deterministic select + compact (single block) ----------------
__device__ unsigned block_exscan(unsigned* buf, unsigned v) {
    int t = threadIdx.x;
    buf[t] = v;
    __syncthreads();
    for (int off = 1; off < 1024; off <<= 1) {
        unsigned add = (t >= off) ? buf[t - off] : 0u;
        __syncthreads();
        buf[t] += add;
        __syncthreads();
    }
    return buf[t] - v;  // exclusive
}

__global__ void select_compact(const unsigned* __restrict__ key, int n,
                               const unsigned* __restrict__ sel,
                               int* __restrict__ kept, int* __restrict__ inv) {
    __shared__ unsigned buf[1024];
    __shared__ unsigned sbase[2];
    unsigned thr = sel[0], tie = sel[1];
    if (threadIdx.x == 0) { sbase[0] = 0u; sbase[1] = 0u; }
    __syncthreads();
    for (int start = 0; start < n; start += 1024) {
        int i = start + (int)threadIdx.x;
        unsigned g = 0u, eq = 0u;
        if (i < n) {
            unsigned u = key[i];
            g = (u > thr) ? 1u : 0u;
            eq = (u == thr) ? 1u : 0u;
        }
        unsigned eq_base = sbase[0];
        unsigned keep_base = sbase[1];
        unsigned eqx = block_exscan(buf, eq);
        unsigned keep = g | (eq & (((eq_base + eqx) < tie) ? 1u : 0u));
        __syncthreads();
        unsigned kx = block_exscan(buf, keep);
        if (i < n) {
            kept[i] = (int)keep;
            inv[i] = (int)(keep_base + kx);
        }
        __syncthreads();
        if (threadIdx.x == 1023) {
            sbase[0] = eq_base + eqx + eq;
            sbase[1] = keep_base + kx + keep;
        }
        __syncthreads();
    }
}

// ---------------- pool apply ----------------
__global__ void pool_apply(const float* __restrict__ h, const float* __restrict__ score,
                           const int* __restrict__ kept, const int* __restrict__ inv,
                           int n, int C, float* __restrict__ hp) {
    size_t total = (size_t)n * C;
    for (size_t i = blockIdx.x * (size_t)blockDim.x + threadIdx.x; i < total;
         i += (size_t)gridDim.x * blockDim.x) {
        int row = (int)(i / C);
        if (!kept[row]) continue;
        int c = (int)(i & (C - 1));
        hp[(size_t)inv[row] * C + c] = h[i] * tanhf(score[row]);
    }
}

// ---------------- edge relabel ----------------
__global__ void edge_relabel(const int* __restrict__ src, const int* __restrict__ dst, int E,
                             const int* __restrict__ kept, const int* __restrict__ inv,
                             int* __restrict__ src2, int* __restrict__ dst2,
                             int* __restrict__ mask2) {
    int e = blockIdx.x * blockDim.x + threadIdx.x;
    if (e >= E) return;
    int s = src[e], d = dst[e];
    int m = kept[s] & kept[d];
    mask2[e] = m;
    src2[e] = m ? inv[s] : 0;
    dst2[e] = m ? inv[d] : 0;
}

// ---------------- masked weighted column mean ----------------
__global__ void masked_colmean(const float* __restrict__ h, const float* __restrict__ score,
                               const int* __restrict__ kept, int n, int C, float invk,
                               float* __restrict__ g) {
    int c = blockIdx.x;
    float s = 0.f;
    for (int i = threadIdx.x; i < n; i += blockDim.x)
        if (kept[i]) s += tanhf(score[i]) * h[(size_t)i * C + c];
    __shared__ float ls[256];
    ls[threadIdx.x] = s;
    __syncthreads();
    for (int off = 128; off > 0; off >>= 1) {
        if ((int)threadIdx.x < off) ls[threadIdx.x] += ls[threadIdx.x + off];
        __syncthreads();
    }
    if (threadIdx.x == 0) g[c] = ls[0] * invk;
}

// ---------------- final: out[j] = bf[j] + sum_c g[c]*Wf[c,j] ----------------
__global__ void final_gemv(const float* __restrict__ g, const float* __restrict__ Wf,
                           const float* __restrict__ bf, float* __restrict__ out) {
    int j = threadIdx.x;  // 128
    float s = bf[j];
    for (int c = 0; c < 256; ++c) s += g[c] * Wf[c * NOUT + j];
    out[j] = s;
}

// =======================================================================================
extern "C" void kernel_launch(void* const* d_in, const int* in_sizes, int n_in,
                              void* d_out, int out_size, void* d_ws, size_t ws_size,
                              hipStream_t stream) {
    const float* x      = (const float*)d_in[0];
    const int*   ei     = (const int*)d_in[1];
    const float* W1     = (const float*)d_in[2];
    const float* b1     = (const float*)d_in[3];
    const float* ln1w   = (const float*)d_in[4];
    const float* ln1b   = (const float*)d_in[5];
    const float* p1wrel = (const float*)d_in[6];
    const float* p1brel = (const float*)d_in[7];
    const float* p1wroot= (const float*)d_in[8];
    const float* W2     = (const float*)d_in[9];
    const float* b2     = (const float*)d_in[10];
    const float* ln2w   = (const float*)d_in[11];
    const float* ln2b   = (const float*)d_in[12];
    const float* p2wrel = (const float*)d_in[13];
    const float* p2brel = (const float*)d_in[14];
    const float* p2wroot= (const float*)d_in[15];
    const float* Wf     = (const float*)d_in[16];
    const float* bf     = (const float*)d_in[17];
    float* out = (float*)d_out;
    char* ws = (char*)d_ws;

    const int* src1 = ei;
    const int* dst1 = ei + NE;

    // ---- workspace layout (bytes) ----
    const size_t oA     = 0;                 // 40,960,000 : xW1 ; later h1p/xW2/h2
    const size_t oH1    = 40960000;          // 40,960,000 : h1
    const size_t oSrc2  = 81920000;          // 1,280,000
    const size_t oDst2  = 83200000;          // 1,280,000
    const size_t oMask2 = 84480000;          // 1,280,000
    const size_t oCsr   = 85760000;          // 1,280,000 : csr_src (both stages)
    const size_t oRow   = 87040000;          // 80,064 : rowstart (n+1)
    const size_t oCur   = 87120064;          // 80,000 : cursor / counts
    const size_t oDeg   = 87200064;          // 80,000
    const size_t oR     = 87280064;          // 80,000
    const size_t oScore1= 87360064;
    const size_t oKeyu  = 87440064;
    const size_t oKept  = 87520064;
    const size_t oInv   = 87600064;
    const size_t oScore2= 87680064;          // 40,000
    const size_t oKeyu2 = 87720064;
    const size_t oKept2 = 87760064;
    const size_t oInv2  = 87800064;
    const size_t oS     = 87840064;          // 8
    const size_t oHist  = 87840128;          // 1,024
    const size_t oSel   = 87841152;          // 8
    const size_t oG     = 87841216;          // 1,024

    float* xW1   = (float*)(ws + oA);
    float* h1p   = (float*)(ws + oA);                 // reuse after stage-1 aggregation
    float* xW2   = (float*)(ws + oA + 20480000);
    float* h2    = (float*)(ws + oA + 30720000);
    float* h1    = (float*)(ws + oH1);
    int*   src2  = (int*)(ws + oSrc2);
    int*   dst2  = (int*)(ws + oDst2);
    int*   mask2 = (int*)(ws + oMask2);
    int*   csr   = (int*)(ws + oCsr);
    int*   row   = (int*)(ws + oRow);
    int*   cur   = (int*)(ws + oCur);
    float* deg   = (float*)(ws + oDeg);
    float* r     = (float*)(ws + oR);
    float* score1= (float*)(ws + oScore1);
    unsigned* keyu  = (unsigned*)(ws + oKeyu);
    int*   kept  = (int*)(ws + oKept);
    int*   inv   = (int*)(ws + oInv);
    float* score2= (float*)(ws + oScore2);
    unsigned* keyu2 = (unsigned*)(ws + oKeyu2);
    int*   kept2 = (int*)(ws + oKept2);
    int*   inv2  = (int*)(ws + oInv2);
    float* S     = (float*)(ws + oS);
    unsigned* hist = (unsigned*)(ws + oHist);
    unsigned* sel  = (unsigned*)(ws + oSel);
    float* g     = (float*)(ws + oG);

    // ================= Stage 1 =================
    gemm_f32<64, 64, 16><<<dim3(cdiv(N1, 64), C1 / 64), 256, 0, stream>>>(x, W1, xW1, N1, CIN, C1);

    // CSR build (dst-grouped incoming edges)
    fill_i32<<<cdiv(N1, 256), 256, 0, stream>>>(cur, 0, N1);
    count_deg<<<cdiv(NE, 256), 256, 0, stream>>>(dst1, nullptr, NE, cur);
    scan_deg<<<1, 1024, 0, stream>>>(N1, cur, row, deg);
    csr_scatter<<<cdiv(NE, 256), 256, 0, stream>>>(src1, dst1, nullptr, NE, cur, csr);

    aggregate_csr<C1><<<cdiv(N1, 4), 256, 0, stream>>>(row, csr, deg, xW1, b1, h1, N1);

    fill_f32<<<1, 64, 0, stream>>>(S, 0.f, 2);
    reduce_sum_sq<<<2048, 256, 0, stream>>>(h1, (size_t)N1 * C1, S);
    norm_relu<<<2048, 256, 0, stream>>>(h1, (size_t)N1 * C1, S, 1.f / ((float)N1 * C1), ln1w, ln1b, C1);

    node_scores<<<cdiv(N1, 4), 256, 0, stream>>>(h1, N1, C1, p1wrel, p1brel, p1wroot, r, score1);
    gather_score<<<cdiv(N1, 256), 256, 0, stream>>>(row, csr, r, score1, N1);

    keyify<<<cdiv(N1, 256), 256, 0, stream>>>(score1, keyu, N1);
    init_sel<<<1, 256, 0, stream>>>(sel, K1, hist);
    for (int pass = 0; pass < 4; ++pass) {
        radix_hist<<<cdiv(N1, 256), 256, 0, stream>>>(keyu, N1, sel, pass, hist);
        radix_scan<<<1, 256, 0, stream>>>(sel, hist, pass);
    }
    select_compact<<<1, 1024, 0, stream>>>(keyu, N1, sel, kept, inv);

    pool_apply<<<4096, 256, 0, stream>>>(h1, score1, kept, inv, N1, C1, h1p);
    edge_relabel<<<cdiv(NE, 256), 256, 0, stream>>>(src1, dst1, NE, kept, inv, src2, dst2, mask2);

    // ================= Stage 2 =================
    gemm_f32<64, 64, 16><<<dim3(cdiv(K1, 64), C2 / 64), 256, 0, stream>>>(h1p, W2, xW2, K1, C1, C2);

    fill_i32<<<cdiv(K1, 256), 256, 0, stream>>>(cur, 0, K1);
    count_deg<<<cdiv(NE, 256), 256, 0, stream>>>(dst2, mask2, NE, cur);
    scan_deg<<<1, 1024, 0, stream>>>(K1, cur, row, deg);
    csr_scatter<<<cdiv(NE, 256), 256, 0, stream>>>(src2, dst2, mask2, NE, cur, csr);

    aggregate_csr<C2><<<cdiv(K1, 4), 256, 0, stream>>>(row, csr, deg, xW2, b2, h2, K1);

    fill_f32<<<1, 64, 0, stream>>>(S, 0.f, 2);
    reduce_sum_sq<<<2048, 256, 0, stream>>>(h2, (size_t)K1 * C2, S);
    norm_relu<<<2048, 256, 0, stream>>>(h2, (size_t)K1 * C2, S, 1.f / ((float)K1 * C2), ln2w, ln2b, C2);

    node_scores<<<cdiv(K1, 4), 256, 0, stream>>>(h2, K1, C2, p2wrel, p2brel, p2wroot, r, score2);
    gather_score<<<cdiv(K1, 256), 256, 0, stream>>>(row, csr, r, score2, K1);

    keyify<<<cdiv(K1, 256), 256, 0, stream>>>(score2, keyu2, K1);
    init_sel<<<1, 256, 0, stream>>>(sel, K2, hist);
    for (int pass = 0; pass < 4; ++pass) {
        radix_hist<<<cdiv(K1, 256), 256, 0, stream>>>(keyu2, K1, sel, pass, hist);
        radix_scan<<<1, 256, 0, stream>>>(sel, hist, pass);
    }
    select_compact<<<1, 1024, 0, stream>>>(keyu2, K1, sel, kept2, inv2);

    // ================= readout =================
    masked_colmean<<<C2, 256, 0, stream>>>(h2, score2, kept2, K1, C2, 1.f / (float)K2, g);
    final_gemv<<<1, NOUT, 0, stream>>>(g, Wf, bf, out);
}

// Round 3
// 656.249 us; speedup vs baseline: 4.7147x; 1.3252x over previous
//
#include <hip/hip_runtime.h>
#include <math.h>

#define N1 20000
#define NE 320000
#define CIN 256
#define C1 512
#define C2 256
#define K1 10000
#define K2 5000
#define NOUT 128
#define EPSV 1e-5f

typedef __attribute__((ext_vector_type(8))) short bf16x8;
typedef __attribute__((ext_vector_type(4))) float f32x4;

static inline unsigned cdiv(unsigned a, unsigned b) { return (a + b - 1) / b; }

__device__ inline ushort f2bf(float f) {
    unsigned u = __float_as_uint(f);
    unsigned r = u + 0x7FFFu + ((u >> 16) & 1u);
    return (ushort)(r >> 16);
}

// ---------------- fills ----------------
__global__ void fill_f32(float* __restrict__ p, float v, int n) {
    int i = blockIdx.x * blockDim.x + threadIdx.x;
    if (i < n) p[i] = v;
}
__global__ void fill_i32(int* __restrict__ p, int v, int n) {
    int i = blockIdx.x * blockDim.x + threadIdx.x;
    if (i < n) p[i] = v;
}

// ---------------- weight convert+transpose: Wt[n][k] = bf16(W[k][n]) ----------------
__global__ void conv_transpose_bf16(const float* __restrict__ W, ushort* __restrict__ Wt,
                                    int K, int N) {
    int i = blockIdx.x * blockDim.x + threadIdx.x;
    if (i >= K * N) return;
    int k = i / N, n = i % N;
    Wt[(size_t)n * K + k] = f2bf(W[i]);
}

// ---------------- MFMA bf16 GEMM ----------------
// C[M][N] f32 = A_bf[M][K] @ (Bt_bf[N][K])^T (+bias). BM=BN=128, BK=32.
// 256 threads = 4 waves in 2x2; each wave computes 64x64 via 4x4 frags of 16x16x32.
__global__ __launch_bounds__(256)
void gemm_bf16_mfma(const ushort* __restrict__ A, const ushort* __restrict__ Bt,
                    const float* __restrict__ bias, float* __restrict__ C,
                    int M, int N, int K) {
    constexpr int BM = 128, BN = 128, BK = 32;
    constexpr int LDK = BK + 8;  // padded bf16 stride (80 B, 16B-aligned)
    __shared__ ushort As[BM * LDK];
    __shared__ ushort Bs[BN * LDK];
    int tid = threadIdx.x;
    int wid = tid >> 6, lane = tid & 63;
    int wr = wid >> 1, wc = wid & 1;
    int bm = blockIdx.x * BM, bn = blockIdx.y * BN;
    int lg = lane >> 4, lm = lane & 15;
    f32x4 zero = {0.f, 0.f, 0.f, 0.f};
    f32x4 acc[4][4];
#pragma unroll
    for (int m = 0; m < 4; ++m)
#pragma unroll
        for (int n = 0; n < 4; ++n) acc[m][n] = zero;

    for (int k0 = 0; k0 < K; k0 += BK) {
#pragma unroll
        for (int it = 0; it < 2; ++it) {
            int task = tid * 2 + it;           // 0..511
            int row = task >> 2, c8 = (task & 3) * 8;
            int gm = bm + row;
            bf16x8 v = {0, 0, 0, 0, 0, 0, 0, 0};
            if (gm < M) v = *(const bf16x8*)&A[(size_t)gm * K + k0 + c8];
            *(bf16x8*)&As[row * LDK + c8] = v;
            int gn = bn + row;
            bf16x8 w = {0, 0, 0, 0, 0, 0, 0, 0};
            if (gn < N) w = *(const bf16x8*)&Bt[(size_t)gn * K + k0 + c8];
            *(bf16x8*)&Bs[row * LDK + c8] = w;
        }
        __syncthreads();
        bf16x8 af[4], bfr[4];
#pragma unroll
        for (int m = 0; m < 4; ++m)
            af[m] = *(bf16x8*)&As[(wr * 64 + m * 16 + lm) * LDK + lg * 8];
#pragma unroll
        for (int n = 0; n < 4; ++n)
            bfr[n] = *(bf16x8*)&Bs[(wc * 64 + n * 16 + lm) * LDK + lg * 8];
#pragma unroll
        for (int m = 0; m < 4; ++m)
#pragma unroll
            for (int n = 0; n < 4; ++n)
                acc[m][n] = __builtin_amdgcn_mfma_f32_16x16x32_bf16(af[m], bfr[n], acc[m][n], 0, 0, 0);
        __syncthreads();
    }
#pragma unroll
    for (int m = 0; m < 4; ++m) {
#pragma unroll
        for (int n = 0; n < 4; ++n) {
            int col = bn + wc * 64 + n * 16 + lm;
            float bv = bias ? bias[col] : 0.f;
#pragma unroll
            for (int r = 0; r < 4; ++r) {
                int row = bm + wr * 64 + m * 16 + lg * 4 + r;
                if (row < M) C[(size_t)row * N + col] = acc[m][n][r] + bv;
            }
        }
    }
}

// ---------------- CSR build ----------------
__global__ void count_deg(const int* __restrict__ dst, const int* __restrict__ mask, int E,
                          int* __restrict__ cnt) {
    int e = blockIdx.x * blockDim.x + threadIdx.x;
    if (e >= E) return;
    if (mask && !mask[e]) return;
    atomicAdd(&cnt[dst[e]], 1);
}

__global__ void scan_deg(int n, int* __restrict__ cursor, int* __restrict__ rowstart,
                         float* __restrict__ deg) {
    __shared__ int buf[1024];
    __shared__ int sbase;
    if (threadIdx.x == 0) sbase = 0;
    __syncthreads();
    for (int start = 0; start < n; start += 1024) {
        int i = start + (int)threadIdx.x;
        int base = sbase;
        int v = (i < n) ? cursor[i] : 0;
        buf[threadIdx.x] = v;
        __syncthreads();
        for (int off = 1; off < 1024; off <<= 1) {
            int add = ((int)threadIdx.x >= off) ? buf[threadIdx.x - off] : 0;
            __syncthreads();
            buf[threadIdx.x] += add;
            __syncthreads();
        }
        int incl = buf[threadIdx.x];
        int excl = incl - v;
        int total = buf[1023];
        if (i < n) {
            rowstart[i] = base + excl;
            cursor[i] = base + excl;
            deg[i] = (float)v + 2.0f;
        }
        __syncthreads();
        if (threadIdx.x == 0) sbase = base + total;
        __syncthreads();
    }
    if (threadIdx.x == 0) rowstart[n] = sbase;
}

__global__ void csr_scatter(const int* __restrict__ src, const int* __restrict__ dst,
                            const int* __restrict__ mask, int E,
                            int* __restrict__ cursor, int* __restrict__ csr_src) {
    int e = blockIdx.x * blockDim.x + threadIdx.x;
    if (e >= E) return;
    if (mask && !mask[e]) return;
    int pos = atomicAdd(&cursor[dst[e]], 1);
    csr_src[pos] = src[e];
}

// ---------------- stage-1 aggregation on raw x (C=256), bf16 out ----------------
// agg[i,:] = (2/deg_i)*x[i,:] + sum_e rsqrt(deg_s)*rsqrt(deg_i)*x[s,:]  -> bf16
__global__ void aggregate_x_bf16(const int* __restrict__ rowstart, const int* __restrict__ csr_src,
                                 const float* __restrict__ deg, const float* __restrict__ x,
                                 ushort* __restrict__ out, int n) {
    int node = blockIdx.x * (blockDim.x >> 6) + ((int)threadIdx.x >> 6);
    if (node >= n) return;
    int lane = threadIdx.x & 63;
    int beg = rowstart[node], end = rowstart[node + 1];
    float dg = deg[node];
    float dinv = rsqrtf(dg);
    float4 acc = make_float4(0.f, 0.f, 0.f, 0.f);
    for (int j = beg; j < end; ++j) {
        int s = csr_src[j];
        float coef = rsqrtf(deg[s]) * dinv;
        float4 t = reinterpret_cast<const float4*>(&x[(size_t)s * CIN])[lane];
        acc.x += coef * t.x; acc.y += coef * t.y; acc.z += coef * t.z; acc.w += coef * t.w;
    }
    float self = 2.0f / dg;
    float4 t = reinterpret_cast<const float4*>(&x[(size_t)node * CIN])[lane];
    acc.x += self * t.x; acc.y += self * t.y; acc.z += self * t.z; acc.w += self * t.w;
    ushort4 o;
    o.x = f2bf(acc.x); o.y = f2bf(acc.y); o.z = f2bf(acc.z); o.w = f2bf(acc.w);
    reinterpret_cast<ushort4*>(&out[(size_t)node * CIN])[lane] = o;
}

// ---------------- stage-2 aggregation (f32, fused self+bias) ----------------
template <int C>
__global__ void aggregate_csr(const int* __restrict__ rowstart, const int* __restrict__ csr_src,
                              const float* __restrict__ deg, const float* __restrict__ xW,
                              const float* __restrict__ b, float* __restrict__ out, int n) {
    int node = blockIdx.x * (blockDim.x >> 6) + ((int)threadIdx.x >> 6);
    if (node >= n) return;
    int lane = threadIdx.x & 63;
    int beg = rowstart[node], end = rowstart[node + 1];
    float dg = deg[node];
    float dinv = rsqrtf(dg);
    constexpr int NV = C / 256;
    float4 acc[NV];
#pragma unroll
    for (int v = 0; v < NV; ++v) acc[v] = make_float4(0.f, 0.f, 0.f, 0.f);
    for (int j = beg; j < end; ++j) {
        int s = csr_src[j];
        float coef = rsqrtf(deg[s]) * dinv;
        const float4* row = reinterpret_cast<const float4*>(&xW[(size_t)s * C]);
#pragma unroll
        for (int v = 0; v < NV; ++v) {
            float4 t = row[lane + 64 * v];
            acc[v].x += coef * t.x; acc[v].y += coef * t.y;
            acc[v].z += coef * t.z; acc[v].w += coef * t.w;
        }
    }
    float self = 2.0f / dg;
    const float4* srow = reinterpret_cast<const float4*>(&xW[(size_t)node * C]);
    const float4* brow = reinterpret_cast<const float4*>(b);
    float4* orow = reinterpret_cast<float4*>(&out[(size_t)node * C]);
#pragma unroll
    for (int v = 0; v < NV; ++v) {
        float4 t = srow[lane + 64 * v];
        float4 bb = brow[lane + 64 * v];
        float4 o;
        o.x = acc[v].x + self * t.x + bb.x;
        o.y = acc[v].y + self * t.y + bb.y;
        o.z = acc[v].z + self * t.z + bb.z;
        o.w = acc[v].w + self * t.w + bb.w;
        orow[lane + 64 * v] = o;
    }
}

// ---------------- graph-norm: sum & sumsq ----------------
__global__ void reduce_sum_sq(const float* __restrict__ x, size_t n, float* __restrict__ S) {
    float s = 0.f, q = 0.f;
    for (size_t i = blockIdx.x * (size_t)blockDim.x + threadIdx.x; i < n;
         i += (size_t)gridDim.x * blockDim.x) {
        float v = x[i];
        s += v; q += v * v;
    }
    __shared__ float ls[256], lq[256];
    ls[threadIdx.x] = s; lq[threadIdx.x] = q;
    __syncthreads();
    for (int off = 128; off > 0; off >>= 1) {
        if ((int)threadIdx.x < off) {
            ls[threadIdx.x] += ls[threadIdx.x + off];
            lq[threadIdx.x] += lq[threadIdx.x + off];
        }
        __syncthreads();
    }
    if (threadIdx.x == 0) {
        atomicAdd(&S[0], ls[0]);
        atomicAdd(&S[1], lq[0]);
    }
}

__global__ void norm_relu(float* __restrict__ x, size_t n, const float* __restrict__ S,
                          float inv_cnt, const float* __restrict__ w,
                          const float* __restrict__ b, int C) {
    float mean = S[0] * inv_cnt;
    float var = S[1] * inv_cnt - mean * mean;
    float istd = 1.f / (sqrtf(fmaxf(var, 0.f)) + EPSV);
    for (size_t i = blockIdx.x * (size_t)blockDim.x + threadIdx.x; i < n;
         i += (size_t)gridDim.x * blockDim.x) {
        int c = (int)(i & (C - 1));
        float v = (x[i] - mean) * istd * w[c] + b[c];
        x[i] = fmaxf(v, 0.f);
    }
}

// ---------------- per-node scores ----------------
__global__ void node_scores(const float* __restrict__ h, int n, int C,
                            const float* __restrict__ wrel, const float* __restrict__ brel,
                            const float* __restrict__ wroot,
                            float* __restrict__ r, float* __restrict__ score) {
    int node = blockIdx.x * (blockDim.x >> 6) + (threadIdx.x >> 6);
    int lane = threadIdx.x & 63;
    if (node >= n) return;
    float sr = 0.f, st = 0.f;
    for (int c = lane; c < C; c += 64) {
        float v = h[(size_t)node * C + c];
        sr += v * wrel[c];
        st += v * wroot[c];
    }
    for (int off = 32; off > 0; off >>= 1) {
        sr += __shfl_down(sr, off);
        st += __shfl_down(st, off);
    }
    if (lane == 0) {
        r[node] = sr;
        score[node] = st + brel[0];
    }
}

__global__ void gather_score(const int* __restrict__ rowstart, const int* __restrict__ csr_src,
                             const float* __restrict__ r, float* __restrict__ score, int n) {
    int i = blockIdx.x * blockDim.x + threadIdx.x;
    if (i >= n) return;
    float s = 0.f;
    int beg = rowstart[i], end = rowstart[i + 1];
    for (int j = beg; j < end; ++j) s += r[csr_src[j]];
    score[i] += s;
}

// ---------------- top-k ----------------
__global__ void keyify(const float* __restrict__ score, unsigned* __restrict__ key, int n) {
    int i = blockIdx.x * blockDim.x + threadIdx.x;
    if (i >= n) return;
    unsigned u = __float_as_uint(score[i]);
    key[i] = (u & 0x80000000u) ? ~u : (u | 0x80000000u);
}

__global__ void init_sel(unsigned* __restrict__ sel, unsigned k, unsigned* __restrict__ hist) {
    if (threadIdx.x == 0) { sel[0] = 0u; sel[1] = k; }
    if (threadIdx.x < 256) hist[threadIdx.x] = 0u;
}

__global__ void radix_hist(const unsigned* __restrict__ key, int n,
                           const unsigned* __restrict__ sel, int pass,
                           unsigned* __restrict__ hist) {
    __shared__ unsigned lh[256];
    if (threadIdx.x < 256) lh[threadIdx.x] = 0u;
    __syncthreads();
    unsigned pref = sel[0];
    unsigned msk = pass ? (0xFFFFFFFFu << (32 - 8 * pass)) : 0u;
    int shift = 24 - 8 * pass;
    for (int i = blockIdx.x * blockDim.x + threadIdx.x; i < n; i += gridDim.x * blockDim.x) {
        unsigned u = key[i];
        if (((u ^ pref) & msk) == 0u) atomicAdd(&lh[(u >> shift) & 255u], 1u);
    }
    __syncthreads();
    if (threadIdx.x < 256 && lh[threadIdx.x]) atomicAdd(&hist[threadIdx.x], lh[threadIdx.x]);
}

__global__ void radix_scan(unsigned* __restrict__ sel, unsigned* __restrict__ hist, int pass) {
    if (threadIdx.x == 0) {
        unsigned rem = sel[1];
        unsigned cum = 0u;
        int b = 0;
        for (int bb = 255; bb >= 0; --bb) {
            unsigned h = hist[bb];
            if (cum + h >= rem) { b = bb; break; }
            cum += h;
        }
        sel[0] |= ((unsigned)b) << (24 - 8 * pass);
        sel[1] = rem - cum;
    }
    __syncthreads();
    if (threadIdx.x < 256) hist[threadIdx.x] = 0u;
}

__device__ unsigned block_exscan(unsigned* buf, unsigned v) {
    int t = threadIdx.x;
    buf[t] = v;
    __syncthreads();
    for (int off = 1; off < 1024; off <<= 1) {
        unsigned add = (t >= off) ? buf[t - off] : 0u;
        __syncthreads();
        buf[t] += add;
        __syncthreads();
    }
    return buf[t] - v;
}

__global__ void select_compact(const unsigned* __restrict__ key, int n,
                               const unsigned* __restrict__ sel,
                               int* __restrict__ kept, int* __restrict__ inv) {
    __shared__ unsigned buf[1024];
    __shared__ unsigned sbase[2];
    unsigned thr = sel[0], tie = sel[1];
    if (threadIdx.x == 0) { sbase[0] = 0u; sbase[1] = 0u; }
    __syncthreads();
    for (int start = 0; start < n; start += 1024) {
        int i = start + (int)threadIdx.x;
        unsigned g = 0u, eq = 0u;
        if (i < n) {
            unsigned u = key[i];
            g = (u > thr) ? 1u : 0u;
            eq = (u == thr) ? 1u : 0u;
        }
        unsigned eq_base = sbase[0];
        unsigned keep_base = sbase[1];
        unsigned eqx = block_exscan(buf, eq);
        unsigned keep = g | (eq & (((eq_base + eqx) < tie) ? 1u : 0u));
        __syncthreads();
        unsigned kx = block_exscan(buf, keep);
        if (i < n) {
            kept[i] = (int)keep;
            inv[i] = (int)(keep_base + kx);
        }
        __syncthreads();
        if (threadIdx.x == 1023) {
            sbase[0] = eq_base + eqx + eq;
            sbase[1] = keep_base + kx + keep;
        }
        __syncthreads();
    }
}

// ---------------- pool apply (bf16 out) ----------------
__global__ void pool_apply_bf16(const float* __restrict__ h, const float* __restrict__ score,
                                const int* __restrict__ kept, const int* __restrict__ inv,
                                int n, int C, ushort* __restrict__ hp) {
    size_t total = (size_t)n * C;
    for (size_t i = blockIdx.x * (size_t)blockDim.x + threadIdx.x; i < total;
         i += (size_t)gridDim.x * blockDim.x) {
        int row = (int)(i / C);
        if (!kept[row]) continue;
        int c = (int)(i & (C - 1));
        hp[(size_t)inv[row] * C + c] = f2bf(h[i] * tanhf(score[row]));
    }
}

// ---------------- edge relabel ----------------
__global__ void edge_relabel(const int* __restrict__ src, const int* __restrict__ dst, int E,
                             const int* __restrict__ kept, const int* __restrict__ inv,
                             int* __restrict__ src2, int* __restrict__ dst2,
                             int* __restrict__ mask2) {
    int e = blockIdx.x * blockDim.x + threadIdx.x;
    if (e >= E) return;
    int s = src[e], d = dst[e];
    int m = kept[s] & kept[d];
    mask2[e] = m;
    src2[e] = m ? inv[s] : 0;
    dst2[e] = m ? inv[d] : 0;
}

// ---------------- masked weighted column mean ----------------
__global__ void masked_colmean(const float* __restrict__ h, const float* __restrict__ score,
                               const int* __restrict__ kept, int n, int C, float invk,
                               float* __restrict__ g) {
    int c = blockIdx.x;
    float s = 0.f;
    for (int i = threadIdx.x; i < n; i += blockDim.x)
        if (kept[i]) s += tanhf(score[i]) * h[(size_t)i * C + c];
    __shared__ float ls[256];
    ls[threadIdx.x] = s;
    __syncthreads();
    for (int off = 128; off > 0; off >>= 1) {
        if ((int)threadIdx.x < off) ls[threadIdx.x] += ls[threadIdx.x + off];
        __syncthreads();
    }
    if (threadIdx.x == 0) g[c] = ls[0] * invk;
}

__global__ void final_gemv(const float* __restrict__ g, const float* __restrict__ Wf,
                           const float* __restrict__ bf, float* __restrict__ out) {
    int j = threadIdx.x;  // 128
    float s = bf[j];
    for (int c = 0; c < 256; ++c) s += g[c] * Wf[c * NOUT + j];
    out[j] = s;
}

// =======================================================================================
extern "C" void kernel_launch(void* const* d_in, const int* in_sizes, int n_in,
                              void* d_out, int out_size, void* d_ws, size_t ws_size,
                              hipStream_t stream) {
    const float* x      = (const float*)d_in[0];
    const int*   ei     = (const int*)d_in[1];
    const float* W1     = (const float*)d_in[2];
    const float* b1     = (const float*)d_in[3];
    const float* ln1w   = (const float*)d_in[4];
    const float* ln1b   = (const float*)d_in[5];
    const float* p1wrel = (const float*)d_in[6];
    const float* p1brel = (const float*)d_in[7];
    const float* p1wroot= (const float*)d_in[8];
    const float* W2     = (const float*)d_in[9];
    const float* b2     = (const float*)d_in[10];
    const float* ln2w   = (const float*)d_in[11];
    const float* ln2b   = (const float*)d_in[12];
    const float* p2wrel = (const float*)d_in[13];
    const float* p2brel = (const float*)d_in[14];
    const float* p2wroot= (const float*)d_in[15];
    const float* Wf     = (const float*)d_in[16];
    const float* bf     = (const float*)d_in[17];
    float* out = (float*)d_out;
    char* ws = (char*)d_ws;

    const int* src1 = ei;
    const int* dst1 = ei + NE;

    // ---- workspace layout (bytes) ----
    // region 0 (40.96 MB): h1 f32 [20000][512]; after h1 dies: xW2 f32 @+0, h2 f32 @+20,480,000
    // region 1 (10.24 MB): agg_bf [20000][256] bf16; after GEMM1: h1p_bf [10000][512] bf16
    const size_t o0     = 0;
    const size_t o1     = 40960000;
    const size_t oW1t   = 51200000;   // 262,144
    const size_t oW2t   = 51462144;   // 262,144
    const size_t oSrc2  = 51724288;   // 1,280,000
    const size_t oDst2  = 53004288;
    const size_t oMask2 = 54284288;
    const size_t oCsr   = 55564288;   // 1,280,000
    const size_t oRow   = 56844288;   // 80,064
    const size_t oCur   = 56924352;
    const size_t oDeg   = 57004352;
    const size_t oR     = 57084352;
    const size_t oScore1= 57164352;
    const size_t oKeyu  = 57244352;
    const size_t oKept  = 57324352;
    const size_t oInv   = 57404352;
    const size_t oScore2= 57484352;
    const size_t oKeyu2 = 57524352;
    const size_t oKept2 = 57564352;
    const size_t oInv2  = 57604352;
    const size_t oS     = 57644352;
    const size_t oHist  = 57644416;
    const size_t oSel   = 57645440;
    const size_t oG     = 57645504;

    float*  h1    = (float*)(ws + o0);
    float*  xW2   = (float*)(ws + o0);
    float*  h2    = (float*)(ws + o0 + 20480000);
    ushort* aggb  = (ushort*)(ws + o1);
    ushort* h1pb  = (ushort*)(ws + o1);
    ushort* W1t   = (ushort*)(ws + oW1t);
    ushort* W2t   = (ushort*)(ws + oW2t);
    int*    src2  = (int*)(ws + oSrc2);
    int*    dst2  = (int*)(ws + oDst2);
    int*    mask2 = (int*)(ws + oMask2);
    int*    csr   = (int*)(ws + oCsr);
    int*    row   = (int*)(ws + oRow);
    int*    cur   = (int*)(ws + oCur);
    float*  deg   = (float*)(ws + oDeg);
    float*  r     = (float*)(ws + oR);
    float*  score1= (float*)(ws + oScore1);
    unsigned* keyu  = (unsigned*)(ws + oKeyu);
    int*    kept  = (int*)(ws + oKept);
    int*    inv   = (int*)(ws + oInv);
    float*  score2= (float*)(ws + oScore2);
    unsigned* keyu2 = (unsigned*)(ws + oKeyu2);
    int*    kept2 = (int*)(ws + oKept2);
    int*    inv2  = (int*)(ws + oInv2);
    float*  S     = (float*)(ws + oS);
    unsigned* hist = (unsigned*)(ws + oHist);
    unsigned* sel  = (unsigned*)(ws + oSel);
    float*  g     = (float*)(ws + oG);

    // ================= Stage 1 =================
    // CSR build
    fill_i32<<<cdiv(N1, 256), 256, 0, stream>>>(cur, 0, N1);
    count_deg<<<cdiv(NE, 256), 256, 0, stream>>>(dst1, nullptr, NE, cur);
    scan_deg<<<1, 1024, 0, stream>>>(N1, cur, row, deg);
    csr_scatter<<<cdiv(NE, 256), 256, 0, stream>>>(src1, dst1, nullptr, NE, cur, csr);

    // aggregate BEFORE transform (C_in=256 < C_out=512), emit bf16
    aggregate_x_bf16<<<cdiv(N1, 4), 256, 0, stream>>>(row, csr, deg, x, aggb, N1);

    // h1 = agg @ W1 + b1   (MFMA bf16)
    conv_transpose_bf16<<<cdiv(CIN * C1, 256), 256, 0, stream>>>(W1, W1t, CIN, C1);
    gemm_bf16_mfma<<<dim3(cdiv(N1, 128), C1 / 128), 256, 0, stream>>>(aggb, W1t, b1, h1, N1, C1, CIN);

    fill_f32<<<1, 64, 0, stream>>>(S, 0.f, 2);
    reduce_sum_sq<<<2048, 256, 0, stream>>>(h1, (size_t)N1 * C1, S);
    norm_relu<<<2048, 256, 0, stream>>>(h1, (size_t)N1 * C1, S, 1.f / ((float)N1 * C1), ln1w, ln1b, C1);

    node_scores<<<cdiv(N1, 4), 256, 0, stream>>>(h1, N1, C1, p1wrel, p1brel, p1wroot, r, score1);
    gather_score<<<cdiv(N1, 256), 256, 0, stream>>>(row, csr, r, score1, N1);

    keyify<<<cdiv(N1, 256), 256, 0, stream>>>(score1, keyu, N1);
    init_sel<<<1, 256, 0, stream>>>(sel, K1, hist);
    for (int pass = 0; pass < 4; ++pass) {
        radix_hist<<<cdiv(N1, 256), 256, 0, stream>>>(keyu, N1, sel, pass, hist);
        radix_scan<<<1, 256, 0, stream>>>(sel, hist, pass);
    }
    select_compact<<<1, 1024, 0, stream>>>(keyu, N1, sel, kept, inv);

    pool_apply_bf16<<<4096, 256, 0, stream>>>(h1, score1, kept, inv, N1, C1, h1pb);
    edge_relabel<<<cdiv(NE, 256), 256, 0, stream>>>(src1, dst1, NE, kept, inv, src2, dst2, mask2);

    // ================= Stage 2 =================
    // transform BEFORE aggregate (C_in=512 > C_out=256): xW2 = h1p @ W2 (no bias here)
    conv_transpose_bf16<<<cdiv(C1 * C2, 256), 256, 0, stream>>>(W2, W2t, C1, C2);
    gemm_bf16_mfma<<<dim3(cdiv(K1, 128), C2 / 128), 256, 0, stream>>>(h1pb, W2t, nullptr, xW2, K1, C2, C1);

    fill_i32<<<cdiv(K1, 256), 256, 0, stream>>>(cur, 0, K1);
    count_deg<<<cdiv(NE, 256), 256, 0, stream>>>(dst2, mask2, NE, cur);
    scan_deg<<<1, 1024, 0, stream>>>(K1, cur, row, deg);
    csr_scatter<<<cdiv(NE, 256), 256, 0, stream>>>(src2, dst2, mask2, NE, cur, csr);

    aggregate_csr<C2><<<cdiv(K1, 4), 256, 0, stream>>>(row, csr, deg, xW2, b2, h2, K1);

    fill_f32<<<1, 64, 0, stream>>>(S, 0.f, 2);
    reduce_sum_sq<<<2048, 256, 0, stream>>>(h2, (size_t)K1 * C2, S);
    norm_relu<<<2048, 256, 0, stream>>>(h2, (size_t)K1 * C2, S, 1.f / ((float)K1 * C2), ln2w, ln2b, C2);

    node_scores<<<cdiv(K1, 4), 256, 0, stream>>>(h2, K1, C2, p2wrel, p2brel, p2wroot, r, score2);
    gather_score<<<cdiv(K1, 256), 256, 0, stream>>>(row, csr, r, score2, K1);

    keyify<<<cdiv(K1, 256), 256, 0, stream>>>(score2, keyu2, K1);
    init_sel<<<1, 256, 0, stream>>>(sel, K2, hist);
    for (int pass = 0; pass < 4; ++pass) {
        radix_hist<<<cdiv(K1, 256), 256, 0, stream>>>(keyu2, K1, sel, pass, hist);
        radix_scan<<<1, 256, 0, stream>>>(sel, hist, pass);
    }
    select_compact<<<1, 1024, 0, stream>>>(keyu2, K1, sel, kept2, inv2);

    // ================= readout =================
    masked_colmean<<<C2, 256, 0, stream>>>(h2, score2, kept2, K1, C2, 1.f / (float)K2, g);
    final_gemv<<<1, NOUT, 0, stream>>>(g, Wf, bf, out);
}

// Round 4
// 593.761 us; speedup vs baseline: 5.2109x; 1.1052x over previous
//
#include <hip/hip_runtime.h>
#include <math.h>

#define N1 20000
#define NE 320000
#define CIN 256
#define C1 512
#define C2 256
#define K1 10000
#define K2 5000
#define NOUT 128
#define EPSV 1e-5f

typedef __attribute__((ext_vector_type(8))) short bf16x8;
typedef __attribute__((ext_vector_type(4))) float f32x4;

static inline unsigned cdiv(unsigned a, unsigned b) { return (a + b - 1) / b; }

__device__ inline ushort f2bf(float f) {
    unsigned u = __float_as_uint(f);
    unsigned r = u + 0x7FFFu + ((u >> 16) & 1u);
    return (ushort)(r >> 16);
}
__device__ inline float bf2f(ushort u) { return __uint_as_float(((unsigned)u) << 16); }

// ---------------- fills ----------------
__global__ void fill_f32(float* __restrict__ p, float v, int n) {
    int i = blockIdx.x * blockDim.x + threadIdx.x;
    if (i < n) p[i] = v;
}
__global__ void fill_i32(int* __restrict__ p, int v, int n) {
    int i = blockIdx.x * blockDim.x + threadIdx.x;
    if (i < n) p[i] = v;
}

// ---------------- f32 -> bf16 (vectorized, n multiple of 4) ----------------
__global__ void f32_to_bf16(const float* __restrict__ in, ushort* __restrict__ out, int n4) {
    int i = blockIdx.x * blockDim.x + threadIdx.x;
    if (i >= n4) return;
    float4 v = reinterpret_cast<const float4*>(in)[i];
    ushort4 o;
    o.x = f2bf(v.x); o.y = f2bf(v.y); o.z = f2bf(v.z); o.w = f2bf(v.w);
    reinterpret_cast<ushort4*>(out)[i] = o;
}

// ---------------- weight convert+transpose: Wt[n][k] = bf16(W[k][n]) ----------------
__global__ void conv_transpose_bf16(const float* __restrict__ W, ushort* __restrict__ Wt,
                                    int K, int N) {
    int i = blockIdx.x * blockDim.x + threadIdx.x;
    if (i >= K * N) return;
    int k = i / N, n = i % N;
    Wt[(size_t)n * K + k] = f2bf(W[i]);
}

// ---------------- MFMA bf16 GEMM ----------------
// BM=BN=128, BK=32; 4 waves 2x2, each 64x64 via 4x4 frags of 16x16x32.
template <bool BF16OUT>
__global__ __launch_bounds__(256)
void gemm_bf16_mfma(const ushort* __restrict__ A, const ushort* __restrict__ Bt,
                    const float* __restrict__ bias, float* __restrict__ C,
                    ushort* __restrict__ Cb, int M, int N, int K) {
    constexpr int BM = 128, BN = 128, BK = 32;
    constexpr int LDK = BK + 8;
    __shared__ ushort As[BM * LDK];
    __shared__ ushort Bs[BN * LDK];
    int tid = threadIdx.x;
    int wid = tid >> 6, lane = tid & 63;
    int wr = wid >> 1, wc = wid & 1;
    int bm = blockIdx.x * BM, bn = blockIdx.y * BN;
    int lg = lane >> 4, lm = lane & 15;
    f32x4 zero = {0.f, 0.f, 0.f, 0.f};
    f32x4 acc[4][4];
#pragma unroll
    for (int m = 0; m < 4; ++m)
#pragma unroll
        for (int n = 0; n < 4; ++n) acc[m][n] = zero;

    for (int k0 = 0; k0 < K; k0 += BK) {
#pragma unroll
        for (int it = 0; it < 2; ++it) {
            int task = tid * 2 + it;
            int row = task >> 2, c8 = (task & 3) * 8;
            int gm = bm + row;
            bf16x8 v = {0, 0, 0, 0, 0, 0, 0, 0};
            if (gm < M) v = *(const bf16x8*)&A[(size_t)gm * K + k0 + c8];
            *(bf16x8*)&As[row * LDK + c8] = v;
            int gn = bn + row;
            bf16x8 w = {0, 0, 0, 0, 0, 0, 0, 0};
            if (gn < N) w = *(const bf16x8*)&Bt[(size_t)gn * K + k0 + c8];
            *(bf16x8*)&Bs[row * LDK + c8] = w;
        }
        __syncthreads();
        bf16x8 af[4], bfr[4];
#pragma unroll
        for (int m = 0; m < 4; ++m)
            af[m] = *(bf16x8*)&As[(wr * 64 + m * 16 + lm) * LDK + lg * 8];
#pragma unroll
        for (int n = 0; n < 4; ++n)
            bfr[n] = *(bf16x8*)&Bs[(wc * 64 + n * 16 + lm) * LDK + lg * 8];
#pragma unroll
        for (int m = 0; m < 4; ++m)
#pragma unroll
            for (int n = 0; n < 4; ++n)
                acc[m][n] = __builtin_amdgcn_mfma_f32_16x16x32_bf16(af[m], bfr[n], acc[m][n], 0, 0, 0);
        __syncthreads();
    }
#pragma unroll
    for (int m = 0; m < 4; ++m) {
#pragma unroll
        for (int n = 0; n < 4; ++n) {
            int col = bn + wc * 64 + n * 16 + lm;
            float bv = bias ? bias[col] : 0.f;
#pragma unroll
            for (int r = 0; r < 4; ++r) {
                int row = bm + wr * 64 + m * 16 + lg * 4 + r;
                if (row < M) {
                    float val = acc[m][n][r] + bv;
                    if (BF16OUT) Cb[(size_t)row * N + col] = f2bf(val);
                    else         C[(size_t)row * N + col] = val;
                }
            }
        }
    }
}

// ---------------- CSR build ----------------
__global__ void count_deg(const int* __restrict__ dst, const int* __restrict__ mask, int E,
                          int* __restrict__ cnt) {
    int e = blockIdx.x * blockDim.x + threadIdx.x;
    if (e >= E) return;
    if (mask && !mask[e]) return;
    atomicAdd(&cnt[dst[e]], 1);
}

__global__ void scan_deg(int n, int* __restrict__ cursor, int* __restrict__ rowstart,
                         float* __restrict__ deg, float* __restrict__ dinv) {
    __shared__ int buf[1024];
    __shared__ int sbase;
    if (threadIdx.x == 0) sbase = 0;
    __syncthreads();
    for (int start = 0; start < n; start += 1024) {
        int i = start + (int)threadIdx.x;
        int base = sbase;
        int v = (i < n) ? cursor[i] : 0;
        buf[threadIdx.x] = v;
        __syncthreads();
        for (int off = 1; off < 1024; off <<= 1) {
            int add = ((int)threadIdx.x >= off) ? buf[threadIdx.x - off] : 0;
            __syncthreads();
            buf[threadIdx.x] += add;
            __syncthreads();
        }
        int incl = buf[threadIdx.x];
        int excl = incl - v;
        int total = buf[1023];
        if (i < n) {
            rowstart[i] = base + excl;
            cursor[i] = base + excl;
            float dg = (float)v + 2.0f;
            deg[i] = dg;
            dinv[i] = rsqrtf(dg);
        }
        __syncthreads();
        if (threadIdx.x == 0) sbase = base + total;
        __syncthreads();
    }
    if (threadIdx.x == 0) rowstart[n] = sbase;
}

__global__ void csr_scatter(const int* __restrict__ src, const int* __restrict__ dst,
                            const int* __restrict__ mask, int E,
                            int* __restrict__ cursor, int* __restrict__ csr_src) {
    int e = blockIdx.x * blockDim.x + threadIdx.x;
    if (e >= E) return;
    if (mask && !mask[e]) return;
    int pos = atomicAdd(&cursor[dst[e]], 1);
    csr_src[pos] = src[e];
}

// ---------------- stage-1 aggregation on bf16 x (C=256), bf16 out ----------------
__global__ void aggregate_xb(const int* __restrict__ rowstart, const int* __restrict__ csr_src,
                             const float* __restrict__ deg, const float* __restrict__ dinv,
                             const ushort* __restrict__ xb, ushort* __restrict__ out, int n) {
    int node = blockIdx.x * (blockDim.x >> 6) + ((int)threadIdx.x >> 6);
    if (node >= n) return;
    int lane = threadIdx.x & 63;
    int beg = rowstart[node], end = rowstart[node + 1];
    float di = dinv[node];
    float4 acc = make_float4(0.f, 0.f, 0.f, 0.f);
    for (int j = beg; j < end; ++j) {
        int s = csr_src[j];
        float coef = dinv[s] * di;
        ushort4 t = reinterpret_cast<const ushort4*>(&xb[(size_t)s * CIN])[lane];
        acc.x += coef * bf2f(t.x);
        acc.y += coef * bf2f(t.y);
        acc.z += coef * bf2f(t.z);
        acc.w += coef * bf2f(t.w);
    }
    float self = 2.0f / deg[node];
    ushort4 t = reinterpret_cast<const ushort4*>(&xb[(size_t)node * CIN])[lane];
    acc.x += self * bf2f(t.x);
    acc.y += self * bf2f(t.y);
    acc.z += self * bf2f(t.z);
    acc.w += self * bf2f(t.w);
    ushort4 o;
    o.x = f2bf(acc.x); o.y = f2bf(acc.y); o.z = f2bf(acc.z); o.w = f2bf(acc.w);
    reinterpret_cast<ushort4*>(&out[(size_t)node * CIN])[lane] = o;
}

// ---------------- stage-2 aggregation on bf16 xW (C=256), f32 out + bias + self ----------------
__global__ void aggregate_csr_bf(const int* __restrict__ rowstart, const int* __restrict__ csr_src,
                                 const float* __restrict__ deg, const float* __restrict__ dinv,
                                 const ushort* __restrict__ xWb, const float* __restrict__ b,
                                 float* __restrict__ out, int n) {
    int node = blockIdx.x * (blockDim.x >> 6) + ((int)threadIdx.x >> 6);
    if (node >= n) return;
    int lane = threadIdx.x & 63;
    int beg = rowstart[node], end = rowstart[node + 1];
    float di = dinv[node];
    float4 acc = make_float4(0.f, 0.f, 0.f, 0.f);
    for (int j = beg; j < end; ++j) {
        int s = csr_src[j];
        float coef = dinv[s] * di;
        ushort4 t = reinterpret_cast<const ushort4*>(&xWb[(size_t)s * C2])[lane];
        acc.x += coef * bf2f(t.x);
        acc.y += coef * bf2f(t.y);
        acc.z += coef * bf2f(t.z);
        acc.w += coef * bf2f(t.w);
    }
    float self = 2.0f / deg[node];
    ushort4 t = reinterpret_cast<const ushort4*>(&xWb[(size_t)node * C2])[lane];
    float4 bb = reinterpret_cast<const float4*>(b)[lane];
    float4 o;
    o.x = acc.x + self * bf2f(t.x) + bb.x;
    o.y = acc.y + self * bf2f(t.y) + bb.y;
    o.z = acc.z + self * bf2f(t.z) + bb.z;
    o.w = acc.w + self * bf2f(t.w) + bb.w;
    reinterpret_cast<float4*>(&out[(size_t)node * C2])[lane] = o;
}

// ---------------- graph-norm ----------------
__global__ void reduce_sum_sq(const float* __restrict__ x, size_t n, float* __restrict__ S) {
    float s = 0.f, q = 0.f;
    for (size_t i = blockIdx.x * (size_t)blockDim.x + threadIdx.x; i < n;
         i += (size_t)gridDim.x * blockDim.x) {
        float v = x[i];
        s += v; q += v * v;
    }
    __shared__ float ls[256], lq[256];
    ls[threadIdx.x] = s; lq[threadIdx.x] = q;
    __syncthreads();
    for (int off = 128; off > 0; off >>= 1) {
        if ((int)threadIdx.x < off) {
            ls[threadIdx.x] += ls[threadIdx.x + off];
            lq[threadIdx.x] += lq[threadIdx.x + off];
        }
        __syncthreads();
    }
    if (threadIdx.x == 0) {
        atomicAdd(&S[0], ls[0]);
        atomicAdd(&S[1], lq[0]);
    }
}

__global__ void norm_relu(float* __restrict__ x, size_t n, const float* __restrict__ S,
                          float inv_cnt, const float* __restrict__ w,
                          const float* __restrict__ b, int C) {
    float mean = S[0] * inv_cnt;
    float var = S[1] * inv_cnt - mean * mean;
    float istd = 1.f / (sqrtf(fmaxf(var, 0.f)) + EPSV);
    for (size_t i = blockIdx.x * (size_t)blockDim.x + threadIdx.x; i < n;
         i += (size_t)gridDim.x * blockDim.x) {
        int c = (int)(i & (C - 1));
        float v = (x[i] - mean) * istd * w[c] + b[c];
        x[i] = fmaxf(v, 0.f);
    }
}

// ---------------- per-node scores ----------------
__global__ void node_scores(const float* __restrict__ h, int n, int C,
                            const float* __restrict__ wrel, const float* __restrict__ brel,
                            const float* __restrict__ wroot,
                            float* __restrict__ r, float* __restrict__ score) {
    int node = blockIdx.x * (blockDim.x >> 6) + (threadIdx.x >> 6);
    int lane = threadIdx.x & 63;
    if (node >= n) return;
    float sr = 0.f, st = 0.f;
    for (int c = lane; c < C; c += 64) {
        float v = h[(size_t)node * C + c];
        sr += v * wrel[c];
        st += v * wroot[c];
    }
    for (int off = 32; off > 0; off >>= 1) {
        sr += __shfl_down(sr, off);
        st += __shfl_down(st, off);
    }
    if (lane == 0) {
        r[node] = sr;
        score[node] = st + brel[0];
    }
}

__global__ void gather_score(const int* __restrict__ rowstart, const int* __restrict__ csr_src,
                             const float* __restrict__ r, float* __restrict__ score, int n) {
    int i = blockIdx.x * blockDim.x + threadIdx.x;
    if (i >= n) return;
    float s = 0.f;
    int beg = rowstart[i], end = rowstart[i + 1];
    for (int j = beg; j < end; ++j) s += r[csr_src[j]];
    score[i] += s;
}

// ---------------- top-k: keyify + radix select ----------------
__global__ void keyify(const float* __restrict__ score, unsigned* __restrict__ key, int n) {
    int i = blockIdx.x * blockDim.x + threadIdx.x;
    if (i >= n) return;
    unsigned u = __float_as_uint(score[i]);
    key[i] = (u & 0x80000000u) ? ~u : (u | 0x80000000u);
}

__global__ void init_sel(unsigned* __restrict__ sel, unsigned k, unsigned* __restrict__ hist) {
    if (threadIdx.x == 0) { sel[0] = 0u; sel[1] = k; }
    if (threadIdx.x < 256) hist[threadIdx.x] = 0u;
}

__global__ void radix_hist(const unsigned* __restrict__ key, int n,
                           const unsigned* __restrict__ sel, int pass,
                           unsigned* __restrict__ hist) {
    __shared__ unsigned lh[256];
    if (threadIdx.x < 256) lh[threadIdx.x] = 0u;
    __syncthreads();
    unsigned pref = sel[0];
    unsigned msk = pass ? (0xFFFFFFFFu << (32 - 8 * pass)) : 0u;
    int shift = 24 - 8 * pass;
    for (int i = blockIdx.x * blockDim.x + threadIdx.x; i < n; i += gridDim.x * blockDim.x) {
        unsigned u = key[i];
        if (((u ^ pref) & msk) == 0u) atomicAdd(&lh[(u >> shift) & 255u], 1u);
    }
    __syncthreads();
    if (threadIdx.x < 256 && lh[threadIdx.x]) atomicAdd(&hist[threadIdx.x], lh[threadIdx.x]);
}

__global__ void radix_scan(unsigned* __restrict__ sel, unsigned* __restrict__ hist, int pass) {
    if (threadIdx.x == 0) {
        unsigned rem = sel[1];
        unsigned cum = 0u;
        int b = 0;
        for (int bb = 255; bb >= 0; --bb) {
            unsigned h = hist[bb];
            if (cum + h >= rem) { b = bb; break; }
            cum += h;
        }
        sel[0] |= ((unsigned)b) << (24 - 8 * pass);
        sel[1] = rem - cum;
    }
    __syncthreads();
    if (threadIdx.x < 256) hist[threadIdx.x] = 0u;
}

// ---------------- multi-block deterministic select + compact ----------------
// inv[i] = #g before i + min(#eq before i, tie); kept via first-`tie` eq rule.
// 1024 elements per block (256 threads x 4 consecutive).
__global__ void sc_partial(const unsigned* __restrict__ key, int n, const unsigned* __restrict__ sel,
                           int* __restrict__ gpart, int* __restrict__ epart) {
    unsigned thr = sel[0];
    int base = blockIdx.x * 1024 + (int)threadIdx.x * 4;
    int gs = 0, es = 0;
#pragma unroll
    for (int t = 0; t < 4; ++t) {
        int i = base + t;
        if (i < n) {
            unsigned u = key[i];
            gs += (u > thr); es += (u == thr);
        }
    }
    for (int off = 32; off > 0; off >>= 1) {
        gs += __shfl_down(gs, off);
        es += __shfl_down(es, off);
    }
    __shared__ int sg[4], se[4];
    int wid = threadIdx.x >> 6;
    if ((threadIdx.x & 63) == 0) { sg[wid] = gs; se[wid] = es; }
    __syncthreads();
    if (threadIdx.x == 0) {
        gpart[blockIdx.x] = sg[0] + sg[1] + sg[2] + sg[3];
        epart[blockIdx.x] = se[0] + se[1] + se[2] + se[3];
    }
}

__global__ void sc_scan_partials(int nb, int* __restrict__ gpart, int* __restrict__ epart) {
    int lane = threadIdx.x;  // one wave of 64; nb <= 64
    int g0 = (lane < nb) ? gpart[lane] : 0;
    int e0 = (lane < nb) ? epart[lane] : 0;
    int g = g0, e = e0;
    for (int off = 1; off < 64; off <<= 1) {
        int gg = __shfl_up(g, off), ee = __shfl_up(e, off);
        if (lane >= off) { g += gg; e += ee; }
    }
    if (lane < nb) { gpart[lane] = g - g0; epart[lane] = e - e0; }  // exclusive
}

__global__ void sc_final(const unsigned* __restrict__ key, int n, const unsigned* __restrict__ sel,
                         const int* __restrict__ gpart, const int* __restrict__ epart,
                         int* __restrict__ kept, int* __restrict__ inv) {
    unsigned thr = sel[0];
    int tie = (int)sel[1];
    int base = blockIdx.x * 1024 + (int)threadIdx.x * 4;
    int gl[4], el[4];
    int gs = 0, es = 0;
#pragma unroll
    for (int t = 0; t < 4; ++t) {
        int i = base + t;
        gl[t] = 0; el[t] = 0;
        if (i < n) {
            unsigned u = key[i];
            gl[t] = (u > thr); el[t] = (u == thr);
        }
        gs += gl[t]; es += el[t];
    }
    int lane = threadIdx.x & 63, wid = threadIdx.x >> 6;
    int gi = gs, ei = es;
    for (int off = 1; off < 64; off <<= 1) {
        int gg = __shfl_up(gi, off), ee = __shfl_up(ei, off);
        if (lane >= off) { gi += gg; ei += ee; }
    }
    __shared__ int wg[4], we[4];
    if (lane == 63) { wg[wid] = gi; we[wid] = ei; }
    __syncthreads();
    int wgo = 0, weo = 0;
    for (int w = 0; w < wid; ++w) { wgo += wg[w]; weo += we[w]; }
    int gp = gpart[blockIdx.x] + (gi - gs) + wgo;
    int ep = epart[blockIdx.x] + (ei - es) + weo;
#pragma unroll
    for (int t = 0; t < 4; ++t) {
        int i = base + t;
        if (i < n) {
            int keep = gl[t] | (el[t] & ((ep < tie) ? 1 : 0));
            kept[i] = keep;
            inv[i] = gp + ((ep < tie) ? ep : tie);
        }
        gp += gl[t]; ep += el[t];
    }
}

// ---------------- pool apply (bf16 out) ----------------
__global__ void pool_apply_bf16(const float* __restrict__ h, const float* __restrict__ score,
                                const int* __restrict__ kept, const int* __restrict__ inv,
                                int n, int C, ushort* __restrict__ hp) {
    size_t total = (size_t)n * C;
    for (size_t i = blockIdx.x * (size_t)blockDim.x + threadIdx.x; i < total;
         i += (size_t)gridDim.x * blockDim.x) {
        int row = (int)(i / C);
        if (!kept[row]) continue;
        int c = (int)(i & (C - 1));
        hp[(size_t)inv[row] * C + c] = f2bf(h[i] * tanhf(score[row]));
    }
}

// ---------------- edge relabel ----------------
__global__ void edge_relabel(const int* __restrict__ src, const int* __restrict__ dst, int E,
                             const int* __restrict__ kept, const int* __restrict__ inv,
                             int* __restrict__ src2, int* __restrict__ dst2,
                             int* __restrict__ mask2) {
    int e = blockIdx.x * blockDim.x + threadIdx.x;
    if (e >= E) return;
    int s = src[e], d = dst[e];
    int m = kept[s] & kept[d];
    mask2[e] = m;
    src2[e] = m ? inv[s] : 0;
    dst2[e] = m ? inv[d] : 0;
}

// ---------------- masked weighted column mean ----------------
__global__ void masked_colmean(const float* __restrict__ h, const float* __restrict__ score,
                               const int* __restrict__ kept, int n, int C, float invk,
                               float* __restrict__ g) {
    int c = blockIdx.x;
    float s = 0.f;
    for (int i = threadIdx.x; i < n; i += blockDim.x)
        if (kept[i]) s += tanhf(score[i]) * h[(size_t)i * C + c];
    __shared__ float ls[256];
    ls[threadIdx.x] = s;
    __syncthreads();
    for (int off = 128; off > 0; off >>= 1) {
        if ((int)threadIdx.x < off) ls[threadIdx.x] += ls[threadIdx.x + off];
        __syncthreads();
    }
    if (threadIdx.x == 0) g[c] = ls[0] * invk;
}

__global__ void final_gemv(const float* __restrict__ g, const float* __restrict__ Wf,
                           const float* __restrict__ bf, float* __restrict__ out) {
    int j = threadIdx.x;  // 128
    float s = bf[j];
    for (int c = 0; c < 256; ++c) s += g[c] * Wf[c * NOUT + j];
    out[j] = s;
}

// =======================================================================================
extern "C" void kernel_launch(void* const* d_in, const int* in_sizes, int n_in,
                              void* d_out, int out_size, void* d_ws, size_t ws_size,
                              hipStream_t stream) {
    const float* x      = (const float*)d_in[0];
    const int*   ei     = (const int*)d_in[1];
    const float* W1     = (const float*)d_in[2];
    const float* b1     = (const float*)d_in[3];
    const float* ln1w   = (const float*)d_in[4];
    const float* ln1b   = (const float*)d_in[5];
    const float* p1wrel = (const float*)d_in[6];
    const float* p1brel = (const float*)d_in[7];
    const float* p1wroot= (const float*)d_in[8];
    const float* W2     = (const float*)d_in[9];
    const float* b2     = (const float*)d_in[10];
    const float* ln2w   = (const float*)d_in[11];
    const float* ln2b   = (const float*)d_in[12];
    const float* p2wrel = (const float*)d_in[13];
    const float* p2brel = (const float*)d_in[14];
    const float* p2wroot= (const float*)d_in[15];
    const float* Wf     = (const float*)d_in[16];
    const float* bf     = (const float*)d_in[17];
    float* out = (float*)d_out;
    char* ws = (char*)d_ws;

    const int* src1 = ei;
    const int* dst1 = ei + NE;

    // ---- workspace layout (bytes) ----
    // region 0 (40.96 MB): h1 f32 [20000][512]; after h1 dies: h2 f32 @+0 (10.24MB),
    //                      xW2b bf16 @+10,240,000 (5.12MB)
    // region 1 (10.24 MB): aggb bf16 [20000][256]; after GEMM1: h1pb bf16 [10000][512]
    const size_t o0     = 0;
    const size_t o1     = 40960000;
    const size_t oXb    = 51200000;   // 10,240,000 : xb bf16
    const size_t oW1t   = 61440000;   // 262,144
    const size_t oW2t   = 61702144;   // 262,144
    const size_t oSrc2  = 61964288;   // 1,280,000
    const size_t oDst2  = 63244288;
    const size_t oMask2 = 64524288;
    const size_t oCsr   = 65804288;   // 1,280,000
    const size_t oRow   = 67084288;   // 80,064
    const size_t oCur   = 67164352;   // 80,000
    const size_t oDeg   = 67244352;
    const size_t oDinv  = 67324352;
    const size_t oR     = 67404352;
    const size_t oScore1= 67484352;
    const size_t oKeyu  = 67564352;
    const size_t oKept  = 67644352;
    const size_t oInv   = 67724352;
    const size_t oScore2= 67804352;   // 40,000
    const size_t oKeyu2 = 67844352;
    const size_t oKept2 = 67884352;
    const size_t oInv2  = 67924352;
    const size_t oS     = 67964352;   // 64
    const size_t oHist  = 67964416;   // 1,024
    const size_t oSel   = 67965440;   // 64
    const size_t oGpart = 67965504;   // 256
    const size_t oEpart = 67965760;   // 256
    const size_t oG     = 67966016;   // 1,024

    float*  h1    = (float*)(ws + o0);
    float*  h2    = (float*)(ws + o0);
    ushort* xW2b  = (ushort*)(ws + o0 + 10240000);
    ushort* aggb  = (ushort*)(ws + o1);
    ushort* h1pb  = (ushort*)(ws + o1);
    ushort* xb    = (ushort*)(ws + oXb);
    ushort* W1t   = (ushort*)(ws + oW1t);
    ushort* W2t   = (ushort*)(ws + oW2t);
    int*    src2  = (int*)(ws + oSrc2);
    int*    dst2  = (int*)(ws + oDst2);
    int*    mask2 = (int*)(ws + oMask2);
    int*    csr   = (int*)(ws + oCsr);
    int*    row   = (int*)(ws + oRow);
    int*    cur   = (int*)(ws + oCur);
    float*  deg   = (float*)(ws + oDeg);
    float*  dinv  = (float*)(ws + oDinv);
    float*  r     = (float*)(ws + oR);
    float*  score1= (float*)(ws + oScore1);
    unsigned* keyu  = (unsigned*)(ws + oKeyu);
    int*    kept  = (int*)(ws + oKept);
    int*    inv   = (int*)(ws + oInv);
    float*  score2= (float*)(ws + oScore2);
    unsigned* keyu2 = (unsigned*)(ws + oKeyu2);
    int*    kept2 = (int*)(ws + oKept2);
    int*    inv2  = (int*)(ws + oInv2);
    float*  S     = (float*)(ws + oS);
    unsigned* hist = (unsigned*)(ws + oHist);
    unsigned* sel  = (unsigned*)(ws + oSel);
    int*    gpart = (int*)(ws + oGpart);
    int*    epart = (int*)(ws + oEpart);
    float*  g     = (float*)(ws + oG);

    const int nb1 = cdiv(N1, 1024);  // 20
    const int nb2 = cdiv(K1, 1024);  // 10

    // ================= Stage 1 =================
    f32_to_bf16<<<cdiv(N1 * CIN / 4, 256), 256, 0, stream>>>(x, xb, N1 * CIN / 4);

    fill_i32<<<cdiv(N1, 256), 256, 0, stream>>>(cur, 0, N1);
    count_deg<<<cdiv(NE, 256), 256, 0, stream>>>(dst1, nullptr, NE, cur);
    scan_deg<<<1, 1024, 0, stream>>>(N1, cur, row, deg, dinv);
    csr_scatter<<<cdiv(NE, 256), 256, 0, stream>>>(src1, dst1, nullptr, NE, cur, csr);

    aggregate_xb<<<cdiv(N1, 4), 256, 0, stream>>>(row, csr, deg, dinv, xb, aggb, N1);

    conv_transpose_bf16<<<cdiv(CIN * C1, 256), 256, 0, stream>>>(W1, W1t, CIN, C1);
    gemm_bf16_mfma<false><<<dim3(cdiv(N1, 128), C1 / 128), 256, 0, stream>>>(
        aggb, W1t, b1, h1, nullptr, N1, C1, CIN);

    fill_f32<<<1, 64, 0, stream>>>(S, 0.f, 2);
    reduce_sum_sq<<<2048, 256, 0, stream>>>(h1, (size_t)N1 * C1, S);
    norm_relu<<<2048, 256, 0, stream>>>(h1, (size_t)N1 * C1, S, 1.f / ((float)N1 * C1), ln1w, ln1b, C1);

    node_scores<<<cdiv(N1, 4), 256, 0, stream>>>(h1, N1, C1, p1wrel, p1brel, p1wroot, r, score1);
    gather_score<<<cdiv(N1, 256), 256, 0, stream>>>(row, csr, r, score1, N1);

    keyify<<<cdiv(N1, 256), 256, 0, stream>>>(score1, keyu, N1);
    init_sel<<<1, 256, 0, stream>>>(sel, K1, hist);
    for (int pass = 0; pass < 4; ++pass) {
        radix_hist<<<cdiv(N1, 256), 256, 0, stream>>>(keyu, N1, sel, pass, hist);
        radix_scan<<<1, 256, 0, stream>>>(sel, hist, pass);
    }
    sc_partial<<<nb1, 256, 0, stream>>>(keyu, N1, sel, gpart, epart);
    sc_scan_partials<<<1, 64, 0, stream>>>(nb1, gpart, epart);
    sc_final<<<nb1, 256, 0, stream>>>(keyu, N1, sel, gpart, epart, kept, inv);

    pool_apply_bf16<<<4096, 256, 0, stream>>>(h1, score1, kept, inv, N1, C1, h1pb);
    edge_relabel<<<cdiv(NE, 256), 256, 0, stream>>>(src1, dst1, NE, kept, inv, src2, dst2, mask2);

    // ================= Stage 2 =================
    conv_transpose_bf16<<<cdiv(C1 * C2, 256), 256, 0, stream>>>(W2, W2t, C1, C2);
    gemm_bf16_mfma<true><<<dim3(cdiv(K1, 128), C2 / 128), 256, 0, stream>>>(
        h1pb, W2t, nullptr, nullptr, xW2b, K1, C2, C1);

    fill_i32<<<cdiv(K1, 256), 256, 0, stream>>>(cur, 0, K1);
    count_deg<<<cdiv(NE, 256), 256, 0, stream>>>(dst2, mask2, NE, cur);
    scan_deg<<<1, 1024, 0, stream>>>(K1, cur, row, deg, dinv);
    csr_scatter<<<cdiv(NE, 256), 256, 0, stream>>>(src2, dst2, mask2, NE, cur, csr);

    aggregate_csr_bf<<<cdiv(K1, 4), 256, 0, stream>>>(row, csr, deg, dinv, xW2b, b2, h2, K1);

    fill_f32<<<1, 64, 0, stream>>>(S, 0.f, 2);
    reduce_sum_sq<<<2048, 256, 0, stream>>>(h2, (size_t)K1 * C2, S);
    norm_relu<<<2048, 256, 0, stream>>>(h2, (size_t)K1 * C2, S, 1.f / ((float)K1 * C2), ln2w, ln2b, C2);

    node_scores<<<cdiv(K1, 4), 256, 0, stream>>>(h2, K1, C2, p2wrel, p2brel, p2wroot, r, score2);
    gather_score<<<cdiv(K1, 256), 256, 0, stream>>>(row, csr, r, score2, K1);

    keyify<<<cdiv(K1, 256), 256, 0, stream>>>(score2, keyu2, K1);
    init_sel<<<1, 256, 0, stream>>>(sel, K2, hist);
    for (int pass = 0; pass < 4; ++pass) {
        radix_hist<<<cdiv(K1, 256), 256, 0, stream>>>(keyu2, K1, sel, pass, hist);
        radix_scan<<<1, 256, 0, stream>>>(sel, hist, pass);
    }
    sc_partial<<<nb2, 256, 0, stream>>>(keyu2, K1, sel, gpart, epart);
    sc_scan_partials<<<1, 64, 0, stream>>>(nb2, gpart, epart);
    sc_final<<<nb2, 256, 0, stream>>>(keyu2, K1, sel, gpart, epart, kept2, inv2);

    // ================= readout =================
    masked_colmean<<<C2, 256, 0, stream>>>(h2, score2, kept2, K1, C2, 1.f / (float)K2, g);
    final_gemv<<<1, NOUT, 0, stream>>>(g, Wf, bf, out);
}

// Round 5
// 479.223 us; speedup vs baseline: 6.4564x; 1.2390x over previous
//
#include <hip/hip_runtime.h>
#include <math.h>

#define N1 20000
#define NE 320000
#define CIN 256
#define C1 512
#define C2 256
#define K1 10000
#define K2 5000
#define NOUT 128
#define EPSV 1e-5f
#define NB_RED 512

typedef __attribute__((ext_vector_type(8))) short bf16x8;
typedef __attribute__((ext_vector_type(4))) float f32x4;

static inline unsigned cdiv(unsigned a, unsigned b) { return (a + b - 1) / b; }

__device__ inline ushort f2bf(float f) {
    unsigned u = __float_as_uint(f);
    unsigned r = u + 0x7FFFu + ((u >> 16) & 1u);
    return (ushort)(r >> 16);
}
__device__ inline float bf2f(ushort u) { return __uint_as_float(((unsigned)u) << 16); }

// ---------------- fills ----------------
__global__ void fill_i32(int* __restrict__ p, int v, int n) {
    int i = blockIdx.x * blockDim.x + threadIdx.x;
    if (i < n) p[i] = v;
}

// ---------------- f32 -> bf16 (vectorized, n multiple of 4) ----------------
__global__ void f32_to_bf16(const float* __restrict__ in, ushort* __restrict__ out, int n4) {
    int i = blockIdx.x * blockDim.x + threadIdx.x;
    if (i >= n4) return;
    float4 v = reinterpret_cast<const float4*>(in)[i];
    ushort4 o;
    o.x = f2bf(v.x); o.y = f2bf(v.y); o.z = f2bf(v.z); o.w = f2bf(v.w);
    reinterpret_cast<ushort4*>(out)[i] = o;
}

// ---------------- weight convert+transpose: Wt[n][k] = bf16(W[k][n]) ----------------
__global__ void conv_transpose_bf16(const float* __restrict__ W, ushort* __restrict__ Wt,
                                    int K, int N) {
    int i = blockIdx.x * blockDim.x + threadIdx.x;
    if (i >= K * N) return;
    int k = i / N, n = i % N;
    Wt[(size_t)n * K + k] = f2bf(W[i]);
}

// ---------------- MFMA bf16 GEMM ----------------
template <bool BF16OUT>
__global__ __launch_bounds__(256)
void gemm_bf16_mfma(const ushort* __restrict__ A, const ushort* __restrict__ Bt,
                    const float* __restrict__ bias, float* __restrict__ C,
                    ushort* __restrict__ Cb, int M, int N, int K) {
    constexpr int BM = 128, BN = 128, BK = 32;
    constexpr int LDK = BK + 8;
    __shared__ ushort As[BM * LDK];
    __shared__ ushort Bs[BN * LDK];
    int tid = threadIdx.x;
    int wid = tid >> 6, lane = tid & 63;
    int wr = wid >> 1, wc = wid & 1;
    int bm = blockIdx.x * BM, bn = blockIdx.y * BN;
    int lg = lane >> 4, lm = lane & 15;
    f32x4 zero = {0.f, 0.f, 0.f, 0.f};
    f32x4 acc[4][4];
#pragma unroll
    for (int m = 0; m < 4; ++m)
#pragma unroll
        for (int n = 0; n < 4; ++n) acc[m][n] = zero;

    for (int k0 = 0; k0 < K; k0 += BK) {
#pragma unroll
        for (int it = 0; it < 2; ++it) {
            int task = tid * 2 + it;
            int row = task >> 2, c8 = (task & 3) * 8;
            int gm = bm + row;
            bf16x8 v = {0, 0, 0, 0, 0, 0, 0, 0};
            if (gm < M) v = *(const bf16x8*)&A[(size_t)gm * K + k0 + c8];
            *(bf16x8*)&As[row * LDK + c8] = v;
            int gn = bn + row;
            bf16x8 w = {0, 0, 0, 0, 0, 0, 0, 0};
            if (gn < N) w = *(const bf16x8*)&Bt[(size_t)gn * K + k0 + c8];
            *(bf16x8*)&Bs[row * LDK + c8] = w;
        }
        __syncthreads();
        bf16x8 af[4], bfr[4];
#pragma unroll
        for (int m = 0; m < 4; ++m)
            af[m] = *(bf16x8*)&As[(wr * 64 + m * 16 + lm) * LDK + lg * 8];
#pragma unroll
        for (int n = 0; n < 4; ++n)
            bfr[n] = *(bf16x8*)&Bs[(wc * 64 + n * 16 + lm) * LDK + lg * 8];
#pragma unroll
        for (int m = 0; m < 4; ++m)
#pragma unroll
            for (int n = 0; n < 4; ++n)
                acc[m][n] = __builtin_amdgcn_mfma_f32_16x16x32_bf16(af[m], bfr[n], acc[m][n], 0, 0, 0);
        __syncthreads();
    }
#pragma unroll
    for (int m = 0; m < 4; ++m) {
#pragma unroll
        for (int n = 0; n < 4; ++n) {
            int col = bn + wc * 64 + n * 16 + lm;
            float bv = bias ? bias[col] : 0.f;
#pragma unroll
            for (int r = 0; r < 4; ++r) {
                int row = bm + wr * 64 + m * 16 + lg * 4 + r;
                if (row < M) {
                    float val = acc[m][n][r] + bv;
                    if (BF16OUT) Cb[(size_t)row * N + col] = f2bf(val);
                    else         C[(size_t)row * N + col] = val;
                }
            }
        }
    }
}

// ---------------- CSR build ----------------
__global__ void count_deg(const int* __restrict__ dst, const int* __restrict__ mask, int E,
                          int* __restrict__ cnt) {
    int e = blockIdx.x * blockDim.x + threadIdx.x;
    if (e >= E) return;
    if (mask && !mask[e]) return;
    atomicAdd(&cnt[dst[e]], 1);
}

__global__ void scan_deg(int n, int* __restrict__ cursor, int* __restrict__ rowstart,
                         float* __restrict__ deg, float* __restrict__ dinv) {
    __shared__ int buf[1024];
    __shared__ int sbase;
    if (threadIdx.x == 0) sbase = 0;
    __syncthreads();
    for (int start = 0; start < n; start += 1024) {
        int i = start + (int)threadIdx.x;
        int base = sbase;
        int v = (i < n) ? cursor[i] : 0;
        buf[threadIdx.x] = v;
        __syncthreads();
        for (int off = 1; off < 1024; off <<= 1) {
            int add = ((int)threadIdx.x >= off) ? buf[threadIdx.x - off] : 0;
            __syncthreads();
            buf[threadIdx.x] += add;
            __syncthreads();
        }
        int incl = buf[threadIdx.x];
        int excl = incl - v;
        int total = buf[1023];
        if (i < n) {
            rowstart[i] = base + excl;
            cursor[i] = base + excl;
            float dg = (float)v + 2.0f;
            deg[i] = dg;
            dinv[i] = rsqrtf(dg);
        }
        __syncthreads();
        if (threadIdx.x == 0) sbase = base + total;
        __syncthreads();
    }
    if (threadIdx.x == 0) rowstart[n] = sbase;
}

__global__ void csr_scatter(const int* __restrict__ src, const int* __restrict__ dst,
                            const int* __restrict__ mask, int E,
                            int* __restrict__ cursor, int* __restrict__ csr_src) {
    int e = blockIdx.x * blockDim.x + threadIdx.x;
    if (e >= E) return;
    if (mask && !mask[e]) return;
    int pos = atomicAdd(&cursor[dst[e]], 1);
    csr_src[pos] = src[e];
}

// ---------------- stage-1 aggregation on bf16 x (C=256), bf16 out ----------------
__global__ void aggregate_xb(const int* __restrict__ rowstart, const int* __restrict__ csr_src,
                             const float* __restrict__ deg, const float* __restrict__ dinv,
                             const ushort* __restrict__ xb, ushort* __restrict__ out, int n) {
    int node = blockIdx.x * (blockDim.x >> 6) + ((int)threadIdx.x >> 6);
    if (node >= n) return;
    int lane = threadIdx.x & 63;
    int beg = rowstart[node], end = rowstart[node + 1];
    float di = dinv[node];
    float4 acc = make_float4(0.f, 0.f, 0.f, 0.f);
    for (int j = beg; j < end; ++j) {
        int s = csr_src[j];
        float coef = dinv[s] * di;
        ushort4 t = reinterpret_cast<const ushort4*>(&xb[(size_t)s * CIN])[lane];
        acc.x += coef * bf2f(t.x);
        acc.y += coef * bf2f(t.y);
        acc.z += coef * bf2f(t.z);
        acc.w += coef * bf2f(t.w);
    }
    float self = 2.0f / deg[node];
    ushort4 t = reinterpret_cast<const ushort4*>(&xb[(size_t)node * CIN])[lane];
    acc.x += self * bf2f(t.x);
    acc.y += self * bf2f(t.y);
    acc.z += self * bf2f(t.z);
    acc.w += self * bf2f(t.w);
    ushort4 o;
    o.x = f2bf(acc.x); o.y = f2bf(acc.y); o.z = f2bf(acc.z); o.w = f2bf(acc.w);
    reinterpret_cast<ushort4*>(&out[(size_t)node * CIN])[lane] = o;
}

// ---------------- stage-2 aggregation on bf16 xW (C=256), f32 out + bias + self ----------------
__global__ void aggregate_csr_bf(const int* __restrict__ rowstart, const int* __restrict__ csr_src,
                                 const float* __restrict__ deg, const float* __restrict__ dinv,
                                 const ushort* __restrict__ xWb, const float* __restrict__ b,
                                 float* __restrict__ out, int n) {
    int node = blockIdx.x * (blockDim.x >> 6) + ((int)threadIdx.x >> 6);
    if (node >= n) return;
    int lane = threadIdx.x & 63;
    int beg = rowstart[node], end = rowstart[node + 1];
    float di = dinv[node];
    float4 acc = make_float4(0.f, 0.f, 0.f, 0.f);
    for (int j = beg; j < end; ++j) {
        int s = csr_src[j];
        float coef = dinv[s] * di;
        ushort4 t = reinterpret_cast<const ushort4*>(&xWb[(size_t)s * C2])[lane];
        acc.x += coef * bf2f(t.x);
        acc.y += coef * bf2f(t.y);
        acc.z += coef * bf2f(t.z);
        acc.w += coef * bf2f(t.w);
    }
    float self = 2.0f / deg[node];
    ushort4 t = reinterpret_cast<const ushort4*>(&xWb[(size_t)node * C2])[lane];
    float4 bb = reinterpret_cast<const float4*>(b)[lane];
    float4 o;
    o.x = acc.x + self * bf2f(t.x) + bb.x;
    o.y = acc.y + self * bf2f(t.y) + bb.y;
    o.z = acc.z + self * bf2f(t.z) + bb.z;
    o.w = acc.w + self * bf2f(t.w) + bb.w;
    reinterpret_cast<float4*>(&out[(size_t)node * C2])[lane] = o;
}

// ---------------- graph-norm: two-stage sum & sumsq (no same-address atomics) ----------------
__global__ void reduce_sum_sq_part(const float* __restrict__ x, int n4, float* __restrict__ Sp) {
    float s = 0.f, q = 0.f;
    const float4* x4 = reinterpret_cast<const float4*>(x);
    for (int i = blockIdx.x * blockDim.x + threadIdx.x; i < n4; i += gridDim.x * blockDim.x) {
        float4 v = x4[i];
        s += v.x + v.y + v.z + v.w;
        q += v.x * v.x + v.y * v.y + v.z * v.z + v.w * v.w;
    }
    __shared__ float ls[256], lq[256];
    ls[threadIdx.x] = s; lq[threadIdx.x] = q;
    __syncthreads();
    for (int off = 128; off > 0; off >>= 1) {
        if ((int)threadIdx.x < off) {
            ls[threadIdx.x] += ls[threadIdx.x + off];
            lq[threadIdx.x] += lq[threadIdx.x + off];
        }
        __syncthreads();
    }
    if (threadIdx.x == 0) {
        Sp[2 * blockIdx.x] = ls[0];
        Sp[2 * blockIdx.x + 1] = lq[0];
    }
}

__global__ void reduce_final(const float* __restrict__ Sp, int nb, float* __restrict__ S) {
    float s = 0.f, q = 0.f;
    for (int i = threadIdx.x; i < nb; i += 256) {
        s += Sp[2 * i];
        q += Sp[2 * i + 1];
    }
    __shared__ float ls[256], lq[256];
    ls[threadIdx.x] = s; lq[threadIdx.x] = q;
    __syncthreads();
    for (int off = 128; off > 0; off >>= 1) {
        if ((int)threadIdx.x < off) {
            ls[threadIdx.x] += ls[threadIdx.x + off];
            lq[threadIdx.x] += lq[threadIdx.x + off];
        }
        __syncthreads();
    }
    if (threadIdx.x == 0) { S[0] = ls[0]; S[1] = lq[0]; }
}

// ---------------- fused norm+relu+scores: one pass over h ----------------
// h[i,:] = relu((h-mean)*istd*lnw+lnb); r[i]=h.wrel; score[i]=h.wroot+brel
template <int C>
__global__ void norm_scores(float* __restrict__ h, int n, const float* __restrict__ S,
                            float inv_cnt, const float* __restrict__ lnw,
                            const float* __restrict__ lnb, const float* __restrict__ wrel,
                            const float* __restrict__ brel, const float* __restrict__ wroot,
                            float* __restrict__ r, float* __restrict__ score) {
    int node = blockIdx.x * (blockDim.x >> 6) + ((int)threadIdx.x >> 6);
    if (node >= n) return;
    int lane = threadIdx.x & 63;
    float mean = S[0] * inv_cnt;
    float var = S[1] * inv_cnt - mean * mean;
    float istd = 1.f / (sqrtf(fmaxf(var, 0.f)) + EPSV);
    float4* row = reinterpret_cast<float4*>(&h[(size_t)node * C]);
    float sr = 0.f, st = 0.f;
#pragma unroll
    for (int kk = 0; kk < C / 256; ++kk) {
        int idx = lane + 64 * kk;
        float4 v = row[idx];
        float4 w = reinterpret_cast<const float4*>(lnw)[idx];
        float4 bb = reinterpret_cast<const float4*>(lnb)[idx];
        float4 w4 = reinterpret_cast<const float4*>(wrel)[idx];
        float4 o4 = reinterpret_cast<const float4*>(wroot)[idx];
        v.x = fmaxf((v.x - mean) * istd * w.x + bb.x, 0.f);
        v.y = fmaxf((v.y - mean) * istd * w.y + bb.y, 0.f);
        v.z = fmaxf((v.z - mean) * istd * w.z + bb.z, 0.f);
        v.w = fmaxf((v.w - mean) * istd * w.w + bb.w, 0.f);
        sr += v.x * w4.x + v.y * w4.y + v.z * w4.z + v.w * w4.w;
        st += v.x * o4.x + v.y * o4.y + v.z * o4.z + v.w * o4.w;
        row[idx] = v;
    }
    for (int off = 32; off > 0; off >>= 1) {
        sr += __shfl_down(sr, off);
        st += __shfl_down(st, off);
    }
    if (lane == 0) {
        r[node] = sr;
        score[node] = st + brel[0];
    }
}

// ---------------- gather score over CSR + keyify ----------------
__global__ void gather_score_key(const int* __restrict__ rowstart, const int* __restrict__ csr_src,
                                 const float* __restrict__ r, float* __restrict__ score,
                                 unsigned* __restrict__ key, int n) {
    int i = blockIdx.x * blockDim.x + threadIdx.x;
    if (i >= n) return;
    float s = score[i];
    int beg = rowstart[i], end = rowstart[i + 1];
    for (int j = beg; j < end; ++j) s += r[csr_src[j]];
    score[i] = s;
    unsigned u = __float_as_uint(s);
    key[i] = (u & 0x80000000u) ? ~u : (u | 0x80000000u);
}

// ---------------- single-kernel radix select (n small; keys L2-resident) ----------------
__global__ void radix_select(const unsigned* __restrict__ key, int n, unsigned k,
                             unsigned* __restrict__ sel) {
    __shared__ unsigned hist[256];
    __shared__ unsigned spref, srem;
    if (threadIdx.x == 0) { spref = 0u; srem = k; }
#pragma unroll
    for (int pass = 0; pass < 4; ++pass) {
        if (threadIdx.x < 256) hist[threadIdx.x] = 0u;
        __syncthreads();
        unsigned pref = spref;
        unsigned msk = pass ? (0xFFFFFFFFu << (32 - 8 * pass)) : 0u;
        int shift = 24 - 8 * pass;
        for (int i = threadIdx.x; i < n; i += blockDim.x) {
            unsigned u = key[i];
            if (((u ^ pref) & msk) == 0u) atomicAdd(&hist[(u >> shift) & 255u], 1u);
        }
        __syncthreads();
        if (threadIdx.x == 0) {
            unsigned rem = srem, cum = 0u;
            int b = 0;
            for (int bb = 255; bb >= 0; --bb) {
                unsigned h = hist[bb];
                if (cum + h >= rem) { b = bb; break; }
                cum += h;
            }
            spref = pref | ((unsigned)b << shift);
            srem = rem - cum;
        }
        __syncthreads();
    }
    if (threadIdx.x == 0) { sel[0] = spref; sel[1] = srem; }
}

// ---------------- multi-block deterministic select + compact ----------------
__global__ void sc_partial(const unsigned* __restrict__ key, int n, const unsigned* __restrict__ sel,
                           int* __restrict__ gpart, int* __restrict__ epart) {
    unsigned thr = sel[0];
    int base = blockIdx.x * 1024 + (int)threadIdx.x * 4;
    int gs = 0, es = 0;
#pragma unroll
    for (int t = 0; t < 4; ++t) {
        int i = base + t;
        if (i < n) {
            unsigned u = key[i];
            gs += (u > thr); es += (u == thr);
        }
    }
    for (int off = 32; off > 0; off >>= 1) {
        gs += __shfl_down(gs, off);
        es += __shfl_down(es, off);
    }
    __shared__ int sg[4], se[4];
    int wid = threadIdx.x >> 6;
    if ((threadIdx.x & 63) == 0) { sg[wid] = gs; se[wid] = es; }
    __syncthreads();
    if (threadIdx.x == 0) {
        gpart[blockIdx.x] = sg[0] + sg[1] + sg[2] + sg[3];
        epart[blockIdx.x] = se[0] + se[1] + se[2] + se[3];
    }
}

__global__ void sc_scan_partials(int nb, int* __restrict__ gpart, int* __restrict__ epart) {
    int lane = threadIdx.x;
    int g0 = (lane < nb) ? gpart[lane] : 0;
    int e0 = (lane < nb) ? epart[lane] : 0;
    int g = g0, e = e0;
    for (int off = 1; off < 64; off <<= 1) {
        int gg = __shfl_up(g, off), ee = __shfl_up(e, off);
        if (lane >= off) { g += gg; e += ee; }
    }
    if (lane < nb) { gpart[lane] = g - g0; epart[lane] = e - e0; }
}

__global__ void sc_final(const unsigned* __restrict__ key, int n, const unsigned* __restrict__ sel,
                         const int* __restrict__ gpart, const int* __restrict__ epart,
                         int* __restrict__ kept, int* __restrict__ inv) {
    unsigned thr = sel[0];
    int tie = (int)sel[1];
    int base = blockIdx.x * 1024 + (int)threadIdx.x * 4;
    int gl[4], el[4];
    int gs = 0, es = 0;
#pragma unroll
    for (int t = 0; t < 4; ++t) {
        int i = base + t;
        gl[t] = 0; el[t] = 0;
        if (i < n) {
            unsigned u = key[i];
            gl[t] = (u > thr); el[t] = (u == thr);
        }
        gs += gl[t]; es += el[t];
    }
    int lane = threadIdx.x & 63, wid = threadIdx.x >> 6;
    int gi = gs, ei = es;
    for (int off = 1; off < 64; off <<= 1) {
        int gg = __shfl_up(gi, off), ee = __shfl_up(ei, off);
        if (lane >= off) { gi += gg; ei += ee; }
    }
    __shared__ int wg[4], we[4];
    if (lane == 63) { wg[wid] = gi; we[wid] = ei; }
    __syncthreads();
    int wgo = 0, weo = 0;
    for (int w = 0; w < wid; ++w) { wgo += wg[w]; weo += we[w]; }
    int gp = gpart[blockIdx.x] + (gi - gs) + wgo;
    int ep = epart[blockIdx.x] + (ei - es) + weo;
#pragma unroll
    for (int t = 0; t < 4; ++t) {
        int i = base + t;
        if (i < n) {
            int keep = gl[t] | (el[t] & ((ep < tie) ? 1 : 0));
            kept[i] = keep;
            inv[i] = gp + ((ep < tie) ? ep : tie);
        }
        gp += gl[t]; ep += el[t];
    }
}

// ---------------- pool apply (bf16 out) ----------------
__global__ void pool_apply_bf16(const float* __restrict__ h, const float* __restrict__ score,
                                const int* __restrict__ kept, const int* __restrict__ inv,
                                int n, int C, ushort* __restrict__ hp) {
    size_t total = (size_t)n * C;
    for (size_t i = blockIdx.x * (size_t)blockDim.x + threadIdx.x; i < total;
         i += (size_t)gridDim.x * blockDim.x) {
        int row = (int)(i / C);
        if (!kept[row]) continue;
        int c = (int)(i & (C - 1));
        hp[(size_t)inv[row] * C + c] = f2bf(h[i] * tanhf(score[row]));
    }
}

// ---------------- edge relabel ----------------
__global__ void edge_relabel(const int* __restrict__ src, const int* __restrict__ dst, int E,
                             const int* __restrict__ kept, const int* __restrict__ inv,
                             int* __restrict__ src2, int* __restrict__ dst2,
                             int* __restrict__ mask2) {
    int e = blockIdx.x * blockDim.x + threadIdx.x;
    if (e >= E) return;
    int s = src[e], d = dst[e];
    int m = kept[s] & kept[d];
    mask2[e] = m;
    src2[e] = m ? inv[s] : 0;
    dst2[e] = m ? inv[d] : 0;
}

// ---------------- masked weighted column mean ----------------
__global__ void masked_colmean(const float* __restrict__ h, const float* __restrict__ score,
                               const int* __restrict__ kept, int n, int C, float invk,
                               float* __restrict__ g) {
    int c = blockIdx.x;
    float s = 0.f;
    for (int i = threadIdx.x; i < n; i += blockDim.x)
        if (kept[i]) s += tanhf(score[i]) * h[(size_t)i * C + c];
    __shared__ float ls[256];
    ls[threadIdx.x] = s;
    __syncthreads();
    for (int off = 128; off > 0; off >>= 1) {
        if ((int)threadIdx.x < off) ls[threadIdx.x] += ls[threadIdx.x + off];
        __syncthreads();
    }
    if (threadIdx.x == 0) g[c] = ls[0] * invk;
}

__global__ void final_gemv(const float* __restrict__ g, const float* __restrict__ Wf,
                           const float* __restrict__ bf, float* __restrict__ out) {
    int j = threadIdx.x;  // 128
    float s = bf[j];
    for (int c = 0; c < 256; ++c) s += g[c] * Wf[c * NOUT + j];
    out[j] = s;
}

// =======================================================================================
extern "C" void kernel_launch(void* const* d_in, const int* in_sizes, int n_in,
                              void* d_out, int out_size, void* d_ws, size_t ws_size,
                              hipStream_t stream) {
    const float* x      = (const float*)d_in[0];
    const int*   ei     = (const int*)d_in[1];
    const float* W1     = (const float*)d_in[2];
    const float* b1     = (const float*)d_in[3];
    const float* ln1w   = (const float*)d_in[4];
    const float* ln1b   = (const float*)d_in[5];
    const float* p1wrel = (const float*)d_in[6];
    const float* p1brel = (const float*)d_in[7];
    const float* p1wroot= (const float*)d_in[8];
    const float* W2     = (const float*)d_in[9];
    const float* b2     = (const float*)d_in[10];
    const float* ln2w   = (const float*)d_in[11];
    const float* ln2b   = (const float*)d_in[12];
    const float* p2wrel = (const float*)d_in[13];
    const float* p2brel = (const float*)d_in[14];
    const float* p2wroot= (const float*)d_in[15];
    const float* Wf     = (const float*)d_in[16];
    const float* bf     = (const float*)d_in[17];
    float* out = (float*)d_out;
    char* ws = (char*)d_ws;

    const int* src1 = ei;
    const int* dst1 = ei + NE;

    // ---- workspace layout (bytes) ----
    const size_t o0     = 0;          // 40.96 MB: h1 f32; later h2 f32 @+0, xW2b bf16 @+10,240,000
    const size_t o1     = 40960000;   // 10.24 MB: aggb bf16; later h1pb bf16
    const size_t oXb    = 51200000;   // 10,240,000 : xb bf16
    const size_t oW1t   = 61440000;   // 262,144
    const size_t oW2t   = 61702144;   // 262,144
    const size_t oSrc2  = 61964288;   // 1,280,000
    const size_t oDst2  = 63244288;
    const size_t oMask2 = 64524288;
    const size_t oCsr   = 65804288;   // 1,280,000
    const size_t oRow   = 67084288;   // 80,064
    const size_t oCur   = 67164352;   // 80,000
    const size_t oDeg   = 67244352;
    const size_t oDinv  = 67324352;
    const size_t oR     = 67404352;
    const size_t oScore1= 67484352;
    const size_t oKeyu  = 67564352;
    const size_t oKept  = 67644352;
    const size_t oInv   = 67724352;
    const size_t oScore2= 67804352;   // 40,000
    const size_t oKeyu2 = 67844352;
    const size_t oKept2 = 67884352;
    const size_t oInv2  = 67924352;
    const size_t oS     = 67964352;   // 64
    const size_t oSel   = 67964416;   // 64
    const size_t oGpart = 67964480;   // 256
    const size_t oEpart = 67964736;   // 256
    const size_t oG     = 67964992;   // 1,024
    const size_t oSp    = 67966016;   // 4,096 : reduction partials

    float*  h1    = (float*)(ws + o0);
    float*  h2    = (float*)(ws + o0);
    ushort* xW2b  = (ushort*)(ws + o0 + 10240000);
    ushort* aggb  = (ushort*)(ws + o1);
    ushort* h1pb  = (ushort*)(ws + o1);
    ushort* xb    = (ushort*)(ws + oXb);
    ushort* W1t   = (ushort*)(ws + oW1t);
    ushort* W2t   = (ushort*)(ws + oW2t);
    int*    src2  = (int*)(ws + oSrc2);
    int*    dst2  = (int*)(ws + oDst2);
    int*    mask2 = (int*)(ws + oMask2);
    int*    csr   = (int*)(ws + oCsr);
    int*    row   = (int*)(ws + oRow);
    int*    cur   = (int*)(ws + oCur);
    float*  deg   = (float*)(ws + oDeg);
    float*  dinv  = (float*)(ws + oDinv);
    float*  r     = (float*)(ws + oR);
    float*  score1= (float*)(ws + oScore1);
    unsigned* keyu  = (unsigned*)(ws + oKeyu);
    int*    kept  = (int*)(ws + oKept);
    int*    inv   = (int*)(ws + oInv);
    float*  score2= (float*)(ws + oScore2);
    unsigned* keyu2 = (unsigned*)(ws + oKeyu2);
    int*    kept2 = (int*)(ws + oKept2);
    int*    inv2  = (int*)(ws + oInv2);
    float*  S     = (float*)(ws + oS);
    unsigned* sel  = (unsigned*)(ws + oSel);
    int*    gpart = (int*)(ws + oGpart);
    int*    epart = (int*)(ws + oEpart);
    float*  g     = (float*)(ws + oG);
    float*  Sp    = (float*)(ws + oSp);

    const int nb1 = cdiv(N1, 1024);  // 20
    const int nb2 = cdiv(K1, 1024);  // 10

    // ================= Stage 1 =================
    f32_to_bf16<<<cdiv(N1 * CIN / 4, 256), 256, 0, stream>>>(x, xb, N1 * CIN / 4);

    fill_i32<<<cdiv(N1, 256), 256, 0, stream>>>(cur, 0, N1);
    count_deg<<<cdiv(NE, 256), 256, 0, stream>>>(dst1, nullptr, NE, cur);
    scan_deg<<<1, 1024, 0, stream>>>(N1, cur, row, deg, dinv);
    csr_scatter<<<cdiv(NE, 256), 256, 0, stream>>>(src1, dst1, nullptr, NE, cur, csr);

    aggregate_xb<<<cdiv(N1, 4), 256, 0, stream>>>(row, csr, deg, dinv, xb, aggb, N1);

    conv_transpose_bf16<<<cdiv(CIN * C1, 256), 256, 0, stream>>>(W1, W1t, CIN, C1);
    gemm_bf16_mfma<false><<<dim3(cdiv(N1, 128), C1 / 128), 256, 0, stream>>>(
        aggb, W1t, b1, h1, nullptr, N1, C1, CIN);

    reduce_sum_sq_part<<<NB_RED, 256, 0, stream>>>(h1, N1 * C1 / 4, Sp);
    reduce_final<<<1, 256, 0, stream>>>(Sp, NB_RED, S);
    norm_scores<C1><<<cdiv(N1, 4), 256, 0, stream>>>(h1, N1, S, 1.f / ((float)N1 * C1),
                                                     ln1w, ln1b, p1wrel, p1brel, p1wroot, r, score1);
    gather_score_key<<<cdiv(N1, 256), 256, 0, stream>>>(row, csr, r, score1, keyu, N1);

    radix_select<<<1, 1024, 0, stream>>>(keyu, N1, K1, sel);
    sc_partial<<<nb1, 256, 0, stream>>>(keyu, N1, sel, gpart, epart);
    sc_scan_partials<<<1, 64, 0, stream>>>(nb1, gpart, epart);
    sc_final<<<nb1, 256, 0, stream>>>(keyu, N1, sel, gpart, epart, kept, inv);

    pool_apply_bf16<<<4096, 256, 0, stream>>>(h1, score1, kept, inv, N1, C1, h1pb);
    edge_relabel<<<cdiv(NE, 256), 256, 0, stream>>>(src1, dst1, NE, kept, inv, src2, dst2, mask2);

    // ================= Stage 2 =================
    conv_transpose_bf16<<<cdiv(C1 * C2, 256), 256, 0, stream>>>(W2, W2t, C1, C2);
    gemm_bf16_mfma<true><<<dim3(cdiv(K1, 128), C2 / 128), 256, 0, stream>>>(
        h1pb, W2t, nullptr, nullptr, xW2b, K1, C2, C1);

    fill_i32<<<cdiv(K1, 256), 256, 0, stream>>>(cur, 0, K1);
    count_deg<<<cdiv(NE, 256), 256, 0, stream>>>(dst2, mask2, NE, cur);
    scan_deg<<<1, 1024, 0, stream>>>(K1, cur, row, deg, dinv);
    csr_scatter<<<cdiv(NE, 256), 256, 0, stream>>>(src2, dst2, mask2, NE, cur, csr);

    aggregate_csr_bf<<<cdiv(K1, 4), 256, 0, stream>>>(row, csr, deg, dinv, xW2b, b2, h2, K1);

    reduce_sum_sq_part<<<NB_RED, 256, 0, stream>>>(h2, K1 * C2 / 4, Sp);
    reduce_final<<<1, 256, 0, stream>>>(Sp, NB_RED, S);
    norm_scores<C2><<<cdiv(K1, 4), 256, 0, stream>>>(h2, K1, S, 1.f / ((float)K1 * C2),
                                                     ln2w, ln2b, p2wrel, p2brel, p2wroot, r, score2);
    gather_score_key<<<cdiv(K1, 256), 256, 0, stream>>>(row, csr, r, score2, keyu2, K1);

    radix_select<<<1, 1024, 0, stream>>>(keyu2, K1, K2, sel);
    sc_partial<<<nb2, 256, 0, stream>>>(keyu2, K1, sel, gpart, epart);
    sc_scan_partials<<<1, 64, 0, stream>>>(nb2, gpart, epart);
    sc_final<<<nb2, 256, 0, stream>>>(keyu2, K1, sel, gpart, epart, kept2, inv2);

    // ================= readout =================
    masked_colmean<<<C2, 256, 0, stream>>>(h2, score2, kept2, K1, C2, 1.f / (float)K2, g);
    final_gemv<<<1, NOUT, 0, stream>>>(g, Wf, bf, out);
}

// Round 6
// 455.900 us; speedup vs baseline: 6.7866x; 1.0512x over previous
//
#include <hip/hip_runtime.h>
#include <math.h>

#define N1 20000
#define NE 320000
#define CIN 256
#define C1 512
#define C2 256
#define K1 10000
#define K2 5000
#define NOUT 128
#define EPSV 1e-5f
#define NB_RED 512

typedef __attribute__((ext_vector_type(8))) short bf16x8;
typedef __attribute__((ext_vector_type(4))) float f32x4;

static inline unsigned cdiv(unsigned a, unsigned b) { return (a + b - 1) / b; }

__device__ inline ushort f2bf(float f) {
    unsigned u = __float_as_uint(f);
    unsigned r = u + 0x7FFFu + ((u >> 16) & 1u);
    return (ushort)(r >> 16);
}
__device__ inline float bf2f(ushort u) { return __uint_as_float(((unsigned)u) << 16); }

// ---------------- fills ----------------
__global__ void fill_i32(int* __restrict__ p, int v, int n) {
    int i = blockIdx.x * blockDim.x + threadIdx.x;
    if (i < n) p[i] = v;
}
__global__ void fill_f32(float* __restrict__ p, float v, int n) {
    int i = blockIdx.x * blockDim.x + threadIdx.x;
    if (i < n) p[i] = v;
}

// ---------------- f32 -> bf16 ----------------
__global__ void f32_to_bf16(const float* __restrict__ in, ushort* __restrict__ out, int n4) {
    int i = blockIdx.x * blockDim.x + threadIdx.x;
    if (i >= n4) return;
    float4 v = reinterpret_cast<const float4*>(in)[i];
    ushort4 o;
    o.x = f2bf(v.x); o.y = f2bf(v.y); o.z = f2bf(v.z); o.w = f2bf(v.w);
    reinterpret_cast<ushort4*>(out)[i] = o;
}

// ---------------- weight convert+transpose ----------------
__global__ void conv_transpose_bf16(const float* __restrict__ W, ushort* __restrict__ Wt,
                                    int K, int N) {
    int i = blockIdx.x * blockDim.x + threadIdx.x;
    if (i >= K * N) return;
    int k = i / N, n = i % N;
    Wt[(size_t)n * K + k] = f2bf(W[i]);
}

// ---------------- MFMA bf16 GEMM ----------------
template <bool BF16OUT>
__global__ __launch_bounds__(256)
void gemm_bf16_mfma(const ushort* __restrict__ A, const ushort* __restrict__ Bt,
                    const float* __restrict__ bias, float* __restrict__ C,
                    ushort* __restrict__ Cb, int M, int N, int K) {
    constexpr int BM = 128, BN = 128, BK = 32;
    constexpr int LDK = BK + 8;
    __shared__ ushort As[BM * LDK];
    __shared__ ushort Bs[BN * LDK];
    int tid = threadIdx.x;
    int wid = tid >> 6, lane = tid & 63;
    int wr = wid >> 1, wc = wid & 1;
    int bm = blockIdx.x * BM, bn = blockIdx.y * BN;
    int lg = lane >> 4, lm = lane & 15;
    f32x4 zero = {0.f, 0.f, 0.f, 0.f};
    f32x4 acc[4][4];
#pragma unroll
    for (int m = 0; m < 4; ++m)
#pragma unroll
        for (int n = 0; n < 4; ++n) acc[m][n] = zero;

    for (int k0 = 0; k0 < K; k0 += BK) {
#pragma unroll
        for (int it = 0; it < 2; ++it) {
            int task = tid * 2 + it;
            int row = task >> 2, c8 = (task & 3) * 8;
            int gm = bm + row;
            bf16x8 v = {0, 0, 0, 0, 0, 0, 0, 0};
            if (gm < M) v = *(const bf16x8*)&A[(size_t)gm * K + k0 + c8];
            *(bf16x8*)&As[row * LDK + c8] = v;
            int gn = bn + row;
            bf16x8 w = {0, 0, 0, 0, 0, 0, 0, 0};
            if (gn < N) w = *(const bf16x8*)&Bt[(size_t)gn * K + k0 + c8];
            *(bf16x8*)&Bs[row * LDK + c8] = w;
        }
        __syncthreads();
        bf16x8 af[4], bfr[4];
#pragma unroll
        for (int m = 0; m < 4; ++m)
            af[m] = *(bf16x8*)&As[(wr * 64 + m * 16 + lm) * LDK + lg * 8];
#pragma unroll
        for (int n = 0; n < 4; ++n)
            bfr[n] = *(bf16x8*)&Bs[(wc * 64 + n * 16 + lm) * LDK + lg * 8];
#pragma unroll
        for (int m = 0; m < 4; ++m)
#pragma unroll
            for (int n = 0; n < 4; ++n)
                acc[m][n] = __builtin_amdgcn_mfma_f32_16x16x32_bf16(af[m], bfr[n], acc[m][n], 0, 0, 0);
        __syncthreads();
    }
#pragma unroll
    for (int m = 0; m < 4; ++m) {
#pragma unroll
        for (int n = 0; n < 4; ++n) {
            int col = bn + wc * 64 + n * 16 + lm;
            float bv = bias ? bias[col] : 0.f;
#pragma unroll
            for (int r = 0; r < 4; ++r) {
                int row = bm + wr * 64 + m * 16 + lg * 4 + r;
                if (row < M) {
                    float val = acc[m][n][r] + bv;
                    if (BF16OUT) Cb[(size_t)row * N + col] = f2bf(val);
                    else         C[(size_t)row * N + col] = val;
                }
            }
        }
    }
}

// ---------------- CSR build ----------------
__global__ void count_deg(const int* __restrict__ dst, const int* __restrict__ mask, int E,
                          int* __restrict__ cnt) {
    int e = blockIdx.x * blockDim.x + threadIdx.x;
    if (e >= E) return;
    if (mask && !mask[e]) return;
    atomicAdd(&cnt[dst[e]], 1);
}

// --- multi-block exclusive scan of counts: dp_partial -> scan64k -> dp_final ---
__global__ void dp_partial(const int* __restrict__ cnt, int n, int* __restrict__ part) {
    int base = blockIdx.x * 1024 + (int)threadIdx.x * 4;
    int s = 0;
#pragma unroll
    for (int t = 0; t < 4; ++t) {
        int i = base + t;
        if (i < n) s += cnt[i];
    }
    for (int off = 32; off > 0; off >>= 1) s += __shfl_down(s, off);
    __shared__ int sg[4];
    int wid = threadIdx.x >> 6;
    if ((threadIdx.x & 63) == 0) sg[wid] = s;
    __syncthreads();
    if (threadIdx.x == 0) part[blockIdx.x] = sg[0] + sg[1] + sg[2] + sg[3];
}

__global__ void scan64k(int nb, int* __restrict__ part, int* __restrict__ row_n) {
    int lane = threadIdx.x;  // one wave, nb <= 64
    int v0 = (lane < nb) ? part[lane] : 0;
    int v = v0;
    for (int off = 1; off < 64; off <<= 1) {
        int vv = __shfl_up(v, off);
        if (lane >= off) v += vv;
    }
    if (lane == nb - 1) row_n[0] = v;  // total edges
    if (lane < nb) part[lane] = v - v0;  // exclusive
}

__global__ void dp_final(const int* __restrict__ cnt, int n, const int* __restrict__ part,
                         int* __restrict__ rowstart, int* __restrict__ cursor,
                         float* __restrict__ deg, float* __restrict__ dinv) {
    int base = blockIdx.x * 1024 + (int)threadIdx.x * 4;
    int c[4];
    int s = 0;
#pragma unroll
    for (int t = 0; t < 4; ++t) {
        int i = base + t;
        c[t] = (i < n) ? cnt[i] : 0;
        s += c[t];
    }
    int lane = threadIdx.x & 63, wid = threadIdx.x >> 6;
    int si = s;
    for (int off = 1; off < 64; off <<= 1) {
        int vv = __shfl_up(si, off);
        if (lane >= off) si += vv;
    }
    __shared__ int wg[4];
    if (lane == 63) wg[wid] = si;
    __syncthreads();
    int woff = 0;
    for (int w = 0; w < wid; ++w) woff += wg[w];
    int excl = part[blockIdx.x] + (si - s) + woff;
#pragma unroll
    for (int t = 0; t < 4; ++t) {
        int i = base + t;
        if (i < n) {
            rowstart[i] = excl;
            cursor[i] = excl;
            float dg = (float)c[t] + 2.0f;
            deg[i] = dg;
            dinv[i] = rsqrtf(dg);
        }
        excl += c[t];
    }
}

__global__ void csr_scatter(const int* __restrict__ src, const int* __restrict__ dst,
                            const int* __restrict__ mask, int E,
                            int* __restrict__ cursor, int* __restrict__ csr_src) {
    int e = blockIdx.x * blockDim.x + threadIdx.x;
    if (e >= E) return;
    if (mask && !mask[e]) return;
    int pos = atomicAdd(&cursor[dst[e]], 1);
    csr_src[pos] = src[e];
}

// ---------------- stage-1 aggregation on bf16 x (C=256), bf16 out ----------------
__global__ void aggregate_xb(const int* __restrict__ rowstart, const int* __restrict__ csr_src,
                             const float* __restrict__ deg, const float* __restrict__ dinv,
                             const ushort* __restrict__ xb, ushort* __restrict__ out, int n) {
    int node = blockIdx.x * (blockDim.x >> 6) + ((int)threadIdx.x >> 6);
    if (node >= n) return;
    int lane = threadIdx.x & 63;
    int beg = rowstart[node], end = rowstart[node + 1];
    float di = dinv[node];
    float4 acc = make_float4(0.f, 0.f, 0.f, 0.f);
    for (int j = beg; j < end; ++j) {
        int s = csr_src[j];
        float coef = dinv[s] * di;
        ushort4 t = reinterpret_cast<const ushort4*>(&xb[(size_t)s * CIN])[lane];
        acc.x += coef * bf2f(t.x);
        acc.y += coef * bf2f(t.y);
        acc.z += coef * bf2f(t.z);
        acc.w += coef * bf2f(t.w);
    }
    float self = 2.0f / deg[node];
    ushort4 t = reinterpret_cast<const ushort4*>(&xb[(size_t)node * CIN])[lane];
    acc.x += self * bf2f(t.x);
    acc.y += self * bf2f(t.y);
    acc.z += self * bf2f(t.z);
    acc.w += self * bf2f(t.w);
    ushort4 o;
    o.x = f2bf(acc.x); o.y = f2bf(acc.y); o.z = f2bf(acc.z); o.w = f2bf(acc.w);
    reinterpret_cast<ushort4*>(&out[(size_t)node * CIN])[lane] = o;
}

// ---------------- stage-2 aggregation on bf16 xW (C=256), f32 out + bias + self ----------------
__global__ void aggregate_csr_bf(const int* __restrict__ rowstart, const int* __restrict__ csr_src,
                                 const float* __restrict__ deg, const float* __restrict__ dinv,
                                 const ushort* __restrict__ xWb, const float* __restrict__ b,
                                 float* __restrict__ out, int n) {
    int node = blockIdx.x * (blockDim.x >> 6) + ((int)threadIdx.x >> 6);
    if (node >= n) return;
    int lane = threadIdx.x & 63;
    int beg = rowstart[node], end = rowstart[node + 1];
    float di = dinv[node];
    float4 acc = make_float4(0.f, 0.f, 0.f, 0.f);
    for (int j = beg; j < end; ++j) {
        int s = csr_src[j];
        float coef = dinv[s] * di;
        ushort4 t = reinterpret_cast<const ushort4*>(&xWb[(size_t)s * C2])[lane];
        acc.x += coef * bf2f(t.x);
        acc.y += coef * bf2f(t.y);
        acc.z += coef * bf2f(t.z);
        acc.w += coef * bf2f(t.w);
    }
    float self = 2.0f / deg[node];
    ushort4 t = reinterpret_cast<const ushort4*>(&xWb[(size_t)node * C2])[lane];
    float4 bb = reinterpret_cast<const float4*>(b)[lane];
    float4 o;
    o.x = acc.x + self * bf2f(t.x) + bb.x;
    o.y = acc.y + self * bf2f(t.y) + bb.y;
    o.z = acc.z + self * bf2f(t.z) + bb.z;
    o.w = acc.w + self * bf2f(t.w) + bb.w;
    reinterpret_cast<float4*>(&out[(size_t)node * C2])[lane] = o;
}

// ---------------- graph-norm: two-stage sum & sumsq ----------------
__global__ void reduce_sum_sq_part(const float* __restrict__ x, int n4, float* __restrict__ Sp) {
    float s = 0.f, q = 0.f;
    const float4* x4 = reinterpret_cast<const float4*>(x);
    for (int i = blockIdx.x * blockDim.x + threadIdx.x; i < n4; i += gridDim.x * blockDim.x) {
        float4 v = x4[i];
        s += v.x + v.y + v.z + v.w;
        q += v.x * v.x + v.y * v.y + v.z * v.z + v.w * v.w;
    }
    __shared__ float ls[256], lq[256];
    ls[threadIdx.x] = s; lq[threadIdx.x] = q;
    __syncthreads();
    for (int off = 128; off > 0; off >>= 1) {
        if ((int)threadIdx.x < off) {
            ls[threadIdx.x] += ls[threadIdx.x + off];
            lq[threadIdx.x] += lq[threadIdx.x + off];
        }
        __syncthreads();
    }
    if (threadIdx.x == 0) {
        Sp[2 * blockIdx.x] = ls[0];
        Sp[2 * blockIdx.x + 1] = lq[0];
    }
}

__global__ void reduce_final(const float* __restrict__ Sp, int nb, float* __restrict__ S) {
    float s = 0.f, q = 0.f;
    for (int i = threadIdx.x; i < nb; i += 256) {
        s += Sp[2 * i];
        q += Sp[2 * i + 1];
    }
    __shared__ float ls[256], lq[256];
    ls[threadIdx.x] = s; lq[threadIdx.x] = q;
    __syncthreads();
    for (int off = 128; off > 0; off >>= 1) {
        if ((int)threadIdx.x < off) {
            ls[threadIdx.x] += ls[threadIdx.x + off];
            lq[threadIdx.x] += lq[threadIdx.x + off];
        }
        __syncthreads();
    }
    if (threadIdx.x == 0) { S[0] = ls[0]; S[1] = lq[0]; }
}

// ---------------- fused norm+relu+scores ----------------
template <int C>
__global__ void norm_scores(float* __restrict__ h, int n, const float* __restrict__ S,
                            float inv_cnt, const float* __restrict__ lnw,
                            const float* __restrict__ lnb, const float* __restrict__ wrel,
                            const float* __restrict__ brel, const float* __restrict__ wroot,
                            float* __restrict__ r, float* __restrict__ score) {
    int node = blockIdx.x * (blockDim.x >> 6) + ((int)threadIdx.x >> 6);
    if (node >= n) return;
    int lane = threadIdx.x & 63;
    float mean = S[0] * inv_cnt;
    float var = S[1] * inv_cnt - mean * mean;
    float istd = 1.f / (sqrtf(fmaxf(var, 0.f)) + EPSV);
    float4* row = reinterpret_cast<float4*>(&h[(size_t)node * C]);
    float sr = 0.f, st = 0.f;
#pragma unroll
    for (int kk = 0; kk < C / 256; ++kk) {
        int idx = lane + 64 * kk;
        float4 v = row[idx];
        float4 w = reinterpret_cast<const float4*>(lnw)[idx];
        float4 bb = reinterpret_cast<const float4*>(lnb)[idx];
        float4 w4 = reinterpret_cast<const float4*>(wrel)[idx];
        float4 o4 = reinterpret_cast<const float4*>(wroot)[idx];
        v.x = fmaxf((v.x - mean) * istd * w.x + bb.x, 0.f);
        v.y = fmaxf((v.y - mean) * istd * w.y + bb.y, 0.f);
        v.z = fmaxf((v.z - mean) * istd * w.z + bb.z, 0.f);
        v.w = fmaxf((v.w - mean) * istd * w.w + bb.w, 0.f);
        sr += v.x * w4.x + v.y * w4.y + v.z * w4.z + v.w * w4.w;
        st += v.x * o4.x + v.y * o4.y + v.z * o4.z + v.w * o4.w;
        row[idx] = v;
    }
    for (int off = 32; off > 0; off >>= 1) {
        sr += __shfl_down(sr, off);
        st += __shfl_down(st, off);
    }
    if (lane == 0) {
        r[node] = sr;
        score[node] = st + brel[0];
    }
}

// ---------------- gather score over CSR + keyify ----------------
__global__ void gather_score_key(const int* __restrict__ rowstart, const int* __restrict__ csr_src,
                                 const float* __restrict__ r, float* __restrict__ score,
                                 unsigned* __restrict__ key, int n) {
    int i = blockIdx.x * blockDim.x + threadIdx.x;
    if (i >= n) return;
    float s = score[i];
    int beg = rowstart[i], end = rowstart[i + 1];
    for (int j = beg; j < end; ++j) s += r[csr_src[j]];
    score[i] = s;
    unsigned u = __float_as_uint(s);
    key[i] = (u & 0x80000000u) ? ~u : (u | 0x80000000u);
}

// ---------------- two-pass 16-bit radix select (multi-block) ----------------
// hist bin index is DESCENDING-mapped: idx = 0xFFFF ^ (bits), so ascending prefix = count of larger keys.
__global__ void hist_hi(const unsigned* __restrict__ key, int n, unsigned* __restrict__ hist) {
    int i = blockIdx.x * blockDim.x + threadIdx.x;
    if (i >= n) return;
    atomicAdd(&hist[(~key[i]) >> 16], 1u);
}

// 1024 threads, 64 bins each; finds bin where cumulative crosses k; self-zeroes hist.
__global__ void scan_sel1(unsigned* __restrict__ hist, unsigned k, unsigned* __restrict__ sel) {
    __shared__ unsigned ps[1024];
    __shared__ int owner;
    int t = threadIdx.x;
    int base = t * 64;
    unsigned s = 0;
    for (int b = 0; b < 64; ++b) s += hist[base + b];
    ps[t] = s;
    __syncthreads();
    for (int off = 1; off < 1024; off <<= 1) {
        unsigned add = (t >= off) ? ps[t - off] : 0u;
        __syncthreads();
        ps[t] += add;
        __syncthreads();
    }
    unsigned incl = ps[t], excl = incl - s;
    if (excl < k && k <= incl) owner = t;
    __syncthreads();
    if (t == owner) {
        unsigned cum = excl;
        for (int b = 0; b < 64; ++b) {
            unsigned c = hist[base + b];
            if (cum + c >= k) {
                sel[2] = 0xFFFFu ^ (unsigned)(base + b);  // real high16
                sel[3] = k - cum;                          // remaining within bin
                break;
            }
            cum += c;
        }
    }
    __syncthreads();
    for (int b = 0; b < 64; ++b) hist[base + b] = 0u;
}

__global__ void hist_lo(const unsigned* __restrict__ key, int n, const unsigned* __restrict__ sel,
                        unsigned* __restrict__ hist) {
    int i = blockIdx.x * blockDim.x + threadIdx.x;
    if (i >= n) return;
    unsigned u = key[i];
    if ((u >> 16) == sel[2]) atomicAdd(&hist[0xFFFFu ^ (u & 0xFFFFu)], 1u);
}

__global__ void scan_sel2(unsigned* __restrict__ hist, unsigned* __restrict__ sel) {
    __shared__ unsigned ps[1024];
    __shared__ int owner;
    int t = threadIdx.x;
    unsigned k = sel[3];
    unsigned H = sel[2];
    int base = t * 64;
    unsigned s = 0;
    for (int b = 0; b < 64; ++b) s += hist[base + b];
    ps[t] = s;
    __syncthreads();
    for (int off = 1; off < 1024; off <<= 1) {
        unsigned add = (t >= off) ? ps[t - off] : 0u;
        __syncthreads();
        ps[t] += add;
        __syncthreads();
    }
    unsigned incl = ps[t], excl = incl - s;
    if (excl < k && k <= incl) owner = t;
    __syncthreads();
    if (t == owner) {
        unsigned cum = excl;
        for (int b = 0; b < 64; ++b) {
            unsigned c = hist[base + b];
            if (cum + c >= k) {
                sel[0] = (H << 16) | (0xFFFFu ^ (unsigned)(base + b));  // threshold key
                sel[1] = k - cum;                                        // ties to keep
                break;
            }
            cum += c;
        }
    }
    __syncthreads();
    for (int b = 0; b < 64; ++b) hist[base + b] = 0u;
}

// ---------------- multi-block deterministic select + compact ----------------
__global__ void sc_partial(const unsigned* __restrict__ key, int n, const unsigned* __restrict__ sel,
                           int* __restrict__ gpart, int* __restrict__ epart) {
    unsigned thr = sel[0];
    int base = blockIdx.x * 1024 + (int)threadIdx.x * 4;
    int gs = 0, es = 0;
#pragma unroll
    for (int t = 0; t < 4; ++t) {
        int i = base + t;
        if (i < n) {
            unsigned u = key[i];
            gs += (u > thr); es += (u == thr);
        }
    }
    for (int off = 32; off > 0; off >>= 1) {
        gs += __shfl_down(gs, off);
        es += __shfl_down(es, off);
    }
    __shared__ int sg[4], se[4];
    int wid = threadIdx.x >> 6;
    if ((threadIdx.x & 63) == 0) { sg[wid] = gs; se[wid] = es; }
    __syncthreads();
    if (threadIdx.x == 0) {
        gpart[blockIdx.x] = sg[0] + sg[1] + sg[2] + sg[3];
        epart[blockIdx.x] = se[0] + se[1] + se[2] + se[3];
    }
}

__global__ void sc_scan_partials(int nb, int* __restrict__ gpart, int* __restrict__ epart) {
    int lane = threadIdx.x;
    int g0 = (lane < nb) ? gpart[lane] : 0;
    int e0 = (lane < nb) ? epart[lane] : 0;
    int g = g0, e = e0;
    for (int off = 1; off < 64; off <<= 1) {
        int gg = __shfl_up(g, off), ee = __shfl_up(e, off);
        if (lane >= off) { g += gg; e += ee; }
    }
    if (lane < nb) { gpart[lane] = g - g0; epart[lane] = e - e0; }
}

__global__ void sc_final(const unsigned* __restrict__ key, int n, const unsigned* __restrict__ sel,
                         const int* __restrict__ gpart, const int* __restrict__ epart,
                         int* __restrict__ kept, int* __restrict__ inv) {
    unsigned thr = sel[0];
    int tie = (int)sel[1];
    int base = blockIdx.x * 1024 + (int)threadIdx.x * 4;
    int gl[4], el[4];
    int gs = 0, es = 0;
#pragma unroll
    for (int t = 0; t < 4; ++t) {
        int i = base + t;
        gl[t] = 0; el[t] = 0;
        if (i < n) {
            unsigned u = key[i];
            gl[t] = (u > thr); el[t] = (u == thr);
        }
        gs += gl[t]; es += el[t];
    }
    int lane = threadIdx.x & 63, wid = threadIdx.x >> 6;
    int gi = gs, ei = es;
    for (int off = 1; off < 64; off <<= 1) {
        int gg = __shfl_up(gi, off), ee = __shfl_up(ei, off);
        if (lane >= off) { gi += gg; ei += ee; }
    }
    __shared__ int wg[4], we[4];
    if (lane == 63) { wg[wid] = gi; we[wid] = ei; }
    __syncthreads();
    int wgo = 0, weo = 0;
    for (int w = 0; w < wid; ++w) { wgo += wg[w]; weo += we[w]; }
    int gp = gpart[blockIdx.x] + (gi - gs) + wgo;
    int ep = epart[blockIdx.x] + (ei - es) + weo;
#pragma unroll
    for (int t = 0; t < 4; ++t) {
        int i = base + t;
        if (i < n) {
            int keep = gl[t] | (el[t] & ((ep < tie) ? 1 : 0));
            kept[i] = keep;
            inv[i] = gp + ((ep < tie) ? ep : tie);
        }
        gp += gl[t]; ep += el[t];
    }
}

// ---------------- pool apply: wave per node, bf16 out (C=512) ----------------
__global__ void pool_apply_rows(const float* __restrict__ h, const float* __restrict__ score,
                                const int* __restrict__ kept, const int* __restrict__ inv,
                                int n, ushort* __restrict__ hp) {
    int node = blockIdx.x * (blockDim.x >> 6) + ((int)threadIdx.x >> 6);
    if (node >= n) return;
    if (!kept[node]) return;
    int lane = threadIdx.x & 63;
    float tw = tanhf(score[node]);
    const float4* src = reinterpret_cast<const float4*>(&h[(size_t)node * C1]);
    ushort4* dst = reinterpret_cast<ushort4*>(&hp[(size_t)inv[node] * C1]);
#pragma unroll
    for (int v = 0; v < 2; ++v) {
        float4 a = src[lane + 64 * v];
        ushort4 o;
        o.x = f2bf(a.x * tw); o.y = f2bf(a.y * tw);
        o.z = f2bf(a.z * tw); o.w = f2bf(a.w * tw);
        dst[lane + 64 * v] = o;
    }
}

// ---------------- edge relabel ----------------
__global__ void edge_relabel(const int* __restrict__ src, const int* __restrict__ dst, int E,
                             const int* __restrict__ kept, const int* __restrict__ inv,
                             int* __restrict__ src2, int* __restrict__ dst2,
                             int* __restrict__ mask2) {
    int e = blockIdx.x * blockDim.x + threadIdx.x;
    if (e >= E) return;
    int s = src[e], d = dst[e];
    int m = kept[s] & kept[d];
    mask2[e] = m;
    src2[e] = m ? inv[s] : 0;
    dst2[e] = m ? inv[d] : 0;
}

// ---------------- masked weighted column mean: coalesced row-chunk version ----------------
// g[c] += invk * sum_{rows in chunk, kept} tanh(score[i]) * h[i][c]
__global__ void colmean_rows(const float* __restrict__ h, const float* __restrict__ score,
                             const int* __restrict__ kept, int n, float invk,
                             float* __restrict__ g) {
    __shared__ float w[256];
    int i0 = blockIdx.x * 256;
    int t = threadIdx.x;
    int i = i0 + t;
    w[t] = (i < n && kept[i]) ? tanhf(score[i]) : 0.f;
    __syncthreads();
    float acc = 0.f;
    int rows = min(256, n - i0);
    for (int ri = 0; ri < rows; ++ri) {
        float wv = w[ri];
        if (wv != 0.f) acc += wv * h[(size_t)(i0 + ri) * C2 + t];
    }
    atomicAdd(&g[t], acc * invk);
}

__global__ void final_gemv(const float* __restrict__ g, const float* __restrict__ Wf,
                           const float* __restrict__ bf, float* __restrict__ out) {
    int j = threadIdx.x;  // 128
    float s = bf[j];
    for (int c = 0; c < 256; ++c) s += g[c] * Wf[c * NOUT + j];
    out[j] = s;
}

// =======================================================================================
extern "C" void kernel_launch(void* const* d_in, const int* in_sizes, int n_in,
                              void* d_out, int out_size, void* d_ws, size_t ws_size,
                              hipStream_t stream) {
    const float* x      = (const float*)d_in[0];
    const int*   ei     = (const int*)d_in[1];
    const float* W1     = (const float*)d_in[2];
    const float* b1     = (const float*)d_in[3];
    const float* ln1w   = (const float*)d_in[4];
    const float* ln1b   = (const float*)d_in[5];
    const float* p1wrel = (const float*)d_in[6];
    const float* p1brel = (const float*)d_in[7];
    const float* p1wroot= (const float*)d_in[8];
    const float* W2     = (const float*)d_in[9];
    const float* b2     = (const float*)d_in[10];
    const float* ln2w   = (const float*)d_in[11];
    const float* ln2b   = (const float*)d_in[12];
    const float* p2wrel = (const float*)d_in[13];
    const float* p2brel = (const float*)d_in[14];
    const float* p2wroot= (const float*)d_in[15];
    const float* Wf     = (const float*)d_in[16];
    const float* bf     = (const float*)d_in[17];
    float* out = (float*)d_out;
    char* ws = (char*)d_ws;

    const int* src1 = ei;
    const int* dst1 = ei + NE;

    // ---- workspace layout (bytes) ----
    const size_t o0     = 0;          // 40.96 MB: h1 f32; later h2 f32 @+0, xW2b bf16 @+10,240,000
    const size_t o1     = 40960000;   // 10.24 MB: aggb bf16; later h1pb bf16
    const size_t oXb    = 51200000;   // 10,240,000 : xb bf16
    const size_t oW1t   = 61440000;   // 262,144
    const size_t oW2t   = 61702144;   // 262,144
    const size_t oSrc2  = 61964288;   // 1,280,000
    const size_t oDst2  = 63244288;
    const size_t oMask2 = 64524288;
    const size_t oCsr   = 65804288;   // 1,280,000
    const size_t oRow   = 67084288;   // 80,064
    const size_t oCur   = 67164352;   // 80,000
    const size_t oDeg   = 67244352;
    const size_t oDinv  = 67324352;
    const size_t oR     = 67404352;
    const size_t oScore1= 67484352;
    const size_t oKeyu  = 67564352;
    const size_t oKept  = 67644352;
    const size_t oInv   = 67724352;
    const size_t oScore2= 67804352;   // 40,000
    const size_t oKeyu2 = 67844352;
    const size_t oKept2 = 67884352;
    const size_t oInv2  = 67924352;
    const size_t oS     = 67964352;   // 64
    const size_t oSel   = 67964416;   // 64
    const size_t oGpart = 67964480;   // 256
    const size_t oEpart = 67964736;   // 256
    const size_t oG     = 67964992;   // 1,024
    const size_t oSp    = 67966016;   // 4,096
    const size_t oHist  = 67970112;   // 262,144 : 64K-bin histogram

    float*  h1    = (float*)(ws + o0);
    float*  h2    = (float*)(ws + o0);
    ushort* xW2b  = (ushort*)(ws + o0 + 10240000);
    ushort* aggb  = (ushort*)(ws + o1);
    ushort* h1pb  = (ushort*)(ws + o1);
    ushort* xb    = (ushort*)(ws + oXb);
    ushort* W1t   = (ushort*)(ws + oW1t);
    ushort* W2t   = (ushort*)(ws + oW2t);
    int*    src2  = (int*)(ws + oSrc2);
    int*    dst2  = (int*)(ws + oDst2);
    int*    mask2 = (int*)(ws + oMask2);
    int*    csr   = (int*)(ws + oCsr);
    int*    row   = (int*)(ws + oRow);
    int*    cur   = (int*)(ws + oCur);
    float*  deg   = (float*)(ws + oDeg);
    float*  dinv  = (float*)(ws + oDinv);
    float*  r     = (float*)(ws + oR);
    float*  score1= (float*)(ws + oScore1);
    unsigned* keyu  = (unsigned*)(ws + oKeyu);
    int*    kept  = (int*)(ws + oKept);
    int*    inv   = (int*)(ws + oInv);
    float*  score2= (float*)(ws + oScore2);
    unsigned* keyu2 = (unsigned*)(ws + oKeyu2);
    int*    kept2 = (int*)(ws + oKept2);
    int*    inv2  = (int*)(ws + oInv2);
    float*  S     = (float*)(ws + oS);
    unsigned* sel  = (unsigned*)(ws + oSel);
    int*    gpart = (int*)(ws + oGpart);
    int*    epart = (int*)(ws + oEpart);
    float*  g     = (float*)(ws + oG);
    float*  Sp    = (float*)(ws + oSp);
    unsigned* hist = (unsigned*)(ws + oHist);

    const int nb1 = cdiv(N1, 1024);  // 20
    const int nb2 = cdiv(K1, 1024);  // 10

    // ================= Stage 1 =================
    f32_to_bf16<<<cdiv(N1 * CIN / 4, 256), 256, 0, stream>>>(x, xb, N1 * CIN / 4);

    fill_i32<<<cdiv(N1, 256), 256, 0, stream>>>(cur, 0, N1);
    fill_i32<<<cdiv(65536, 256), 256, 0, stream>>>((int*)hist, 0, 65536);  // scan kernels self-zero after
    count_deg<<<cdiv(NE, 256), 256, 0, stream>>>(dst1, nullptr, NE, cur);
    dp_partial<<<nb1, 256, 0, stream>>>(cur, N1, gpart);
    scan64k<<<1, 64, 0, stream>>>(nb1, gpart, row + N1);
    dp_final<<<nb1, 256, 0, stream>>>(cur, N1, gpart, row, cur, deg, dinv);
    csr_scatter<<<cdiv(NE, 256), 256, 0, stream>>>(src1, dst1, nullptr, NE, cur, csr);

    aggregate_xb<<<cdiv(N1, 4), 256, 0, stream>>>(row, csr, deg, dinv, xb, aggb, N1);

    conv_transpose_bf16<<<cdiv(CIN * C1, 256), 256, 0, stream>>>(W1, W1t, CIN, C1);
    gemm_bf16_mfma<false><<<dim3(cdiv(N1, 128), C1 / 128), 256, 0, stream>>>(
        aggb, W1t, b1, h1, nullptr, N1, C1, CIN);

    reduce_sum_sq_part<<<NB_RED, 256, 0, stream>>>(h1, N1 * C1 / 4, Sp);
    reduce_final<<<1, 256, 0, stream>>>(Sp, NB_RED, S);
    norm_scores<C1><<<cdiv(N1, 4), 256, 0, stream>>>(h1, N1, S, 1.f / ((float)N1 * C1),
                                                     ln1w, ln1b, p1wrel, p1brel, p1wroot, r, score1);
    gather_score_key<<<cdiv(N1, 256), 256, 0, stream>>>(row, csr, r, score1, keyu, N1);

    hist_hi<<<cdiv(N1, 256), 256, 0, stream>>>(keyu, N1, hist);
    scan_sel1<<<1, 1024, 0, stream>>>(hist, K1, sel);
    hist_lo<<<cdiv(N1, 256), 256, 0, stream>>>(keyu, N1, sel, hist);
    scan_sel2<<<1, 1024, 0, stream>>>(hist, sel);
    sc_partial<<<nb1, 256, 0, stream>>>(keyu, N1, sel, gpart, epart);
    sc_scan_partials<<<1, 64, 0, stream>>>(nb1, gpart, epart);
    sc_final<<<nb1, 256, 0, stream>>>(keyu, N1, sel, gpart, epart, kept, inv);

    pool_apply_rows<<<cdiv(N1, 4), 256, 0, stream>>>(h1, score1, kept, inv, N1, h1pb);
    edge_relabel<<<cdiv(NE, 256), 256, 0, stream>>>(src1, dst1, NE, kept, inv, src2, dst2, mask2);

    // ================= Stage 2 =================
    conv_transpose_bf16<<<cdiv(C1 * C2, 256), 256, 0, stream>>>(W2, W2t, C1, C2);
    gemm_bf16_mfma<true><<<dim3(cdiv(K1, 128), C2 / 128), 256, 0, stream>>>(
        h1pb, W2t, nullptr, nullptr, xW2b, K1, C2, C1);

    fill_i32<<<cdiv(K1, 256), 256, 0, stream>>>(cur, 0, K1);
    count_deg<<<cdiv(NE, 256), 256, 0, stream>>>(dst2, mask2, NE, cur);
    dp_partial<<<nb2, 256, 0, stream>>>(cur, K1, gpart);
    scan64k<<<1, 64, 0, stream>>>(nb2, gpart, row + K1);
    dp_final<<<nb2, 256, 0, stream>>>(cur, K1, gpart, row, cur, deg, dinv);
    csr_scatter<<<cdiv(NE, 256), 256, 0, stream>>>(src2, dst2, mask2, NE, cur, csr);

    aggregate_csr_bf<<<cdiv(K1, 4), 256, 0, stream>>>(row, csr, deg, dinv, xW2b, b2, h2, K1);

    reduce_sum_sq_part<<<NB_RED, 256, 0, stream>>>(h2, K1 * C2 / 4, Sp);
    reduce_final<<<1, 256, 0, stream>>>(Sp, NB_RED, S);
    norm_scores<C2><<<cdiv(K1, 4), 256, 0, stream>>>(h2, K1, S, 1.f / ((float)K1 * C2),
                                                     ln2w, ln2b, p2wrel, p2brel, p2wroot, r, score2);
    gather_score_key<<<cdiv(K1, 256), 256, 0, stream>>>(row, csr, r, score2, keyu2, K1);

    hist_hi<<<cdiv(K1, 256), 256, 0, stream>>>(keyu2, K1, hist);
    scan_sel1<<<1, 1024, 0, stream>>>(hist, K2, sel);
    hist_lo<<<cdiv(K1, 256), 256, 0, stream>>>(keyu2, K1, sel, hist);
    scan_sel2<<<1, 1024, 0, stream>>>(hist, sel);
    sc_partial<<<nb2, 256, 0, stream>>>(keyu2, K1, sel, gpart, epart);
    sc_scan_partials<<<1, 64, 0, stream>>>(nb2, gpart, epart);
    sc_final<<<nb2, 256, 0, stream>>>(keyu2, K1, sel, gpart, epart, kept2, inv2);

    // ================= readout =================
    fill_f32<<<1, 256, 0, stream>>>(g, 0.f, C2);
    colmean_rows<<<cdiv(K1, 256), 256, 0, stream>>>(h2, score2, kept2, K1, 1.f / (float)K2, g);
    final_gemv<<<1, NOUT, 0, stream>>>(g, Wf, bf, out);
}

// Round 7
// 420.248 us; speedup vs baseline: 7.3624x; 1.0848x over previous
//
#include <hip/hip_runtime.h>
#include <math.h>

#define N1 20000
#define NE 320000
#define CIN 256
#define C1 512
#define C2 256
#define K1 10000
#define K2 5000
#define NOUT 128
#define EPSV 1e-5f
#define NB_RED 512

typedef __attribute__((ext_vector_type(8))) short bf16x8;
typedef __attribute__((ext_vector_type(4))) float f32x4;

static inline unsigned cdiv(unsigned a, unsigned b) { return (a + b - 1) / b; }

__device__ inline ushort f2bf(float f) {
    unsigned u = __float_as_uint(f);
    unsigned r = u + 0x7FFFu + ((u >> 16) & 1u);
    return (ushort)(r >> 16);
}
__device__ inline float bf2f(ushort u) { return __uint_as_float(((unsigned)u) << 16); }

// ---------------- fills ----------------
__global__ void fill_i32(int* __restrict__ p, int v, int n) {
    int i = blockIdx.x * blockDim.x + threadIdx.x;
    if (i < n) p[i] = v;
}
__global__ void fill_f32(float* __restrict__ p, float v, int n) {
    int i = blockIdx.x * blockDim.x + threadIdx.x;
    if (i < n) p[i] = v;
}

// ---------------- f32 -> bf16 ----------------
__global__ void f32_to_bf16(const float* __restrict__ in, ushort* __restrict__ out, int n4) {
    int i = blockIdx.x * blockDim.x + threadIdx.x;
    if (i >= n4) return;
    float4 v = reinterpret_cast<const float4*>(in)[i];
    ushort4 o;
    o.x = f2bf(v.x); o.y = f2bf(v.y); o.z = f2bf(v.z); o.w = f2bf(v.w);
    reinterpret_cast<ushort4*>(out)[i] = o;
}

// ---------------- weight convert+transpose ----------------
__global__ void conv_transpose_bf16(const float* __restrict__ W, ushort* __restrict__ Wt,
                                    int K, int N) {
    int i = blockIdx.x * blockDim.x + threadIdx.x;
    if (i >= K * N) return;
    int k = i / N, n = i % N;
    Wt[(size_t)n * K + k] = f2bf(W[i]);
}

// ---------------- MFMA bf16 GEMM ----------------
template <bool BF16OUT>
__global__ __launch_bounds__(256)
void gemm_bf16_mfma(const ushort* __restrict__ A, const ushort* __restrict__ Bt,
                    const float* __restrict__ bias, float* __restrict__ C,
                    ushort* __restrict__ Cb, int M, int N, int K) {
    constexpr int BM = 128, BN = 128, BK = 32;
    constexpr int LDK = BK + 8;
    __shared__ ushort As[BM * LDK];
    __shared__ ushort Bs[BN * LDK];
    int tid = threadIdx.x;
    int wid = tid >> 6, lane = tid & 63;
    int wr = wid >> 1, wc = wid & 1;
    int bm = blockIdx.x * BM, bn = blockIdx.y * BN;
    int lg = lane >> 4, lm = lane & 15;
    f32x4 zero = {0.f, 0.f, 0.f, 0.f};
    f32x4 acc[4][4];
#pragma unroll
    for (int m = 0; m < 4; ++m)
#pragma unroll
        for (int n = 0; n < 4; ++n) acc[m][n] = zero;

    for (int k0 = 0; k0 < K; k0 += BK) {
#pragma unroll
        for (int it = 0; it < 2; ++it) {
            int task = tid * 2 + it;
            int row = task >> 2, c8 = (task & 3) * 8;
            int gm = bm + row;
            bf16x8 v = {0, 0, 0, 0, 0, 0, 0, 0};
            if (gm < M) v = *(const bf16x8*)&A[(size_t)gm * K + k0 + c8];
            *(bf16x8*)&As[row * LDK + c8] = v;
            int gn = bn + row;
            bf16x8 w = {0, 0, 0, 0, 0, 0, 0, 0};
            if (gn < N) w = *(const bf16x8*)&Bt[(size_t)gn * K + k0 + c8];
            *(bf16x8*)&Bs[row * LDK + c8] = w;
        }
        __syncthreads();
        bf16x8 af[4], bfr[4];
#pragma unroll
        for (int m = 0; m < 4; ++m)
            af[m] = *(bf16x8*)&As[(wr * 64 + m * 16 + lm) * LDK + lg * 8];
#pragma unroll
        for (int n = 0; n < 4; ++n)
            bfr[n] = *(bf16x8*)&Bs[(wc * 64 + n * 16 + lm) * LDK + lg * 8];
#pragma unroll
        for (int m = 0; m < 4; ++m)
#pragma unroll
            for (int n = 0; n < 4; ++n)
                acc[m][n] = __builtin_amdgcn_mfma_f32_16x16x32_bf16(af[m], bfr[n], acc[m][n], 0, 0, 0);
        __syncthreads();
    }
#pragma unroll
    for (int m = 0; m < 4; ++m) {
#pragma unroll
        for (int n = 0; n < 4; ++n) {
            int col = bn + wc * 64 + n * 16 + lm;
            float bv = bias ? bias[col] : 0.f;
#pragma unroll
            for (int r = 0; r < 4; ++r) {
                int row = bm + wr * 64 + m * 16 + lg * 4 + r;
                if (row < M) {
                    float val = acc[m][n][r] + bv;
                    if (BF16OUT) Cb[(size_t)row * N + col] = f2bf(val);
                    else         C[(size_t)row * N + col] = val;
                }
            }
        }
    }
}

// ---------------- CSR build ----------------
__global__ void count_deg(const int* __restrict__ dst, const int* __restrict__ mask, int E,
                          int* __restrict__ cnt) {
    int e = blockIdx.x * blockDim.x + threadIdx.x;
    if (e >= E) return;
    if (mask && !mask[e]) return;
    atomicAdd(&cnt[dst[e]], 1);
}

__global__ void dp_partial(const int* __restrict__ cnt, int n, int* __restrict__ part) {
    int base = blockIdx.x * 1024 + (int)threadIdx.x * 4;
    int s = 0;
#pragma unroll
    for (int t = 0; t < 4; ++t) {
        int i = base + t;
        if (i < n) s += cnt[i];
    }
    for (int off = 32; off > 0; off >>= 1) s += __shfl_down(s, off);
    __shared__ int sg[4];
    int wid = threadIdx.x >> 6;
    if ((threadIdx.x & 63) == 0) sg[wid] = s;
    __syncthreads();
    if (threadIdx.x == 0) part[blockIdx.x] = sg[0] + sg[1] + sg[2] + sg[3];
}

__global__ void scan64k(int nb, int* __restrict__ part, int* __restrict__ row_n) {
    int lane = threadIdx.x;
    int v0 = (lane < nb) ? part[lane] : 0;
    int v = v0;
    for (int off = 1; off < 64; off <<= 1) {
        int vv = __shfl_up(v, off);
        if (lane >= off) v += vv;
    }
    if (lane == nb - 1) row_n[0] = v;
    if (lane < nb) part[lane] = v - v0;
}

__global__ void dp_final(const int* __restrict__ cnt, int n, const int* __restrict__ part,
                         int* __restrict__ rowstart, int* __restrict__ cursor,
                         float* __restrict__ deg, float* __restrict__ dinv) {
    int base = blockIdx.x * 1024 + (int)threadIdx.x * 4;
    int c[4];
    int s = 0;
#pragma unroll
    for (int t = 0; t < 4; ++t) {
        int i = base + t;
        c[t] = (i < n) ? cnt[i] : 0;
        s += c[t];
    }
    int lane = threadIdx.x & 63, wid = threadIdx.x >> 6;
    int si = s;
    for (int off = 1; off < 64; off <<= 1) {
        int vv = __shfl_up(si, off);
        if (lane >= off) si += vv;
    }
    __shared__ int wg[4];
    if (lane == 63) wg[wid] = si;
    __syncthreads();
    int woff = 0;
    for (int w = 0; w < wid; ++w) woff += wg[w];
    int excl = part[blockIdx.x] + (si - s) + woff;
#pragma unroll
    for (int t = 0; t < 4; ++t) {
        int i = base + t;
        if (i < n) {
            rowstart[i] = excl;
            cursor[i] = excl;
            float dg = (float)c[t] + 2.0f;
            deg[i] = dg;
            dinv[i] = rsqrtf(dg);
        }
        excl += c[t];
    }
}

__global__ void csr_scatter(const int* __restrict__ src, const int* __restrict__ dst,
                            const int* __restrict__ mask, int E,
                            int* __restrict__ cursor, int* __restrict__ csr_src) {
    int e = blockIdx.x * blockDim.x + threadIdx.x;
    if (e >= E) return;
    if (mask && !mask[e]) return;
    int pos = atomicAdd(&cursor[dst[e]], 1);
    csr_src[pos] = src[e];
}

// ---------------- stage-1 aggregation: 8-deep pipelined gather (bf16 in/out) ----------------
__global__ void aggregate_xb(const int* __restrict__ rowstart, const int* __restrict__ csr_src,
                             const float* __restrict__ deg, const float* __restrict__ dinv,
                             const ushort* __restrict__ xb, ushort* __restrict__ out, int n) {
    int node = blockIdx.x * (blockDim.x >> 6) + ((int)threadIdx.x >> 6);
    if (node >= n) return;
    int lane = threadIdx.x & 63;
    int beg = rowstart[node], end = rowstart[node + 1];
    float di = dinv[node];
    float4 acc = make_float4(0.f, 0.f, 0.f, 0.f);
    int j = beg;
    for (; j + 8 <= end; j += 8) {
        int s[8];
#pragma unroll
        for (int u = 0; u < 8; ++u) s[u] = csr_src[j + u];
        float c[8];
#pragma unroll
        for (int u = 0; u < 8; ++u) c[u] = dinv[s[u]] * di;
        ushort4 t[8];
#pragma unroll
        for (int u = 0; u < 8; ++u)
            t[u] = reinterpret_cast<const ushort4*>(&xb[(size_t)s[u] * CIN])[lane];
#pragma unroll
        for (int u = 0; u < 8; ++u) {
            acc.x += c[u] * bf2f(t[u].x);
            acc.y += c[u] * bf2f(t[u].y);
            acc.z += c[u] * bf2f(t[u].z);
            acc.w += c[u] * bf2f(t[u].w);
        }
    }
    for (; j < end; ++j) {
        int s = csr_src[j];
        float coef = dinv[s] * di;
        ushort4 t = reinterpret_cast<const ushort4*>(&xb[(size_t)s * CIN])[lane];
        acc.x += coef * bf2f(t.x);
        acc.y += coef * bf2f(t.y);
        acc.z += coef * bf2f(t.z);
        acc.w += coef * bf2f(t.w);
    }
    float self = 2.0f / deg[node];
    ushort4 t = reinterpret_cast<const ushort4*>(&xb[(size_t)node * CIN])[lane];
    acc.x += self * bf2f(t.x);
    acc.y += self * bf2f(t.y);
    acc.z += self * bf2f(t.z);
    acc.w += self * bf2f(t.w);
    ushort4 o;
    o.x = f2bf(acc.x); o.y = f2bf(acc.y); o.z = f2bf(acc.z); o.w = f2bf(acc.w);
    reinterpret_cast<ushort4*>(&out[(size_t)node * CIN])[lane] = o;
}

// ---------------- stage-2 aggregation: 8-deep pipelined gather, f32 out + bias + self ----------------
__global__ void aggregate_csr_bf(const int* __restrict__ rowstart, const int* __restrict__ csr_src,
                                 const float* __restrict__ deg, const float* __restrict__ dinv,
                                 const ushort* __restrict__ xWb, const float* __restrict__ b,
                                 float* __restrict__ out, int n) {
    int node = blockIdx.x * (blockDim.x >> 6) + ((int)threadIdx.x >> 6);
    if (node >= n) return;
    int lane = threadIdx.x & 63;
    int beg = rowstart[node], end = rowstart[node + 1];
    float di = dinv[node];
    float4 acc = make_float4(0.f, 0.f, 0.f, 0.f);
    int j = beg;
    for (; j + 8 <= end; j += 8) {
        int s[8];
#pragma unroll
        for (int u = 0; u < 8; ++u) s[u] = csr_src[j + u];
        float c[8];
#pragma unroll
        for (int u = 0; u < 8; ++u) c[u] = dinv[s[u]] * di;
        ushort4 t[8];
#pragma unroll
        for (int u = 0; u < 8; ++u)
            t[u] = reinterpret_cast<const ushort4*>(&xWb[(size_t)s[u] * C2])[lane];
#pragma unroll
        for (int u = 0; u < 8; ++u) {
            acc.x += c[u] * bf2f(t[u].x);
            acc.y += c[u] * bf2f(t[u].y);
            acc.z += c[u] * bf2f(t[u].z);
            acc.w += c[u] * bf2f(t[u].w);
        }
    }
    for (; j < end; ++j) {
        int s = csr_src[j];
        float coef = dinv[s] * di;
        ushort4 t = reinterpret_cast<const ushort4*>(&xWb[(size_t)s * C2])[lane];
        acc.x += coef * bf2f(t.x);
        acc.y += coef * bf2f(t.y);
        acc.z += coef * bf2f(t.z);
        acc.w += coef * bf2f(t.w);
    }
    float self = 2.0f / deg[node];
    ushort4 t = reinterpret_cast<const ushort4*>(&xWb[(size_t)node * C2])[lane];
    float4 bb = reinterpret_cast<const float4*>(b)[lane];
    float4 o;
    o.x = acc.x + self * bf2f(t.x) + bb.x;
    o.y = acc.y + self * bf2f(t.y) + bb.y;
    o.z = acc.z + self * bf2f(t.z) + bb.z;
    o.w = acc.w + self * bf2f(t.w) + bb.w;
    reinterpret_cast<float4*>(&out[(size_t)node * C2])[lane] = o;
}

// ---------------- graph-norm: two-stage sum & sumsq ----------------
__global__ void reduce_sum_sq_part(const float* __restrict__ x, int n4, float* __restrict__ Sp) {
    float s = 0.f, q = 0.f;
    const float4* x4 = reinterpret_cast<const float4*>(x);
    for (int i = blockIdx.x * blockDim.x + threadIdx.x; i < n4; i += gridDim.x * blockDim.x) {
        float4 v = x4[i];
        s += v.x + v.y + v.z + v.w;
        q += v.x * v.x + v.y * v.y + v.z * v.z + v.w * v.w;
    }
    __shared__ float ls[256], lq[256];
    ls[threadIdx.x] = s; lq[threadIdx.x] = q;
    __syncthreads();
    for (int off = 128; off > 0; off >>= 1) {
        if ((int)threadIdx.x < off) {
            ls[threadIdx.x] += ls[threadIdx.x + off];
            lq[threadIdx.x] += lq[threadIdx.x + off];
        }
        __syncthreads();
    }
    if (threadIdx.x == 0) {
        Sp[2 * blockIdx.x] = ls[0];
        Sp[2 * blockIdx.x + 1] = lq[0];
    }
}

__global__ void reduce_final(const float* __restrict__ Sp, int nb, float* __restrict__ S) {
    float s = 0.f, q = 0.f;
    for (int i = threadIdx.x; i < nb; i += 256) {
        s += Sp[2 * i];
        q += Sp[2 * i + 1];
    }
    __shared__ float ls[256], lq[256];
    ls[threadIdx.x] = s; lq[threadIdx.x] = q;
    __syncthreads();
    for (int off = 128; off > 0; off >>= 1) {
        if ((int)threadIdx.x < off) {
            ls[threadIdx.x] += ls[threadIdx.x + off];
            lq[threadIdx.x] += lq[threadIdx.x + off];
        }
        __syncthreads();
    }
    if (threadIdx.x == 0) { S[0] = ls[0]; S[1] = lq[0]; }
}

// ---------------- fused norm+relu+scores ----------------
template <int C>
__global__ void norm_scores(float* __restrict__ h, int n, const float* __restrict__ S,
                            float inv_cnt, const float* __restrict__ lnw,
                            const float* __restrict__ lnb, const float* __restrict__ wrel,
                            const float* __restrict__ brel, const float* __restrict__ wroot,
                            float* __restrict__ r, float* __restrict__ score) {
    int node = blockIdx.x * (blockDim.x >> 6) + ((int)threadIdx.x >> 6);
    if (node >= n) return;
    int lane = threadIdx.x & 63;
    float mean = S[0] * inv_cnt;
    float var = S[1] * inv_cnt - mean * mean;
    float istd = 1.f / (sqrtf(fmaxf(var, 0.f)) + EPSV);
    float4* row = reinterpret_cast<float4*>(&h[(size_t)node * C]);
    float sr = 0.f, st = 0.f;
#pragma unroll
    for (int kk = 0; kk < C / 256; ++kk) {
        int idx = lane + 64 * kk;
        float4 v = row[idx];
        float4 w = reinterpret_cast<const float4*>(lnw)[idx];
        float4 bb = reinterpret_cast<const float4*>(lnb)[idx];
        float4 w4 = reinterpret_cast<const float4*>(wrel)[idx];
        float4 o4 = reinterpret_cast<const float4*>(wroot)[idx];
        v.x = fmaxf((v.x - mean) * istd * w.x + bb.x, 0.f);
        v.y = fmaxf((v.y - mean) * istd * w.y + bb.y, 0.f);
        v.z = fmaxf((v.z - mean) * istd * w.z + bb.z, 0.f);
        v.w = fmaxf((v.w - mean) * istd * w.w + bb.w, 0.f);
        sr += v.x * w4.x + v.y * w4.y + v.z * w4.z + v.w * w4.w;
        st += v.x * o4.x + v.y * o4.y + v.z * o4.z + v.w * o4.w;
        row[idx] = v;
    }
    for (int off = 32; off > 0; off >>= 1) {
        sr += __shfl_down(sr, off);
        st += __shfl_down(st, off);
    }
    if (lane == 0) {
        r[node] = sr;
        score[node] = st + brel[0];
    }
}

// ---------------- gather score over CSR + keyify (4-deep pipelined) ----------------
__global__ void gather_score_key(const int* __restrict__ rowstart, const int* __restrict__ csr_src,
                                 const float* __restrict__ r, float* __restrict__ score,
                                 unsigned* __restrict__ key, int n) {
    int i = blockIdx.x * blockDim.x + threadIdx.x;
    if (i >= n) return;
    float s = score[i];
    int beg = rowstart[i], end = rowstart[i + 1];
    int j = beg;
    for (; j + 4 <= end; j += 4) {
        int s0 = csr_src[j], s1 = csr_src[j + 1], s2 = csr_src[j + 2], s3 = csr_src[j + 3];
        s += r[s0] + r[s1] + r[s2] + r[s3];
    }
    for (; j < end; ++j) s += r[csr_src[j]];
    score[i] = s;
    unsigned u = __float_as_uint(s);
    key[i] = (u & 0x80000000u) ? ~u : (u | 0x80000000u);
}

// ---------------- two-pass 16-bit radix select (multi-block) ----------------
__global__ void hist_hi(const unsigned* __restrict__ key, int n, unsigned* __restrict__ hist) {
    int i = blockIdx.x * blockDim.x + threadIdx.x;
    if (i >= n) return;
    atomicAdd(&hist[(~key[i]) >> 16], 1u);
}

__global__ void scan_sel1(unsigned* __restrict__ hist, unsigned k, unsigned* __restrict__ sel) {
    __shared__ unsigned ps[1024];
    __shared__ int owner;
    int t = threadIdx.x;
    int base = t * 64;
    unsigned s = 0;
    for (int b = 0; b < 64; ++b) s += hist[base + b];
    ps[t] = s;
    __syncthreads();
    for (int off = 1; off < 1024; off <<= 1) {
        unsigned add = (t >= off) ? ps[t - off] : 0u;
        __syncthreads();
        ps[t] += add;
        __syncthreads();
    }
    unsigned incl = ps[t], excl = incl - s;
    if (excl < k && k <= incl) owner = t;
    __syncthreads();
    if (t == owner) {
        unsigned cum = excl;
        for (int b = 0; b < 64; ++b) {
            unsigned c = hist[base + b];
            if (cum + c >= k) {
                sel[2] = 0xFFFFu ^ (unsigned)(base + b);
                sel[3] = k - cum;
                break;
            }
            cum += c;
        }
    }
    __syncthreads();
    for (int b = 0; b < 64; ++b) hist[base + b] = 0u;
}

__global__ void hist_lo(const unsigned* __restrict__ key, int n, const unsigned* __restrict__ sel,
                        unsigned* __restrict__ hist) {
    int i = blockIdx.x * blockDim.x + threadIdx.x;
    if (i >= n) return;
    unsigned u = key[i];
    if ((u >> 16) == sel[2]) atomicAdd(&hist[0xFFFFu ^ (u & 0xFFFFu)], 1u);
}

__global__ void scan_sel2(unsigned* __restrict__ hist, unsigned* __restrict__ sel) {
    __shared__ unsigned ps[1024];
    __shared__ int owner;
    int t = threadIdx.x;
    unsigned k = sel[3];
    unsigned H = sel[2];
    int base = t * 64;
    unsigned s = 0;
    for (int b = 0; b < 64; ++b) s += hist[base + b];
    ps[t] = s;
    __syncthreads();
    for (int off = 1; off < 1024; off <<= 1) {
        unsigned add = (t >= off) ? ps[t - off] : 0u;
        __syncthreads();
        ps[t] += add;
        __syncthreads();
    }
    unsigned incl = ps[t], excl = incl - s;
    if (excl < k && k <= incl) owner = t;
    __syncthreads();
    if (t == owner) {
        unsigned cum = excl;
        for (int b = 0; b < 64; ++b) {
            unsigned c = hist[base + b];
            if (cum + c >= k) {
                sel[0] = (H << 16) | (0xFFFFu ^ (unsigned)(base + b));
                sel[1] = k - cum;
                break;
            }
            cum += c;
        }
    }
    __syncthreads();
    for (int b = 0; b < 64; ++b) hist[base + b] = 0u;
}

// ---------------- multi-block deterministic select + compact ----------------
__global__ void sc_partial(const unsigned* __restrict__ key, int n, const unsigned* __restrict__ sel,
                           int* __restrict__ gpart, int* __restrict__ epart) {
    unsigned thr = sel[0];
    int base = blockIdx.x * 1024 + (int)threadIdx.x * 4;
    int gs = 0, es = 0;
#pragma unroll
    for (int t = 0; t < 4; ++t) {
        int i = base + t;
        if (i < n) {
            unsigned u = key[i];
            gs += (u > thr); es += (u == thr);
        }
    }
    for (int off = 32; off > 0; off >>= 1) {
        gs += __shfl_down(gs, off);
        es += __shfl_down(es, off);
    }
    __shared__ int sg[4], se[4];
    int wid = threadIdx.x >> 6;
    if ((threadIdx.x & 63) == 0) { sg[wid] = gs; se[wid] = es; }
    __syncthreads();
    if (threadIdx.x == 0) {
        gpart[blockIdx.x] = sg[0] + sg[1] + sg[2] + sg[3];
        epart[blockIdx.x] = se[0] + se[1] + se[2] + se[3];
    }
}

__global__ void sc_scan_partials(int nb, int* __restrict__ gpart, int* __restrict__ epart) {
    int lane = threadIdx.x;
    int g0 = (lane < nb) ? gpart[lane] : 0;
    int e0 = (lane < nb) ? epart[lane] : 0;
    int g = g0, e = e0;
    for (int off = 1; off < 64; off <<= 1) {
        int gg = __shfl_up(g, off), ee = __shfl_up(e, off);
        if (lane >= off) { g += gg; e += ee; }
    }
    if (lane < nb) { gpart[lane] = g - g0; epart[lane] = e - e0; }
}

__global__ void sc_final(const unsigned* __restrict__ key, int n, const unsigned* __restrict__ sel,
                         const int* __restrict__ gpart, const int* __restrict__ epart,
                         int* __restrict__ kept, int* __restrict__ inv) {
    unsigned thr = sel[0];
    int tie = (int)sel[1];
    int base = blockIdx.x * 1024 + (int)threadIdx.x * 4;
    int gl[4], el[4];
    int gs = 0, es = 0;
#pragma unroll
    for (int t = 0; t < 4; ++t) {
        int i = base + t;
        gl[t] = 0; el[t] = 0;
        if (i < n) {
            unsigned u = key[i];
            gl[t] = (u > thr); el[t] = (u == thr);
        }
        gs += gl[t]; es += el[t];
    }
    int lane = threadIdx.x & 63, wid = threadIdx.x >> 6;
    int gi = gs, ei = es;
    for (int off = 1; off < 64; off <<= 1) {
        int gg = __shfl_up(gi, off), ee = __shfl_up(ei, off);
        if (lane >= off) { gi += gg; ei += ee; }
    }
    __shared__ int wg[4], we[4];
    if (lane == 63) { wg[wid] = gi; we[wid] = ei; }
    __syncthreads();
    int wgo = 0, weo = 0;
    for (int w = 0; w < wid; ++w) { wgo += wg[w]; weo += we[w]; }
    int gp = gpart[blockIdx.x] + (gi - gs) + wgo;
    int ep = epart[blockIdx.x] + (ei - es) + weo;
#pragma unroll
    for (int t = 0; t < 4; ++t) {
        int i = base + t;
        if (i < n) {
            int keep = gl[t] | (el[t] & ((ep < tie) ? 1 : 0));
            kept[i] = keep;
            inv[i] = gp + ((ep < tie) ? ep : tie);
        }
        gp += gl[t]; ep += el[t];
    }
}

// ---------------- pool apply: wave per node, bf16 out (C=512) ----------------
__global__ void pool_apply_rows(const float* __restrict__ h, const float* __restrict__ score,
                                const int* __restrict__ kept, const int* __restrict__ inv,
                                int n, ushort* __restrict__ hp) {
    int node = blockIdx.x * (blockDim.x >> 6) + ((int)threadIdx.x >> 6);
    if (node >= n) return;
    if (!kept[node]) return;
    int lane = threadIdx.x & 63;
    float tw = tanhf(score[node]);
    const float4* src = reinterpret_cast<const float4*>(&h[(size_t)node * C1]);
    ushort4* dst = reinterpret_cast<ushort4*>(&hp[(size_t)inv[node] * C1]);
#pragma unroll
    for (int v = 0; v < 2; ++v) {
        float4 a = src[lane + 64 * v];
        ushort4 o;
        o.x = f2bf(a.x * tw); o.y = f2bf(a.y * tw);
        o.z = f2bf(a.z * tw); o.w = f2bf(a.w * tw);
        dst[lane + 64 * v] = o;
    }
}

// ---------------- edge relabel ----------------
__global__ void edge_relabel(const int* __restrict__ src, const int* __restrict__ dst, int E,
                             const int* __restrict__ kept, const int* __restrict__ inv,
                             int* __restrict__ src2, int* __restrict__ dst2,
                             int* __restrict__ mask2) {
    int e = blockIdx.x * blockDim.x + threadIdx.x;
    if (e >= E) return;
    int s = src[e], d = dst[e];
    int m = kept[s] & kept[d];
    mask2[e] = m;
    src2[e] = m ? inv[s] : 0;
    dst2[e] = m ? inv[d] : 0;
}

// ---------------- masked weighted column mean ----------------
__global__ void colmean_rows(const float* __restrict__ h, const float* __restrict__ score,
                             const int* __restrict__ kept, int n, float invk,
                             float* __restrict__ g) {
    __shared__ float w[256];
    int i0 = blockIdx.x * 256;
    int t = threadIdx.x;
    int i = i0 + t;
    w[t] = (i < n && kept[i]) ? tanhf(score[i]) : 0.f;
    __syncthreads();
    float acc = 0.f;
    int rows = min(256, n - i0);
    for (int ri = 0; ri < rows; ++ri) {
        float wv = w[ri];
        if (wv != 0.f) acc += wv * h[(size_t)(i0 + ri) * C2 + t];
    }
    atomicAdd(&g[t], acc * invk);
}

__global__ void final_gemv(const float* __restrict__ g, const float* __restrict__ Wf,
                           const float* __restrict__ bf, float* __restrict__ out) {
    int j = threadIdx.x;  // 128
    float s = bf[j];
    for (int c = 0; c < 256; ++c) s += g[c] * Wf[c * NOUT + j];
    out[j] = s;
}

// =======================================================================================
extern "C" void kernel_launch(void* const* d_in, const int* in_sizes, int n_in,
                              void* d_out, int out_size, void* d_ws, size_t ws_size,
                              hipStream_t stream) {
    const float* x      = (const float*)d_in[0];
    const int*   ei     = (const int*)d_in[1];
    const float* W1     = (const float*)d_in[2];
    const float* b1     = (const float*)d_in[3];
    const float* ln1w   = (const float*)d_in[4];
    const float* ln1b   = (const float*)d_in[5];
    const float* p1wrel = (const float*)d_in[6];
    const float* p1brel = (const float*)d_in[7];
    const float* p1wroot= (const float*)d_in[8];
    const float* W2     = (const float*)d_in[9];
    const float* b2     = (const float*)d_in[10];
    const float* ln2w   = (const float*)d_in[11];
    const float* ln2b   = (const float*)d_in[12];
    const float* p2wrel = (const float*)d_in[13];
    const float* p2brel = (const float*)d_in[14];
    const float* p2wroot= (const float*)d_in[15];
    const float* Wf     = (const float*)d_in[16];
    const float* bf     = (const float*)d_in[17];
    float* out = (float*)d_out;
    char* ws = (char*)d_ws;

    const int* src1 = ei;
    const int* dst1 = ei + NE;

    // ---- workspace layout (bytes) ----
    const size_t o0     = 0;          // 40.96 MB: h1 f32; later h2 f32 @+0, xW2b bf16 @+10,240,000
    const size_t o1     = 40960000;   // 10.24 MB: aggb bf16; later h1pb bf16
    const size_t oXb    = 51200000;   // 10,240,000 : xb bf16
    const size_t oW1t   = 61440000;
    const size_t oW2t   = 61702144;
    const size_t oSrc2  = 61964288;
    const size_t oDst2  = 63244288;
    const size_t oMask2 = 64524288;
    const size_t oCsr   = 65804288;
    const size_t oRow   = 67084288;
    const size_t oCur   = 67164352;
    const size_t oDeg   = 67244352;
    const size_t oDinv  = 67324352;
    const size_t oR     = 67404352;
    const size_t oScore1= 67484352;
    const size_t oKeyu  = 67564352;
    const size_t oKept  = 67644352;
    const size_t oInv   = 67724352;
    const size_t oScore2= 67804352;
    const size_t oKeyu2 = 67844352;
    const size_t oKept2 = 67884352;
    const size_t oInv2  = 67924352;
    const size_t oS     = 67964352;
    const size_t oSel   = 67964416;
    const size_t oGpart = 67964480;
    const size_t oEpart = 67964736;
    const size_t oG     = 67964992;
    const size_t oSp    = 67966016;
    const size_t oHist  = 67970112;

    float*  h1    = (float*)(ws + o0);
    float*  h2    = (float*)(ws + o0);
    ushort* xW2b  = (ushort*)(ws + o0 + 10240000);
    ushort* aggb  = (ushort*)(ws + o1);
    ushort* h1pb  = (ushort*)(ws + o1);
    ushort* xb    = (ushort*)(ws + oXb);
    ushort* W1t   = (ushort*)(ws + oW1t);
    ushort* W2t   = (ushort*)(ws + oW2t);
    int*    src2  = (int*)(ws + oSrc2);
    int*    dst2  = (int*)(ws + oDst2);
    int*    mask2 = (int*)(ws + oMask2);
    int*    csr   = (int*)(ws + oCsr);
    int*    row   = (int*)(ws + oRow);
    int*    cur   = (int*)(ws + oCur);
    float*  deg   = (float*)(ws + oDeg);
    float*  dinv  = (float*)(ws + oDinv);
    float*  r     = (float*)(ws + oR);
    float*  score1= (float*)(ws + oScore1);
    unsigned* keyu  = (unsigned*)(ws + oKeyu);
    int*    kept  = (int*)(ws + oKept);
    int*    inv   = (int*)(ws + oInv);
    float*  score2= (float*)(ws + oScore2);
    unsigned* keyu2 = (unsigned*)(ws + oKeyu2);
    int*    kept2 = (int*)(ws + oKept2);
    int*    inv2  = (int*)(ws + oInv2);
    float*  S     = (float*)(ws + oS);
    unsigned* sel  = (unsigned*)(ws + oSel);
    int*    gpart = (int*)(ws + oGpart);
    int*    epart = (int*)(ws + oEpart);
    float*  g     = (float*)(ws + oG);
    float*  Sp    = (float*)(ws + oSp);
    unsigned* hist = (unsigned*)(ws + oHist);

    const int nb1 = cdiv(N1, 1024);  // 20
    const int nb2 = cdiv(K1, 1024);  // 10

    // ================= Stage 1 =================
    f32_to_bf16<<<cdiv(N1 * CIN / 4, 256), 256, 0, stream>>>(x, xb, N1 * CIN / 4);

    fill_i32<<<cdiv(N1, 256), 256, 0, stream>>>(cur, 0, N1);
    fill_i32<<<cdiv(65536, 256), 256, 0, stream>>>((int*)hist, 0, 65536);
    count_deg<<<cdiv(NE, 256), 256, 0, stream>>>(dst1, nullptr, NE, cur);
    dp_partial<<<nb1, 256, 0, stream>>>(cur, N1, gpart);
    scan64k<<<1, 64, 0, stream>>>(nb1, gpart, row + N1);
    dp_final<<<nb1, 256, 0, stream>>>(cur, N1, gpart, row, cur, deg, dinv);
    csr_scatter<<<cdiv(NE, 256), 256, 0, stream>>>(src1, dst1, nullptr, NE, cur, csr);

    aggregate_xb<<<cdiv(N1, 4), 256, 0, stream>>>(row, csr, deg, dinv, xb, aggb, N1);

    conv_transpose_bf16<<<cdiv(CIN * C1, 256), 256, 0, stream>>>(W1, W1t, CIN, C1);
    gemm_bf16_mfma<false><<<dim3(cdiv(N1, 128), C1 / 128), 256, 0, stream>>>(
        aggb, W1t, b1, h1, nullptr, N1, C1, CIN);

    reduce_sum_sq_part<<<NB_RED, 256, 0, stream>>>(h1, N1 * C1 / 4, Sp);
    reduce_final<<<1, 256, 0, stream>>>(Sp, NB_RED, S);
    norm_scores<C1><<<cdiv(N1, 4), 256, 0, stream>>>(h1, N1, S, 1.f / ((float)N1 * C1),
                                                     ln1w, ln1b, p1wrel, p1brel, p1wroot, r, score1);
    gather_score_key<<<cdiv(N1, 256), 256, 0, stream>>>(row, csr, r, score1, keyu, N1);

    hist_hi<<<cdiv(N1, 256), 256, 0, stream>>>(keyu, N1, hist);
    scan_sel1<<<1, 1024, 0, stream>>>(hist, K1, sel);
    hist_lo<<<cdiv(N1, 256), 256, 0, stream>>>(keyu, N1, sel, hist);
    scan_sel2<<<1, 1024, 0, stream>>>(hist, sel);
    sc_partial<<<nb1, 256, 0, stream>>>(keyu, N1, sel, gpart, epart);
    sc_scan_partials<<<1, 64, 0, stream>>>(nb1, gpart, epart);
    sc_final<<<nb1, 256, 0, stream>>>(keyu, N1, sel, gpart, epart, kept, inv);

    pool_apply_rows<<<cdiv(N1, 4), 256, 0, stream>>>(h1, score1, kept, inv, N1, h1pb);
    edge_relabel<<<cdiv(NE, 256), 256, 0, stream>>>(src1, dst1, NE, kept, inv, src2, dst2, mask2);

    // ================= Stage 2 =================
    conv_transpose_bf16<<<cdiv(C1 * C2, 256), 256, 0, stream>>>(W2, W2t, C1, C2);
    gemm_bf16_mfma<true><<<dim3(cdiv(K1, 128), C2 / 128), 256, 0, stream>>>(
        h1pb, W2t, nullptr, nullptr, xW2b, K1, C2, C1);

    fill_i32<<<cdiv(K1, 256), 256, 0, stream>>>(cur, 0, K1);
    count_deg<<<cdiv(NE, 256), 256, 0, stream>>>(dst2, mask2, NE, cur);
    dp_partial<<<nb2, 256, 0, stream>>>(cur, K1, gpart);
    scan64k<<<1, 64, 0, stream>>>(nb2, gpart, row + K1);
    dp_final<<<nb2, 256, 0, stream>>>(cur, K1, gpart, row, cur, deg, dinv);
    csr_scatter<<<cdiv(NE, 256), 256, 0, stream>>>(src2, dst2, mask2, NE, cur, csr);

    aggregate_csr_bf<<<cdiv(K1, 4), 256, 0, stream>>>(row, csr, deg, dinv, xW2b, b2, h2, K1);

    reduce_sum_sq_part<<<NB_RED, 256, 0, stream>>>(h2, K1 * C2 / 4, Sp);
    reduce_final<<<1, 256, 0, stream>>>(Sp, NB_RED, S);
    norm_scores<C2><<<cdiv(K1, 4), 256, 0, stream>>>(h2, K1, S, 1.f / ((float)K1 * C2),
                                                     ln2w, ln2b, p2wrel, p2brel, p2wroot, r, score2);
    gather_score_key<<<cdiv(K1, 256), 256, 0, stream>>>(row, csr, r, score2, keyu2, K1);

    hist_hi<<<cdiv(K1, 256), 256, 0, stream>>>(keyu2, K1, hist);
    scan_sel1<<<1, 1024, 0, stream>>>(hist, K2, sel);
    hist_lo<<<cdiv(K1, 256), 256, 0, stream>>>(keyu2, K1, sel, hist);
    scan_sel2<<<1, 1024, 0, stream>>>(hist, sel);
    sc_partial<<<nb2, 256, 0, stream>>>(keyu2, K1, sel, gpart, epart);
    sc_scan_partials<<<1, 64, 0, stream>>>(nb2, gpart, epart);
    sc_final<<<nb2, 256, 0, stream>>>(keyu2, K1, sel, gpart, epart, kept2, inv2);

    // ================= readout =================
    fill_f32<<<1, 256, 0, stream>>>(g, 0.f, C2);
    colmean_rows<<<cdiv(K1, 256), 256, 0, stream>>>(h2, score2, kept2, K1, 1.f / (float)K2, g);
    final_gemv<<<1, NOUT, 0, stream>>>(g, Wf, bf, out);
}

// Round 8
// 396.808 us; speedup vs baseline: 7.7973x; 1.0591x over previous
//
#include <hip/hip_runtime.h>
#include <math.h>

#define N1 20000
#define NE 320000
#define CIN 256
#define C1 512
#define C2 256
#define K1 10000
#define K2 5000
#define NOUT 128
#define EPSV 1e-5f
#define NB_RED 512
#define CM_ROWS 128

typedef __attribute__((ext_vector_type(8))) short bf16x8;
typedef __attribute__((ext_vector_type(4))) float f32x4;

static inline unsigned cdiv(unsigned a, unsigned b) { return (a + b - 1) / b; }

__device__ inline ushort f2bf(float f) {
    unsigned u = __float_as_uint(f);
    unsigned r = u + 0x7FFFu + ((u >> 16) & 1u);
    return (ushort)(r >> 16);
}
__device__ inline float bf2f(ushort u) { return __uint_as_float(((unsigned)u) << 16); }

// ---------------- fills ----------------
__global__ void fill_i32(int* __restrict__ p, int v, int n) {
    int i = blockIdx.x * blockDim.x + threadIdx.x;
    if (i < n) p[i] = v;
}

// ---------------- f32 -> bf16 ----------------
__global__ void f32_to_bf16(const float* __restrict__ in, ushort* __restrict__ out, int n4) {
    int i = blockIdx.x * blockDim.x + threadIdx.x;
    if (i >= n4) return;
    float4 v = reinterpret_cast<const float4*>(in)[i];
    ushort4 o;
    o.x = f2bf(v.x); o.y = f2bf(v.y); o.z = f2bf(v.z); o.w = f2bf(v.w);
    reinterpret_cast<ushort4*>(out)[i] = o;
}

// ---------------- weight convert+transpose ----------------
__global__ void conv_transpose_bf16(const float* __restrict__ W, ushort* __restrict__ Wt,
                                    int K, int N) {
    int i = blockIdx.x * blockDim.x + threadIdx.x;
    if (i >= K * N) return;
    int k = i / N, n = i % N;
    Wt[(size_t)n * K + k] = f2bf(W[i]);
}

// ---------------- MFMA bf16 GEMM ----------------
template <bool BF16OUT>
__global__ __launch_bounds__(256)
void gemm_bf16_mfma(const ushort* __restrict__ A, const ushort* __restrict__ Bt,
                    const float* __restrict__ bias, float* __restrict__ C,
                    ushort* __restrict__ Cb, int M, int N, int K) {
    constexpr int BM = 128, BN = 128, BK = 32;
    constexpr int LDK = BK + 8;
    __shared__ ushort As[BM * LDK];
    __shared__ ushort Bs[BN * LDK];
    int tid = threadIdx.x;
    int wid = tid >> 6, lane = tid & 63;
    int wr = wid >> 1, wc = wid & 1;
    int bm = blockIdx.x * BM, bn = blockIdx.y * BN;
    int lg = lane >> 4, lm = lane & 15;
    f32x4 zero = {0.f, 0.f, 0.f, 0.f};
    f32x4 acc[4][4];
#pragma unroll
    for (int m = 0; m < 4; ++m)
#pragma unroll
        for (int n = 0; n < 4; ++n) acc[m][n] = zero;

    for (int k0 = 0; k0 < K; k0 += BK) {
#pragma unroll
        for (int it = 0; it < 2; ++it) {
            int task = tid * 2 + it;
            int row = task >> 2, c8 = (task & 3) * 8;
            int gm = bm + row;
            bf16x8 v = {0, 0, 0, 0, 0, 0, 0, 0};
            if (gm < M) v = *(const bf16x8*)&A[(size_t)gm * K + k0 + c8];
            *(bf16x8*)&As[row * LDK + c8] = v;
            int gn = bn + row;
            bf16x8 w = {0, 0, 0, 0, 0, 0, 0, 0};
            if (gn < N) w = *(const bf16x8*)&Bt[(size_t)gn * K + k0 + c8];
            *(bf16x8*)&Bs[row * LDK + c8] = w;
        }
        __syncthreads();
        bf16x8 af[4], bfr[4];
#pragma unroll
        for (int m = 0; m < 4; ++m)
            af[m] = *(bf16x8*)&As[(wr * 64 + m * 16 + lm) * LDK + lg * 8];
#pragma unroll
        for (int n = 0; n < 4; ++n)
            bfr[n] = *(bf16x8*)&Bs[(wc * 64 + n * 16 + lm) * LDK + lg * 8];
#pragma unroll
        for (int m = 0; m < 4; ++m)
#pragma unroll
            for (int n = 0; n < 4; ++n)
                acc[m][n] = __builtin_amdgcn_mfma_f32_16x16x32_bf16(af[m], bfr[n], acc[m][n], 0, 0, 0);
        __syncthreads();
    }
#pragma unroll
    for (int m = 0; m < 4; ++m) {
#pragma unroll
        for (int n = 0; n < 4; ++n) {
            int col = bn + wc * 64 + n * 16 + lm;
            float bv = bias ? bias[col] : 0.f;
#pragma unroll
            for (int r = 0; r < 4; ++r) {
                int row = bm + wr * 64 + m * 16 + lg * 4 + r;
                if (row < M) {
                    float val = acc[m][n][r] + bv;
                    if (BF16OUT) Cb[(size_t)row * N + col] = f2bf(val);
                    else         C[(size_t)row * N + col] = val;
                }
            }
        }
    }
}

// ---------------- CSR build ----------------
__global__ void count_deg(const int* __restrict__ dst, const int* __restrict__ mask, int E,
                          int* __restrict__ cnt) {
    int e = blockIdx.x * blockDim.x + threadIdx.x;
    if (e >= E) return;
    if (mask && !mask[e]) return;
    atomicAdd(&cnt[dst[e]], 1);
}

__global__ void dp_partial(const int* __restrict__ cnt, int n, int* __restrict__ part) {
    int base = blockIdx.x * 1024 + (int)threadIdx.x * 4;
    int s = 0;
#pragma unroll
    for (int t = 0; t < 4; ++t) {
        int i = base + t;
        if (i < n) s += cnt[i];
    }
    for (int off = 32; off > 0; off >>= 1) s += __shfl_down(s, off);
    __shared__ int sg[4];
    int wid = threadIdx.x >> 6;
    if ((threadIdx.x & 63) == 0) sg[wid] = s;
    __syncthreads();
    if (threadIdx.x == 0) part[blockIdx.x] = sg[0] + sg[1] + sg[2] + sg[3];
}

__global__ void scan64k(int nb, int* __restrict__ part, int* __restrict__ row_n) {
    int lane = threadIdx.x;
    int v0 = (lane < nb) ? part[lane] : 0;
    int v = v0;
    for (int off = 1; off < 64; off <<= 1) {
        int vv = __shfl_up(v, off);
        if (lane >= off) v += vv;
    }
    if (lane == nb - 1) row_n[0] = v;
    if (lane < nb) part[lane] = v - v0;
}

__global__ void dp_final(const int* __restrict__ cnt, int n, const int* __restrict__ part,
                         int* __restrict__ rowstart, int* __restrict__ cursor,
                         float* __restrict__ deg, float* __restrict__ dinv) {
    int base = blockIdx.x * 1024 + (int)threadIdx.x * 4;
    int c[4];
    int s = 0;
#pragma unroll
    for (int t = 0; t < 4; ++t) {
        int i = base + t;
        c[t] = (i < n) ? cnt[i] : 0;
        s += c[t];
    }
    int lane = threadIdx.x & 63, wid = threadIdx.x >> 6;
    int si = s;
    for (int off = 1; off < 64; off <<= 1) {
        int vv = __shfl_up(si, off);
        if (lane >= off) si += vv;
    }
    __shared__ int wg[4];
    if (lane == 63) wg[wid] = si;
    __syncthreads();
    int woff = 0;
    for (int w = 0; w < wid; ++w) woff += wg[w];
    int excl = part[blockIdx.x] + (si - s) + woff;
#pragma unroll
    for (int t = 0; t < 4; ++t) {
        int i = base + t;
        if (i < n) {
            rowstart[i] = excl;
            cursor[i] = excl;
            float dg = (float)c[t] + 2.0f;
            deg[i] = dg;
            dinv[i] = rsqrtf(dg);
        }
        excl += c[t];
    }
}

__global__ void csr_scatter(const int* __restrict__ src, const int* __restrict__ dst,
                            const int* __restrict__ mask, int E,
                            int* __restrict__ cursor, int* __restrict__ csr_src) {
    int e = blockIdx.x * blockDim.x + threadIdx.x;
    if (e >= E) return;
    if (mask && !mask[e]) return;
    int pos = atomicAdd(&cursor[dst[e]], 1);
    csr_src[pos] = src[e];
}

// ---------------- stage-1 aggregation: 8-deep pipelined gather (bf16 in/out) ----------------
__global__ void aggregate_xb(const int* __restrict__ rowstart, const int* __restrict__ csr_src,
                             const float* __restrict__ deg, const float* __restrict__ dinv,
                             const ushort* __restrict__ xb, ushort* __restrict__ out, int n) {
    int node = blockIdx.x * (blockDim.x >> 6) + ((int)threadIdx.x >> 6);
    if (node >= n) return;
    int lane = threadIdx.x & 63;
    int beg = rowstart[node], end = rowstart[node + 1];
    float di = dinv[node];
    float4 acc = make_float4(0.f, 0.f, 0.f, 0.f);
    int j = beg;
    for (; j + 8 <= end; j += 8) {
        int s[8];
#pragma unroll
        for (int u = 0; u < 8; ++u) s[u] = csr_src[j + u];
        float c[8];
#pragma unroll
        for (int u = 0; u < 8; ++u) c[u] = dinv[s[u]] * di;
        ushort4 t[8];
#pragma unroll
        for (int u = 0; u < 8; ++u)
            t[u] = reinterpret_cast<const ushort4*>(&xb[(size_t)s[u] * CIN])[lane];
#pragma unroll
        for (int u = 0; u < 8; ++u) {
            acc.x += c[u] * bf2f(t[u].x);
            acc.y += c[u] * bf2f(t[u].y);
            acc.z += c[u] * bf2f(t[u].z);
            acc.w += c[u] * bf2f(t[u].w);
        }
    }
    for (; j < end; ++j) {
        int s = csr_src[j];
        float coef = dinv[s] * di;
        ushort4 t = reinterpret_cast<const ushort4*>(&xb[(size_t)s * CIN])[lane];
        acc.x += coef * bf2f(t.x);
        acc.y += coef * bf2f(t.y);
        acc.z += coef * bf2f(t.z);
        acc.w += coef * bf2f(t.w);
    }
    float self = 2.0f / deg[node];
    ushort4 t = reinterpret_cast<const ushort4*>(&xb[(size_t)node * CIN])[lane];
    acc.x += self * bf2f(t.x);
    acc.y += self * bf2f(t.y);
    acc.z += self * bf2f(t.z);
    acc.w += self * bf2f(t.w);
    ushort4 o;
    o.x = f2bf(acc.x); o.y = f2bf(acc.y); o.z = f2bf(acc.z); o.w = f2bf(acc.w);
    reinterpret_cast<ushort4*>(&out[(size_t)node * CIN])[lane] = o;
}

// ---------------- stage-2 aggregation: 8-deep pipelined gather, f32 out + bias + self ----------------
__global__ void aggregate_csr_bf(const int* __restrict__ rowstart, const int* __restrict__ csr_src,
                                 const float* __restrict__ deg, const float* __restrict__ dinv,
                                 const ushort* __restrict__ xWb, const float* __restrict__ b,
                                 float* __restrict__ out, int n) {
    int node = blockIdx.x * (blockDim.x >> 6) + ((int)threadIdx.x >> 6);
    if (node >= n) return;
    int lane = threadIdx.x & 63;
    int beg = rowstart[node], end = rowstart[node + 1];
    float di = dinv[node];
    float4 acc = make_float4(0.f, 0.f, 0.f, 0.f);
    int j = beg;
    for (; j + 8 <= end; j += 8) {
        int s[8];
#pragma unroll
        for (int u = 0; u < 8; ++u) s[u] = csr_src[j + u];
        float c[8];
#pragma unroll
        for (int u = 0; u < 8; ++u) c[u] = dinv[s[u]] * di;
        ushort4 t[8];
#pragma unroll
        for (int u = 0; u < 8; ++u)
            t[u] = reinterpret_cast<const ushort4*>(&xWb[(size_t)s[u] * C2])[lane];
#pragma unroll
        for (int u = 0; u < 8; ++u) {
            acc.x += c[u] * bf2f(t[u].x);
            acc.y += c[u] * bf2f(t[u].y);
            acc.z += c[u] * bf2f(t[u].z);
            acc.w += c[u] * bf2f(t[u].w);
        }
    }
    for (; j < end; ++j) {
        int s = csr_src[j];
        float coef = dinv[s] * di;
        ushort4 t = reinterpret_cast<const ushort4*>(&xWb[(size_t)s * C2])[lane];
        acc.x += coef * bf2f(t.x);
        acc.y += coef * bf2f(t.y);
        acc.z += coef * bf2f(t.z);
        acc.w += coef * bf2f(t.w);
    }
    float self = 2.0f / deg[node];
    ushort4 t = reinterpret_cast<const ushort4*>(&xWb[(size_t)node * C2])[lane];
    float4 bb = reinterpret_cast<const float4*>(b)[lane];
    float4 o;
    o.x = acc.x + self * bf2f(t.x) + bb.x;
    o.y = acc.y + self * bf2f(t.y) + bb.y;
    o.z = acc.z + self * bf2f(t.z) + bb.z;
    o.w = acc.w + self * bf2f(t.w) + bb.w;
    reinterpret_cast<float4*>(&out[(size_t)node * C2])[lane] = o;
}

// ---------------- graph-norm: two-stage sum & sumsq ----------------
__global__ void reduce_sum_sq_part(const float* __restrict__ x, int n4, float* __restrict__ Sp) {
    float s = 0.f, q = 0.f;
    const float4* x4 = reinterpret_cast<const float4*>(x);
    for (int i = blockIdx.x * blockDim.x + threadIdx.x; i < n4; i += gridDim.x * blockDim.x) {
        float4 v = x4[i];
        s += v.x + v.y + v.z + v.w;
        q += v.x * v.x + v.y * v.y + v.z * v.z + v.w * v.w;
    }
    __shared__ float ls[256], lq[256];
    ls[threadIdx.x] = s; lq[threadIdx.x] = q;
    __syncthreads();
    for (int off = 128; off > 0; off >>= 1) {
        if ((int)threadIdx.x < off) {
            ls[threadIdx.x] += ls[threadIdx.x + off];
            lq[threadIdx.x] += lq[threadIdx.x + off];
        }
        __syncthreads();
    }
    if (threadIdx.x == 0) {
        Sp[2 * blockIdx.x] = ls[0];
        Sp[2 * blockIdx.x + 1] = lq[0];
    }
}

__global__ void reduce_final(const float* __restrict__ Sp, int nb, float* __restrict__ S) {
    float s = 0.f, q = 0.f;
    for (int i = threadIdx.x; i < nb; i += 256) {
        s += Sp[2 * i];
        q += Sp[2 * i + 1];
    }
    __shared__ float ls[256], lq[256];
    ls[threadIdx.x] = s; lq[threadIdx.x] = q;
    __syncthreads();
    for (int off = 128; off > 0; off >>= 1) {
        if ((int)threadIdx.x < off) {
            ls[threadIdx.x] += ls[threadIdx.x + off];
            lq[threadIdx.x] += lq[threadIdx.x + off];
        }
        __syncthreads();
    }
    if (threadIdx.x == 0) { S[0] = ls[0]; S[1] = lq[0]; }
}

// ---------------- fused norm+relu+scores ----------------
template <int C>
__global__ void norm_scores(float* __restrict__ h, int n, const float* __restrict__ S,
                            float inv_cnt, const float* __restrict__ lnw,
                            const float* __restrict__ lnb, const float* __restrict__ wrel,
                            const float* __restrict__ brel, const float* __restrict__ wroot,
                            float* __restrict__ r, float* __restrict__ score) {
    int node = blockIdx.x * (blockDim.x >> 6) + ((int)threadIdx.x >> 6);
    if (node >= n) return;
    int lane = threadIdx.x & 63;
    float mean = S[0] * inv_cnt;
    float var = S[1] * inv_cnt - mean * mean;
    float istd = 1.f / (sqrtf(fmaxf(var, 0.f)) + EPSV);
    float4* row = reinterpret_cast<float4*>(&h[(size_t)node * C]);
    float sr = 0.f, st = 0.f;
#pragma unroll
    for (int kk = 0; kk < C / 256; ++kk) {
        int idx = lane + 64 * kk;
        float4 v = row[idx];
        float4 w = reinterpret_cast<const float4*>(lnw)[idx];
        float4 bb = reinterpret_cast<const float4*>(lnb)[idx];
        float4 w4 = reinterpret_cast<const float4*>(wrel)[idx];
        float4 o4 = reinterpret_cast<const float4*>(wroot)[idx];
        v.x = fmaxf((v.x - mean) * istd * w.x + bb.x, 0.f);
        v.y = fmaxf((v.y - mean) * istd * w.y + bb.y, 0.f);
        v.z = fmaxf((v.z - mean) * istd * w.z + bb.z, 0.f);
        v.w = fmaxf((v.w - mean) * istd * w.w + bb.w, 0.f);
        sr += v.x * w4.x + v.y * w4.y + v.z * w4.z + v.w * w4.w;
        st += v.x * o4.x + v.y * o4.y + v.z * o4.z + v.w * o4.w;
        row[idx] = v;
    }
    for (int off = 32; off > 0; off >>= 1) {
        sr += __shfl_down(sr, off);
        st += __shfl_down(st, off);
    }
    if (lane == 0) {
        r[node] = sr;
        score[node] = st + brel[0];
    }
}

// ---------------- gather score over CSR + keyify (4-deep pipelined) ----------------
__global__ void gather_score_key(const int* __restrict__ rowstart, const int* __restrict__ csr_src,
                                 const float* __restrict__ r, float* __restrict__ score,
                                 unsigned* __restrict__ key, int n) {
    int i = blockIdx.x * blockDim.x + threadIdx.x;
    if (i >= n) return;
    float s = score[i];
    int beg = rowstart[i], end = rowstart[i + 1];
    int j = beg;
    for (; j + 4 <= end; j += 4) {
        int s0 = csr_src[j], s1 = csr_src[j + 1], s2 = csr_src[j + 2], s3 = csr_src[j + 3];
        s += r[s0] + r[s1] + r[s2] + r[s3];
    }
    for (; j < end; ++j) s += r[csr_src[j]];
    score[i] = s;
    unsigned u = __float_as_uint(s);
    key[i] = (u & 0x80000000u) ? ~u : (u | 0x80000000u);
}

// ---------------- two-pass 16-bit radix select (multi-block) ----------------
__global__ void hist_hi(const unsigned* __restrict__ key, int n, unsigned* __restrict__ hist) {
    int i = blockIdx.x * blockDim.x + threadIdx.x;
    if (i >= n) return;
    atomicAdd(&hist[(~key[i]) >> 16], 1u);
}

__global__ void scan_sel1(unsigned* __restrict__ hist, unsigned k, unsigned* __restrict__ sel) {
    __shared__ unsigned ps[1024];
    __shared__ int owner;
    int t = threadIdx.x;
    int base = t * 64;
    unsigned s = 0;
    for (int b = 0; b < 64; ++b) s += hist[base + b];
    ps[t] = s;
    __syncthreads();
    for (int off = 1; off < 1024; off <<= 1) {
        unsigned add = (t >= off) ? ps[t - off] : 0u;
        __syncthreads();
        ps[t] += add;
        __syncthreads();
    }
    unsigned incl = ps[t], excl = incl - s;
    if (excl < k && k <= incl) owner = t;
    __syncthreads();
    if (t == owner) {
        unsigned cum = excl;
        for (int b = 0; b < 64; ++b) {
            unsigned c = hist[base + b];
            if (cum + c >= k) {
                sel[2] = 0xFFFFu ^ (unsigned)(base + b);
                sel[3] = k - cum;
                break;
            }
            cum += c;
        }
    }
    __syncthreads();
    for (int b = 0; b < 64; ++b) hist[base + b] = 0u;
}

__global__ void hist_lo(const unsigned* __restrict__ key, int n, const unsigned* __restrict__ sel,
                        unsigned* __restrict__ hist) {
    int i = blockIdx.x * blockDim.x + threadIdx.x;
    if (i >= n) return;
    unsigned u = key[i];
    if ((u >> 16) == sel[2]) atomicAdd(&hist[0xFFFFu ^ (u & 0xFFFFu)], 1u);
}

__global__ void scan_sel2(unsigned* __restrict__ hist, unsigned* __restrict__ sel) {
    __shared__ unsigned ps[1024];
    __shared__ int owner;
    int t = threadIdx.x;
    unsigned k = sel[3];
    unsigned H = sel[2];
    int base = t * 64;
    unsigned s = 0;
    for (int b = 0; b < 64; ++b) s += hist[base + b];
    ps[t] = s;
    __syncthreads();
    for (int off = 1; off < 1024; off <<= 1) {
        unsigned add = (t >= off) ? ps[t - off] : 0u;
        __syncthreads();
        ps[t] += add;
        __syncthreads();
    }
    unsigned incl = ps[t], excl = incl - s;
    if (excl < k && k <= incl) owner = t;
    __syncthreads();
    if (t == owner) {
        unsigned cum = excl;
        for (int b = 0; b < 64; ++b) {
            unsigned c = hist[base + b];
            if (cum + c >= k) {
                sel[0] = (H << 16) | (0xFFFFu ^ (unsigned)(base + b));
                sel[1] = k - cum;
                break;
            }
            cum += c;
        }
    }
    __syncthreads();
    for (int b = 0; b < 64; ++b) hist[base + b] = 0u;
}

// ---------------- multi-block deterministic select + compact ----------------
__global__ void sc_partial(const unsigned* __restrict__ key, int n, const unsigned* __restrict__ sel,
                           int* __restrict__ gpart, int* __restrict__ epart) {
    unsigned thr = sel[0];
    int base = blockIdx.x * 1024 + (int)threadIdx.x * 4;
    int gs = 0, es = 0;
#pragma unroll
    for (int t = 0; t < 4; ++t) {
        int i = base + t;
        if (i < n) {
            unsigned u = key[i];
            gs += (u > thr); es += (u == thr);
        }
    }
    for (int off = 32; off > 0; off >>= 1) {
        gs += __shfl_down(gs, off);
        es += __shfl_down(es, off);
    }
    __shared__ int sg[4], se[4];
    int wid = threadIdx.x >> 6;
    if ((threadIdx.x & 63) == 0) { sg[wid] = gs; se[wid] = es; }
    __syncthreads();
    if (threadIdx.x == 0) {
        gpart[blockIdx.x] = sg[0] + sg[1] + sg[2] + sg[3];
        epart[blockIdx.x] = se[0] + se[1] + se[2] + se[3];
    }
}

__global__ void sc_scan_partials(int nb, int* __restrict__ gpart, int* __restrict__ epart) {
    int lane = threadIdx.x;
    int g0 = (lane < nb) ? gpart[lane] : 0;
    int e0 = (lane < nb) ? epart[lane] : 0;
    int g = g0, e = e0;
    for (int off = 1; off < 64; off <<= 1) {
        int gg = __shfl_up(g, off), ee = __shfl_up(e, off);
        if (lane >= off) { g += gg; e += ee; }
    }
    if (lane < nb) { gpart[lane] = g - g0; epart[lane] = e - e0; }
}

__global__ void sc_final(const unsigned* __restrict__ key, int n, const unsigned* __restrict__ sel,
                         const int* __restrict__ gpart, const int* __restrict__ epart,
                         int* __restrict__ kept, int* __restrict__ inv) {
    unsigned thr = sel[0];
    int tie = (int)sel[1];
    int base = blockIdx.x * 1024 + (int)threadIdx.x * 4;
    int gl[4], el[4];
    int gs = 0, es = 0;
#pragma unroll
    for (int t = 0; t < 4; ++t) {
        int i = base + t;
        gl[t] = 0; el[t] = 0;
        if (i < n) {
            unsigned u = key[i];
            gl[t] = (u > thr); el[t] = (u == thr);
        }
        gs += gl[t]; es += el[t];
    }
    int lane = threadIdx.x & 63, wid = threadIdx.x >> 6;
    int gi = gs, ei = es;
    for (int off = 1; off < 64; off <<= 1) {
        int gg = __shfl_up(gi, off), ee = __shfl_up(ei, off);
        if (lane >= off) { gi += gg; ei += ee; }
    }
    __shared__ int wg[4], we[4];
    if (lane == 63) { wg[wid] = gi; we[wid] = ei; }
    __syncthreads();
    int wgo = 0, weo = 0;
    for (int w = 0; w < wid; ++w) { wgo += wg[w]; weo += we[w]; }
    int gp = gpart[blockIdx.x] + (gi - gs) + wgo;
    int ep = epart[blockIdx.x] + (ei - es) + weo;
#pragma unroll
    for (int t = 0; t < 4; ++t) {
        int i = base + t;
        if (i < n) {
            int keep = gl[t] | (el[t] & ((ep < tie) ? 1 : 0));
            kept[i] = keep;
            inv[i] = gp + ((ep < tie) ? ep : tie);
        }
        gp += gl[t]; ep += el[t];
    }
}

// ---------------- pool apply: wave per node, bf16 out (C=512) ----------------
__global__ void pool_apply_rows(const float* __restrict__ h, const float* __restrict__ score,
                                const int* __restrict__ kept, const int* __restrict__ inv,
                                int n, ushort* __restrict__ hp) {
    int node = blockIdx.x * (blockDim.x >> 6) + ((int)threadIdx.x >> 6);
    if (node >= n) return;
    if (!kept[node]) return;
    int lane = threadIdx.x & 63;
    float tw = tanhf(score[node]);
    const float4* src = reinterpret_cast<const float4*>(&h[(size_t)node * C1]);
    ushort4* dst = reinterpret_cast<ushort4*>(&hp[(size_t)inv[node] * C1]);
#pragma unroll
    for (int v = 0; v < 2; ++v) {
        float4 a = src[lane + 64 * v];
        ushort4 o;
        o.x = f2bf(a.x * tw); o.y = f2bf(a.y * tw);
        o.z = f2bf(a.z * tw); o.w = f2bf(a.w * tw);
        dst[lane + 64 * v] = o;
    }
}

// ---------------- edge relabel ----------------
__global__ void edge_relabel(const int* __restrict__ src, const int* __restrict__ dst, int E,
                             const int* __restrict__ kept, const int* __restrict__ inv,
                             int* __restrict__ src2, int* __restrict__ dst2,
                             int* __restrict__ mask2) {
    int e = blockIdx.x * blockDim.x + threadIdx.x;
    if (e >= E) return;
    int s = src[e], d = dst[e];
    int m = kept[s] & kept[d];
    mask2[e] = m;
    src2[e] = m ? inv[s] : 0;
    dst2[e] = m ? inv[d] : 0;
}

// ---------------- masked weighted column mean: two-stage, no atomics ----------------
// part: each block handles CM_ROWS rows, writes partial [256] to Gp[b]
__global__ void colmean_part(const float* __restrict__ h, const float* __restrict__ score,
                             const int* __restrict__ kept, int n, float* __restrict__ Gp) {
    __shared__ float w[CM_ROWS];
    int i0 = blockIdx.x * CM_ROWS;
    int t = threadIdx.x;
    for (int i = t; i < CM_ROWS; i += 256) {
        int idx = i0 + i;
        w[i] = (idx < n && kept[idx]) ? tanhf(score[idx]) : 0.f;
    }
    __syncthreads();
    float acc = 0.f;
    int rows = min(CM_ROWS, n - i0);
#pragma unroll 8
    for (int ri = 0; ri < rows; ++ri)
        acc = fmaf(w[ri], h[(size_t)(i0 + ri) * C2 + t], acc);
    Gp[blockIdx.x * 256 + t] = acc;
}

__global__ void colmean_final(const float* __restrict__ Gp, int nb, float invk,
                              float* __restrict__ g) {
    int t = threadIdx.x;  // 256
    float s = 0.f;
    for (int b = 0; b < nb; ++b) s += Gp[b * 256 + t];
    g[t] = s * invk;
}

__global__ void final_gemv(const float* __restrict__ g, const float* __restrict__ Wf,
                           const float* __restrict__ bf, float* __restrict__ out) {
    int j = threadIdx.x;  // 128
    float s = bf[j];
    for (int c = 0; c < 256; ++c) s += g[c] * Wf[c * NOUT + j];
    out[j] = s;
}

// =======================================================================================
extern "C" void kernel_launch(void* const* d_in, const int* in_sizes, int n_in,
                              void* d_out, int out_size, void* d_ws, size_t ws_size,
                              hipStream_t stream) {
    const float* x      = (const float*)d_in[0];
    const int*   ei     = (const int*)d_in[1];
    const float* W1     = (const float*)d_in[2];
    const float* b1     = (const float*)d_in[3];
    const float* ln1w   = (const float*)d_in[4];
    const float* ln1b   = (const float*)d_in[5];
    const float* p1wrel = (const float*)d_in[6];
    const float* p1brel = (const float*)d_in[7];
    const float* p1wroot= (const float*)d_in[8];
    const float* W2     = (const float*)d_in[9];
    const float* b2     = (const float*)d_in[10];
    const float* ln2w   = (const float*)d_in[11];
    const float* ln2b   = (const float*)d_in[12];
    const float* p2wrel = (const float*)d_in[13];
    const float* p2brel = (const float*)d_in[14];
    const float* p2wroot= (const float*)d_in[15];
    const float* Wf     = (const float*)d_in[16];
    const float* bf     = (const float*)d_in[17];
    float* out = (float*)d_out;
    char* ws = (char*)d_ws;

    const int* src1 = ei;
    const int* dst1 = ei + NE;

    // ---- workspace layout (bytes) ----
    const size_t o0     = 0;          // 40.96 MB: h1 f32; later h2 f32 @+0, xW2b bf16 @+10,240,000
    const size_t o1     = 40960000;   // 10.24 MB: aggb bf16; later h1pb bf16
    const size_t oXb    = 51200000;   // 10,240,000 : xb bf16
    const size_t oW1t   = 61440000;
    const size_t oW2t   = 61702144;
    const size_t oSrc2  = 61964288;
    const size_t oDst2  = 63244288;
    const size_t oMask2 = 64524288;
    const size_t oCsr   = 65804288;
    const size_t oRow   = 67084288;
    const size_t oCur   = 67164352;
    const size_t oDeg   = 67244352;
    const size_t oDinv  = 67324352;
    const size_t oR     = 67404352;
    const size_t oScore1= 67484352;
    const size_t oKeyu  = 67564352;
    const size_t oKept  = 67644352;
    const size_t oInv   = 67724352;
    const size_t oScore2= 67804352;
    const size_t oKeyu2 = 67844352;
    const size_t oKept2 = 67884352;
    const size_t oInv2  = 67924352;
    const size_t oS     = 67964352;
    const size_t oSel   = 67964416;
    const size_t oGpart = 67964480;
    const size_t oEpart = 67964736;
    const size_t oG     = 67964992;
    const size_t oSp    = 67966016;   // 4,096
    const size_t oHist  = 67970112;   // 262,144
    const size_t oGp    = 68232256;   // 81,920 : colmean partials (80 x 256 f32)

    float*  h1    = (float*)(ws + o0);
    float*  h2    = (float*)(ws + o0);
    ushort* xW2b  = (ushort*)(ws + o0 + 10240000);
    ushort* aggb  = (ushort*)(ws + o1);
    ushort* h1pb  = (ushort*)(ws + o1);
    ushort* xb    = (ushort*)(ws + oXb);
    ushort* W1t   = (ushort*)(ws + oW1t);
    ushort* W2t   = (ushort*)(ws + oW2t);
    int*    src2  = (int*)(ws + oSrc2);
    int*    dst2  = (int*)(ws + oDst2);
    int*    mask2 = (int*)(ws + oMask2);
    int*    csr   = (int*)(ws + oCsr);
    int*    row   = (int*)(ws + oRow);
    int*    cur   = (int*)(ws + oCur);
    float*  deg   = (float*)(ws + oDeg);
    float*  dinv  = (float*)(ws + oDinv);
    float*  r     = (float*)(ws + oR);
    float*  score1= (float*)(ws + oScore1);
    unsigned* keyu  = (unsigned*)(ws + oKeyu);
    int*    kept  = (int*)(ws + oKept);
    int*    inv   = (int*)(ws + oInv);
    float*  score2= (float*)(ws + oScore2);
    unsigned* keyu2 = (unsigned*)(ws + oKeyu2);
    int*    kept2 = (int*)(ws + oKept2);
    int*    inv2  = (int*)(ws + oInv2);
    float*  S     = (float*)(ws + oS);
    unsigned* sel  = (unsigned*)(ws + oSel);
    int*    gpart = (int*)(ws + oGpart);
    int*    epart = (int*)(ws + oEpart);
    float*  g     = (float*)(ws + oG);
    float*  Sp    = (float*)(ws + oSp);
    unsigned* hist = (unsigned*)(ws + oHist);
    float*  Gp    = (float*)(ws + oGp);

    const int nb1 = cdiv(N1, 1024);  // 20
    const int nb2 = cdiv(K1, 1024);  // 10
    const int nbc = cdiv(K1, CM_ROWS);  // 79

    // ================= Stage 1 =================
    f32_to_bf16<<<cdiv(N1 * CIN / 4, 256), 256, 0, stream>>>(x, xb, N1 * CIN / 4);

    fill_i32<<<cdiv(N1, 256), 256, 0, stream>>>(cur, 0, N1);
    fill_i32<<<cdiv(65536, 256), 256, 0, stream>>>((int*)hist, 0, 65536);
    count_deg<<<cdiv(NE, 256), 256, 0, stream>>>(dst1, nullptr, NE, cur);
    dp_partial<<<nb1, 256, 0, stream>>>(cur, N1, gpart);
    scan64k<<<1, 64, 0, stream>>>(nb1, gpart, row + N1);
    dp_final<<<nb1, 256, 0, stream>>>(cur, N1, gpart, row, cur, deg, dinv);
    csr_scatter<<<cdiv(NE, 256), 256, 0, stream>>>(src1, dst1, nullptr, NE, cur, csr);

    aggregate_xb<<<cdiv(N1, 4), 256, 0, stream>>>(row, csr, deg, dinv, xb, aggb, N1);

    conv_transpose_bf16<<<cdiv(CIN * C1, 256), 256, 0, stream>>>(W1, W1t, CIN, C1);
    gemm_bf16_mfma<false><<<dim3(cdiv(N1, 128), C1 / 128), 256, 0, stream>>>(
        aggb, W1t, b1, h1, nullptr, N1, C1, CIN);

    reduce_sum_sq_part<<<NB_RED, 256, 0, stream>>>(h1, N1 * C1 / 4, Sp);
    reduce_final<<<1, 256, 0, stream>>>(Sp, NB_RED, S);
    norm_scores<C1><<<cdiv(N1, 4), 256, 0, stream>>>(h1, N1, S, 1.f / ((float)N1 * C1),
                                                     ln1w, ln1b, p1wrel, p1brel, p1wroot, r, score1);
    gather_score_key<<<cdiv(N1, 256), 256, 0, stream>>>(row, csr, r, score1, keyu, N1);

    hist_hi<<<cdiv(N1, 256), 256, 0, stream>>>(keyu, N1, hist);
    scan_sel1<<<1, 1024, 0, stream>>>(hist, K1, sel);
    hist_lo<<<cdiv(N1, 256), 256, 0, stream>>>(keyu, N1, sel, hist);
    scan_sel2<<<1, 1024, 0, stream>>>(hist, sel);
    sc_partial<<<nb1, 256, 0, stream>>>(keyu, N1, sel, gpart, epart);
    sc_scan_partials<<<1, 64, 0, stream>>>(nb1, gpart, epart);
    sc_final<<<nb1, 256, 0, stream>>>(keyu, N1, sel, gpart, epart, kept, inv);

    pool_apply_rows<<<cdiv(N1, 4), 256, 0, stream>>>(h1, score1, kept, inv, N1, h1pb);
    edge_relabel<<<cdiv(NE, 256), 256, 0, stream>>>(src1, dst1, NE, kept, inv, src2, dst2, mask2);

    // ================= Stage 2 =================
    conv_transpose_bf16<<<cdiv(C1 * C2, 256), 256, 0, stream>>>(W2, W2t, C1, C2);
    gemm_bf16_mfma<true><<<dim3(cdiv(K1, 128), C2 / 128), 256, 0, stream>>>(
        h1pb, W2t, nullptr, nullptr, xW2b, K1, C2, C1);

    fill_i32<<<cdiv(K1, 256), 256, 0, stream>>>(cur, 0, K1);
    count_deg<<<cdiv(NE, 256), 256, 0, stream>>>(dst2, mask2, NE, cur);
    dp_partial<<<nb2, 256, 0, stream>>>(cur, K1, gpart);
    scan64k<<<1, 64, 0, stream>>>(nb2, gpart, row + K1);
    dp_final<<<nb2, 256, 0, stream>>>(cur, K1, gpart, row, cur, deg, dinv);
    csr_scatter<<<cdiv(NE, 256), 256, 0, stream>>>(src2, dst2, mask2, NE, cur, csr);

    aggregate_csr_bf<<<cdiv(K1, 4), 256, 0, stream>>>(row, csr, deg, dinv, xW2b, b2, h2, K1);

    reduce_sum_sq_part<<<NB_RED, 256, 0, stream>>>(h2, K1 * C2 / 4, Sp);
    reduce_final<<<1, 256, 0, stream>>>(Sp, NB_RED, S);
    norm_scores<C2><<<cdiv(K1, 4), 256, 0, stream>>>(h2, K1, S, 1.f / ((float)K1 * C2),
                                                     ln2w, ln2b, p2wrel, p2brel, p2wroot, r, score2);
    gather_score_key<<<cdiv(K1, 256), 256, 0, stream>>>(row, csr, r, score2, keyu2, K1);

    hist_hi<<<cdiv(K1, 256), 256, 0, stream>>>(keyu2, K1, hist);
    scan_sel1<<<1, 1024, 0, stream>>>(hist, K2, sel);
    hist_lo<<<cdiv(K1, 256), 256, 0, stream>>>(keyu2, K1, sel, hist);
    scan_sel2<<<1, 1024, 0, stream>>>(hist, sel);
    sc_partial<<<nb2, 256, 0, stream>>>(keyu2, K1, sel, gpart, epart);
    sc_scan_partials<<<1, 64, 0, stream>>>(nb2, gpart, epart);
    sc_final<<<nb2, 256, 0, stream>>>(keyu2, K1, sel, gpart, epart, kept2, inv2);

    // ================= readout =================
    colmean_part<<<nbc, 256, 0, stream>>>(h2, score2, kept2, K1, Gp);
    colmean_final<<<1, 256, 0, stream>>>(Gp, nbc, 1.f / (float)K2, g);
    final_gemv<<<1, NOUT, 0, stream>>>(g, Wf, bf, out);
}

// Round 9
// 385.895 us; speedup vs baseline: 8.0178x; 1.0283x over previous
//
#include <hip/hip_runtime.h>
#include <math.h>

#define N1 20000
#define NE 320000
#define CIN 256
#define C1 512
#define C2 256
#define K1 10000
#define K2 5000
#define NOUT 128
#define EPSV 1e-5f
#define CM_ROWS 128

typedef __attribute__((ext_vector_type(8))) short bf16x8;
typedef __attribute__((ext_vector_type(4))) float f32x4;

static inline unsigned cdiv(unsigned a, unsigned b) { return (a + b - 1) / b; }

__device__ inline ushort f2bf(float f) {
    unsigned u = __float_as_uint(f);
    unsigned r = u + 0x7FFFu + ((u >> 16) & 1u);
    return (ushort)(r >> 16);
}
__device__ inline float bf2f(ushort u) { return __uint_as_float(((unsigned)u) << 16); }

// ---------------- fills ----------------
__global__ void fill_i32(int* __restrict__ p, int v, int n) {
    int i = blockIdx.x * blockDim.x + threadIdx.x;
    if (i < n) p[i] = v;
}

// ---------------- f32 -> bf16 ----------------
__global__ void f32_to_bf16(const float* __restrict__ in, ushort* __restrict__ out, int n4) {
    int i = blockIdx.x * blockDim.x + threadIdx.x;
    if (i >= n4) return;
    float4 v = reinterpret_cast<const float4*>(in)[i];
    ushort4 o;
    o.x = f2bf(v.x); o.y = f2bf(v.y); o.z = f2bf(v.z); o.w = f2bf(v.w);
    reinterpret_cast<ushort4*>(out)[i] = o;
}

// ---------------- weight convert+transpose ----------------
__global__ void conv_transpose_bf16(const float* __restrict__ W, ushort* __restrict__ Wt,
                                    int K, int N) {
    int i = blockIdx.x * blockDim.x + threadIdx.x;
    if (i >= K * N) return;
    int k = i / N, n = i % N;
    Wt[(size_t)n * K + k] = f2bf(W[i]);
}

// ---------------- MFMA bf16 GEMM (optional fused sum/sumsq stats) ----------------
template <bool BF16OUT, bool STATS>
__global__ __launch_bounds__(256)
void gemm_bf16_mfma(const ushort* __restrict__ A, const ushort* __restrict__ Bt,
                    const float* __restrict__ bias, float* __restrict__ C,
                    ushort* __restrict__ Cb, float* __restrict__ Sp, int M, int N, int K) {
    constexpr int BM = 128, BN = 128, BK = 32;
    constexpr int LDK = BK + 8;
    __shared__ ushort As[BM * LDK];
    __shared__ ushort Bs[BN * LDK];
    int tid = threadIdx.x;
    int wid = tid >> 6, lane = tid & 63;
    int wr = wid >> 1, wc = wid & 1;
    int bm = blockIdx.x * BM, bn = blockIdx.y * BN;
    int lg = lane >> 4, lm = lane & 15;
    f32x4 zero = {0.f, 0.f, 0.f, 0.f};
    f32x4 acc[4][4];
#pragma unroll
    for (int m = 0; m < 4; ++m)
#pragma unroll
        for (int n = 0; n < 4; ++n) acc[m][n] = zero;

    for (int k0 = 0; k0 < K; k0 += BK) {
#pragma unroll
        for (int it = 0; it < 2; ++it) {
            int task = tid * 2 + it;
            int row = task >> 2, c8 = (task & 3) * 8;
            int gm = bm + row;
            bf16x8 v = {0, 0, 0, 0, 0, 0, 0, 0};
            if (gm < M) v = *(const bf16x8*)&A[(size_t)gm * K + k0 + c8];
            *(bf16x8*)&As[row * LDK + c8] = v;
            int gn = bn + row;
            bf16x8 w = {0, 0, 0, 0, 0, 0, 0, 0};
            if (gn < N) w = *(const bf16x8*)&Bt[(size_t)gn * K + k0 + c8];
            *(bf16x8*)&Bs[row * LDK + c8] = w;
        }
        __syncthreads();
        bf16x8 af[4], bfr[4];
#pragma unroll
        for (int m = 0; m < 4; ++m)
            af[m] = *(bf16x8*)&As[(wr * 64 + m * 16 + lm) * LDK + lg * 8];
#pragma unroll
        for (int n = 0; n < 4; ++n)
            bfr[n] = *(bf16x8*)&Bs[(wc * 64 + n * 16 + lm) * LDK + lg * 8];
#pragma unroll
        for (int m = 0; m < 4; ++m)
#pragma unroll
            for (int n = 0; n < 4; ++n)
                acc[m][n] = __builtin_amdgcn_mfma_f32_16x16x32_bf16(af[m], bfr[n], acc[m][n], 0, 0, 0);
        __syncthreads();
    }
    float ls = 0.f, lq = 0.f;
#pragma unroll
    for (int m = 0; m < 4; ++m) {
#pragma unroll
        for (int n = 0; n < 4; ++n) {
            int col = bn + wc * 64 + n * 16 + lm;
            float bv = bias ? bias[col] : 0.f;
#pragma unroll
            for (int r = 0; r < 4; ++r) {
                int row = bm + wr * 64 + m * 16 + lg * 4 + r;
                if (row < M) {
                    float val = acc[m][n][r] + bv;
                    if (BF16OUT) Cb[(size_t)row * N + col] = f2bf(val);
                    else         C[(size_t)row * N + col] = val;
                    if (STATS) { ls += val; lq += val * val; }
                }
            }
        }
    }
    if (STATS) {
        __shared__ float rs[256], rq[256];
        rs[tid] = ls; rq[tid] = lq;
        __syncthreads();
        for (int off = 128; off > 0; off >>= 1) {
            if (tid < off) { rs[tid] += rs[tid + off]; rq[tid] += rq[tid + off]; }
            __syncthreads();
        }
        if (tid == 0) {
            int b = blockIdx.y * gridDim.x + blockIdx.x;
            Sp[2 * b] = rs[0];
            Sp[2 * b + 1] = rq[0];
        }
    }
}

// ---------------- CSR build ----------------
__global__ void count_deg(const int* __restrict__ dst, const int* __restrict__ mask, int E,
                          int* __restrict__ cnt) {
    int e = blockIdx.x * blockDim.x + threadIdx.x;
    if (e >= E) return;
    if (mask && !mask[e]) return;
    atomicAdd(&cnt[dst[e]], 1);
}

__global__ void dp_partial(const int* __restrict__ cnt, int n, int* __restrict__ part) {
    int base = blockIdx.x * 1024 + (int)threadIdx.x * 4;
    int s = 0;
#pragma unroll
    for (int t = 0; t < 4; ++t) {
        int i = base + t;
        if (i < n) s += cnt[i];
    }
    for (int off = 32; off > 0; off >>= 1) s += __shfl_down(s, off);
    __shared__ int sg[4];
    int wid = threadIdx.x >> 6;
    if ((threadIdx.x & 63) == 0) sg[wid] = s;
    __syncthreads();
    if (threadIdx.x == 0) part[blockIdx.x] = sg[0] + sg[1] + sg[2] + sg[3];
}

__global__ void scan64k(int nb, int* __restrict__ part, int* __restrict__ row_n) {
    int lane = threadIdx.x;
    int v0 = (lane < nb) ? part[lane] : 0;
    int v = v0;
    for (int off = 1; off < 64; off <<= 1) {
        int vv = __shfl_up(v, off);
        if (lane >= off) v += vv;
    }
    if (lane == nb - 1) row_n[0] = v;
    if (lane < nb) part[lane] = v - v0;
}

__global__ void dp_final(const int* __restrict__ cnt, int n, const int* __restrict__ part,
                         int* __restrict__ rowstart, int* __restrict__ cursor,
                         float* __restrict__ deg, float* __restrict__ dinv) {
    int base = blockIdx.x * 1024 + (int)threadIdx.x * 4;
    int c[4];
    int s = 0;
#pragma unroll
    for (int t = 0; t < 4; ++t) {
        int i = base + t;
        c[t] = (i < n) ? cnt[i] : 0;
        s += c[t];
    }
    int lane = threadIdx.x & 63, wid = threadIdx.x >> 6;
    int si = s;
    for (int off = 1; off < 64; off <<= 1) {
        int vv = __shfl_up(si, off);
        if (lane >= off) si += vv;
    }
    __shared__ int wg[4];
    if (lane == 63) wg[wid] = si;
    __syncthreads();
    int woff = 0;
    for (int w = 0; w < wid; ++w) woff += wg[w];
    int excl = part[blockIdx.x] + (si - s) + woff;
#pragma unroll
    for (int t = 0; t < 4; ++t) {
        int i = base + t;
        if (i < n) {
            rowstart[i] = excl;
            cursor[i] = excl;
            float dg = (float)c[t] + 2.0f;
            deg[i] = dg;
            dinv[i] = rsqrtf(dg);
        }
        excl += c[t];
    }
}

__global__ void csr_scatter(const int* __restrict__ src, const int* __restrict__ dst,
                            const int* __restrict__ mask, int E,
                            int* __restrict__ cursor, int* __restrict__ csr_src) {
    int e = blockIdx.x * blockDim.x + threadIdx.x;
    if (e >= E) return;
    if (mask && !mask[e]) return;
    int pos = atomicAdd(&cursor[dst[e]], 1);
    csr_src[pos] = src[e];
}

// ---------------- stage-1 aggregation: 8-deep pipelined gather (bf16 in/out) ----------------
__global__ void aggregate_xb(const int* __restrict__ rowstart, const int* __restrict__ csr_src,
                             const float* __restrict__ deg, const float* __restrict__ dinv,
                             const ushort* __restrict__ xb, ushort* __restrict__ out, int n) {
    int node = blockIdx.x * (blockDim.x >> 6) + ((int)threadIdx.x >> 6);
    if (node >= n) return;
    int lane = threadIdx.x & 63;
    int beg = rowstart[node], end = rowstart[node + 1];
    float di = dinv[node];
    float4 acc = make_float4(0.f, 0.f, 0.f, 0.f);
    int j = beg;
    for (; j + 8 <= end; j += 8) {
        int s[8];
#pragma unroll
        for (int u = 0; u < 8; ++u) s[u] = csr_src[j + u];
        float c[8];
#pragma unroll
        for (int u = 0; u < 8; ++u) c[u] = dinv[s[u]] * di;
        ushort4 t[8];
#pragma unroll
        for (int u = 0; u < 8; ++u)
            t[u] = reinterpret_cast<const ushort4*>(&xb[(size_t)s[u] * CIN])[lane];
#pragma unroll
        for (int u = 0; u < 8; ++u) {
            acc.x += c[u] * bf2f(t[u].x);
            acc.y += c[u] * bf2f(t[u].y);
            acc.z += c[u] * bf2f(t[u].z);
            acc.w += c[u] * bf2f(t[u].w);
        }
    }
    for (; j < end; ++j) {
        int s = csr_src[j];
        float coef = dinv[s] * di;
        ushort4 t = reinterpret_cast<const ushort4*>(&xb[(size_t)s * CIN])[lane];
        acc.x += coef * bf2f(t.x);
        acc.y += coef * bf2f(t.y);
        acc.z += coef * bf2f(t.z);
        acc.w += coef * bf2f(t.w);
    }
    float self = 2.0f / deg[node];
    ushort4 t = reinterpret_cast<const ushort4*>(&xb[(size_t)node * CIN])[lane];
    acc.x += self * bf2f(t.x);
    acc.y += self * bf2f(t.y);
    acc.z += self * bf2f(t.z);
    acc.w += self * bf2f(t.w);
    ushort4 o;
    o.x = f2bf(acc.x); o.y = f2bf(acc.y); o.z = f2bf(acc.z); o.w = f2bf(acc.w);
    reinterpret_cast<ushort4*>(&out[(size_t)node * CIN])[lane] = o;
}

// ---------------- stage-2 aggregation: 8-deep gather, f32 out + bias + self + fused stats ----------------
__global__ void aggregate_csr_bf(const int* __restrict__ rowstart, const int* __restrict__ csr_src,
                                 const float* __restrict__ deg, const float* __restrict__ dinv,
                                 const ushort* __restrict__ xWb, const float* __restrict__ b,
                                 float* __restrict__ out, float* __restrict__ Sp, int n) {
    int node = blockIdx.x * (blockDim.x >> 6) + ((int)threadIdx.x >> 6);
    bool valid = node < n;
    int lane = threadIdx.x & 63;
    float ls = 0.f, lq = 0.f;
    if (valid) {
        int beg = rowstart[node], end = rowstart[node + 1];
        float di = dinv[node];
        float4 acc = make_float4(0.f, 0.f, 0.f, 0.f);
        int j = beg;
        for (; j + 8 <= end; j += 8) {
            int s[8];
#pragma unroll
            for (int u = 0; u < 8; ++u) s[u] = csr_src[j + u];
            float c[8];
#pragma unroll
            for (int u = 0; u < 8; ++u) c[u] = dinv[s[u]] * di;
            ushort4 t[8];
#pragma unroll
            for (int u = 0; u < 8; ++u)
                t[u] = reinterpret_cast<const ushort4*>(&xWb[(size_t)s[u] * C2])[lane];
#pragma unroll
            for (int u = 0; u < 8; ++u) {
                acc.x += c[u] * bf2f(t[u].x);
                acc.y += c[u] * bf2f(t[u].y);
                acc.z += c[u] * bf2f(t[u].z);
                acc.w += c[u] * bf2f(t[u].w);
            }
        }
        for (; j < end; ++j) {
            int s = csr_src[j];
            float coef = dinv[s] * di;
            ushort4 t = reinterpret_cast<const ushort4*>(&xWb[(size_t)s * C2])[lane];
            acc.x += coef * bf2f(t.x);
            acc.y += coef * bf2f(t.y);
            acc.z += coef * bf2f(t.z);
            acc.w += coef * bf2f(t.w);
        }
        float self = 2.0f / deg[node];
        ushort4 t = reinterpret_cast<const ushort4*>(&xWb[(size_t)node * C2])[lane];
        float4 bb = reinterpret_cast<const float4*>(b)[lane];
        float4 o;
        o.x = acc.x + self * bf2f(t.x) + bb.x;
        o.y = acc.y + self * bf2f(t.y) + bb.y;
        o.z = acc.z + self * bf2f(t.z) + bb.z;
        o.w = acc.w + self * bf2f(t.w) + bb.w;
        reinterpret_cast<float4*>(&out[(size_t)node * C2])[lane] = o;
        ls = o.x + o.y + o.z + o.w;
        lq = o.x * o.x + o.y * o.y + o.z * o.z + o.w * o.w;
    }
    __shared__ float rs[256], rq[256];
    rs[threadIdx.x] = ls; rq[threadIdx.x] = lq;
    __syncthreads();
    for (int off = 128; off > 0; off >>= 1) {
        if ((int)threadIdx.x < off) {
            rs[threadIdx.x] += rs[threadIdx.x + off];
            rq[threadIdx.x] += rq[threadIdx.x + off];
        }
        __syncthreads();
    }
    if (threadIdx.x == 0) {
        Sp[2 * blockIdx.x] = rs[0];
        Sp[2 * blockIdx.x + 1] = rq[0];
    }
}

// ---------------- final stats fold ----------------
__global__ void reduce_final(const float* __restrict__ Sp, int nb, float* __restrict__ S) {
    float s = 0.f, q = 0.f;
    for (int i = threadIdx.x; i < nb; i += 256) {
        s += Sp[2 * i];
        q += Sp[2 * i + 1];
    }
    __shared__ float ls[256], lq[256];
    ls[threadIdx.x] = s; lq[threadIdx.x] = q;
    __syncthreads();
    for (int off = 128; off > 0; off >>= 1) {
        if ((int)threadIdx.x < off) {
            ls[threadIdx.x] += ls[threadIdx.x + off];
            lq[threadIdx.x] += lq[threadIdx.x + off];
        }
        __syncthreads();
    }
    if (threadIdx.x == 0) { S[0] = ls[0]; S[1] = lq[0]; }
}

// ---------------- norm+relu scores (READ-ONLY h; norm re-applied by consumers) ----------------
template <int C>
__global__ void norm_scores(const float* __restrict__ h, int n, const float* __restrict__ S,
                            float inv_cnt, const float* __restrict__ lnw,
                            const float* __restrict__ lnb, const float* __restrict__ wrel,
                            const float* __restrict__ brel, const float* __restrict__ wroot,
                            float* __restrict__ r, float* __restrict__ score) {
    int node = blockIdx.x * (blockDim.x >> 6) + ((int)threadIdx.x >> 6);
    if (node >= n) return;
    int lane = threadIdx.x & 63;
    float mean = S[0] * inv_cnt;
    float var = S[1] * inv_cnt - mean * mean;
    float istd = 1.f / (sqrtf(fmaxf(var, 0.f)) + EPSV);
    const float4* row = reinterpret_cast<const float4*>(&h[(size_t)node * C]);
    float sr = 0.f, st = 0.f;
#pragma unroll
    for (int kk = 0; kk < C / 256; ++kk) {
        int idx = lane + 64 * kk;
        float4 v = row[idx];
        float4 w = reinterpret_cast<const float4*>(lnw)[idx];
        float4 bb = reinterpret_cast<const float4*>(lnb)[idx];
        float4 w4 = reinterpret_cast<const float4*>(wrel)[idx];
        float4 o4 = reinterpret_cast<const float4*>(wroot)[idx];
        v.x = fmaxf((v.x - mean) * istd * w.x + bb.x, 0.f);
        v.y = fmaxf((v.y - mean) * istd * w.y + bb.y, 0.f);
        v.z = fmaxf((v.z - mean) * istd * w.z + bb.z, 0.f);
        v.w = fmaxf((v.w - mean) * istd * w.w + bb.w, 0.f);
        sr += v.x * w4.x + v.y * w4.y + v.z * w4.z + v.w * w4.w;
        st += v.x * o4.x + v.y * o4.y + v.z * o4.z + v.w * o4.w;
    }
    for (int off = 32; off > 0; off >>= 1) {
        sr += __shfl_down(sr, off);
        st += __shfl_down(st, off);
    }
    if (lane == 0) {
        r[node] = sr;
        score[node] = st + brel[0];
    }
}

// ---------------- gather score over CSR + keyify ----------------
__global__ void gather_score_key(const int* __restrict__ rowstart, const int* __restrict__ csr_src,
                                 const float* __restrict__ r, float* __restrict__ score,
                                 unsigned* __restrict__ key, int n) {
    int i = blockIdx.x * blockDim.x + threadIdx.x;
    if (i >= n) return;
    float s = score[i];
    int beg = rowstart[i], end = rowstart[i + 1];
    int j = beg;
    for (; j + 4 <= end; j += 4) {
        int s0 = csr_src[j], s1 = csr_src[j + 1], s2 = csr_src[j + 2], s3 = csr_src[j + 3];
        s += r[s0] + r[s1] + r[s2] + r[s3];
    }
    for (; j < end; ++j) s += r[csr_src[j]];
    score[i] = s;
    unsigned u = __float_as_uint(s);
    key[i] = (u & 0x80000000u) ? ~u : (u | 0x80000000u);
}

// ---------------- radix select: multi-block hi-hist + one fused threshold kernel ----------------
__global__ void hist_hi(const unsigned* __restrict__ key, int n, unsigned* __restrict__ hist) {
    int i = blockIdx.x * blockDim.x + threadIdx.x;
    if (i >= n) return;
    atomicAdd(&hist[(~key[i]) >> 16], 1u);
}

// single block, 1024 threads: scan hi-hist -> hi bin; build lo-hist in-kernel; scan -> sel.
// self-zeroes hist (ready for next stage).
__global__ void select_thresh(const unsigned* __restrict__ key, int n, unsigned k,
                              unsigned* __restrict__ hist, unsigned* __restrict__ sel) {
    __shared__ unsigned ps[1024];
    __shared__ int owner;
    __shared__ unsigned s_hi, s_rem;
    int t = threadIdx.x;
    int base = t * 64;
    // phase A: hi scan
    unsigned s = 0;
    for (int b = 0; b < 64; ++b) s += hist[base + b];
    ps[t] = s;
    __syncthreads();
    for (int off = 1; off < 1024; off <<= 1) {
        unsigned a = (t >= off) ? ps[t - off] : 0u;
        __syncthreads();
        ps[t] += a;
        __syncthreads();
    }
    unsigned incl = ps[t], excl = incl - s;
    if (excl < k && k <= incl) owner = t;
    __syncthreads();
    if (t == owner) {
        unsigned cum = excl;
        for (int b = 0; b < 64; ++b) {
            unsigned c = hist[base + b];
            if (cum + c >= k) { s_hi = 0xFFFFu ^ (unsigned)(base + b); s_rem = k - cum; break; }
            cum += c;
        }
    }
    __syncthreads();
    unsigned hi = s_hi, rem = s_rem;
    for (int b = 0; b < 64; ++b) hist[base + b] = 0u;
    __syncthreads();
    // phase B: lo-hist over keys in the hi bin
    for (int i = t; i < n; i += 1024) {
        unsigned u = key[i];
        if ((u >> 16) == hi) atomicAdd(&hist[0xFFFFu ^ (u & 0xFFFFu)], 1u);
    }
    __syncthreads();
    // phase C: lo scan
    s = 0;
    for (int b = 0; b < 64; ++b) s += hist[base + b];
    ps[t] = s;
    __syncthreads();
    for (int off = 1; off < 1024; off <<= 1) {
        unsigned a = (t >= off) ? ps[t - off] : 0u;
        __syncthreads();
        ps[t] += a;
        __syncthreads();
    }
    incl = ps[t]; excl = incl - s;
    if (excl < rem && rem <= incl) owner = t;
    __syncthreads();
    if (t == owner) {
        unsigned cum = excl;
        for (int b = 0; b < 64; ++b) {
            unsigned c = hist[base + b];
            if (cum + c >= rem) {
                sel[0] = (hi << 16) | (0xFFFFu ^ (unsigned)(base + b));
                sel[1] = rem - cum;
                break;
            }
            cum += c;
        }
    }
    __syncthreads();
    for (int b = 0; b < 64; ++b) hist[base + b] = 0u;
}

// ---------------- multi-block deterministic select + compact ----------------
__global__ void sc_partial(const unsigned* __restrict__ key, int n, const unsigned* __restrict__ sel,
                           int* __restrict__ gpart, int* __restrict__ epart) {
    unsigned thr = sel[0];
    int base = blockIdx.x * 1024 + (int)threadIdx.x * 4;
    int gs = 0, es = 0;
#pragma unroll
    for (int t = 0; t < 4; ++t) {
        int i = base + t;
        if (i < n) {
            unsigned u = key[i];
            gs += (u > thr); es += (u == thr);
        }
    }
    for (int off = 32; off > 0; off >>= 1) {
        gs += __shfl_down(gs, off);
        es += __shfl_down(es, off);
    }
    __shared__ int sg[4], se[4];
    int wid = threadIdx.x >> 6;
    if ((threadIdx.x & 63) == 0) { sg[wid] = gs; se[wid] = es; }
    __syncthreads();
    if (threadIdx.x == 0) {
        gpart[blockIdx.x] = sg[0] + sg[1] + sg[2] + sg[3];
        epart[blockIdx.x] = se[0] + se[1] + se[2] + se[3];
    }
}

// reads RAW per-block totals; each block sums its prefix inline (nb <= 20)
__global__ void sc_final(const unsigned* __restrict__ key, int n, const unsigned* __restrict__ sel,
                         const int* __restrict__ gpart, const int* __restrict__ epart,
                         int* __restrict__ kept, int* __restrict__ inv) {
    unsigned thr = sel[0];
    int tie = (int)sel[1];
    int gp0 = 0, ep0 = 0;
    for (int b = 0; b < (int)blockIdx.x; ++b) { gp0 += gpart[b]; ep0 += epart[b]; }
    int base = blockIdx.x * 1024 + (int)threadIdx.x * 4;
    int gl[4], el[4];
    int gs = 0, es = 0;
#pragma unroll
    for (int t = 0; t < 4; ++t) {
        int i = base + t;
        gl[t] = 0; el[t] = 0;
        if (i < n) {
            unsigned u = key[i];
            gl[t] = (u > thr); el[t] = (u == thr);
        }
        gs += gl[t]; es += el[t];
    }
    int lane = threadIdx.x & 63, wid = threadIdx.x >> 6;
    int gi = gs, ei = es;
    for (int off = 1; off < 64; off <<= 1) {
        int gg = __shfl_up(gi, off), ee = __shfl_up(ei, off);
        if (lane >= off) { gi += gg; ei += ee; }
    }
    __shared__ int wg[4], we[4];
    if (lane == 63) { wg[wid] = gi; we[wid] = ei; }
    __syncthreads();
    int wgo = 0, weo = 0;
    for (int w = 0; w < wid; ++w) { wgo += wg[w]; weo += we[w]; }
    int gp = gp0 + (gi - gs) + wgo;
    int ep = ep0 + (ei - es) + weo;
#pragma unroll
    for (int t = 0; t < 4; ++t) {
        int i = base + t;
        if (i < n) {
            int keep = gl[t] | (el[t] & ((ep < tie) ? 1 : 0));
            kept[i] = keep;
            inv[i] = gp + ((ep < tie) ? ep : tie);
        }
        gp += gl[t]; ep += el[t];
    }
}

// ---------------- pool apply: wave per node, applies norm+relu on the fly, bf16 out (C=512) ----------------
__global__ void pool_apply_rows(const float* __restrict__ h, const float* __restrict__ score,
                                const int* __restrict__ kept, const int* __restrict__ inv,
                                int n, const float* __restrict__ S, float inv_cnt,
                                const float* __restrict__ lnw, const float* __restrict__ lnb,
                                ushort* __restrict__ hp) {
    int node = blockIdx.x * (blockDim.x >> 6) + ((int)threadIdx.x >> 6);
    if (node >= n) return;
    if (!kept[node]) return;
    int lane = threadIdx.x & 63;
    float mean = S[0] * inv_cnt;
    float var = S[1] * inv_cnt - mean * mean;
    float istd = 1.f / (sqrtf(fmaxf(var, 0.f)) + EPSV);
    float tw = tanhf(score[node]);
    const float4* src = reinterpret_cast<const float4*>(&h[(size_t)node * C1]);
    ushort4* dst = reinterpret_cast<ushort4*>(&hp[(size_t)inv[node] * C1]);
#pragma unroll
    for (int v = 0; v < 2; ++v) {
        int idx = lane + 64 * v;
        float4 a = src[idx];
        float4 w = reinterpret_cast<const float4*>(lnw)[idx];
        float4 bb = reinterpret_cast<const float4*>(lnb)[idx];
        ushort4 o;
        o.x = f2bf(fmaxf((a.x - mean) * istd * w.x + bb.x, 0.f) * tw);
        o.y = f2bf(fmaxf((a.y - mean) * istd * w.y + bb.y, 0.f) * tw);
        o.z = f2bf(fmaxf((a.z - mean) * istd * w.z + bb.z, 0.f) * tw);
        o.w = f2bf(fmaxf((a.w - mean) * istd * w.w + bb.w, 0.f) * tw);
        dst[idx] = o;
    }
}

// ---------------- edge relabel ----------------
__global__ void edge_relabel(const int* __restrict__ src, const int* __restrict__ dst, int E,
                             const int* __restrict__ kept, const int* __restrict__ inv,
                             int* __restrict__ src2, int* __restrict__ dst2,
                             int* __restrict__ mask2) {
    int e = blockIdx.x * blockDim.x + threadIdx.x;
    if (e >= E) return;
    int s = src[e], d = dst[e];
    int m = kept[s] & kept[d];
    mask2[e] = m;
    src2[e] = m ? inv[s] : 0;
    dst2[e] = m ? inv[d] : 0;
}

// ---------------- masked weighted column mean (norm+relu applied on the fly) ----------------
__global__ void colmean_part(const float* __restrict__ h, const float* __restrict__ score,
                             const int* __restrict__ kept, int n, const float* __restrict__ S,
                             float inv_cnt, const float* __restrict__ lnw,
                             const float* __restrict__ lnb, float* __restrict__ Gp) {
    __shared__ float w[CM_ROWS];
    int i0 = blockIdx.x * CM_ROWS;
    int t = threadIdx.x;
    float mean = S[0] * inv_cnt;
    float var = S[1] * inv_cnt - mean * mean;
    float istd = 1.f / (sqrtf(fmaxf(var, 0.f)) + EPSV);
    float wn = lnw[t] * istd;
    float bn = lnb[t] - mean * wn;
    for (int i = t; i < CM_ROWS; i += 256) {
        int idx = i0 + i;
        w[i] = (idx < n && kept[idx]) ? tanhf(score[idx]) : 0.f;
    }
    __syncthreads();
    float acc = 0.f;
    int rows = min(CM_ROWS, n - i0);
#pragma unroll 8
    for (int ri = 0; ri < rows; ++ri)
        acc = fmaf(w[ri], fmaxf(fmaf(h[(size_t)(i0 + ri) * C2 + t], wn, bn), 0.f), acc);
    Gp[blockIdx.x * 256 + t] = acc;
}

__global__ void colmean_final(const float* __restrict__ Gp, int nb, float invk,
                              float* __restrict__ g) {
    int t = threadIdx.x;  // 256
    float s = 0.f;
    for (int b = 0; b < nb; ++b) s += Gp[b * 256 + t];
    g[t] = s * invk;
}

__global__ void final_gemv(const float* __restrict__ g, const float* __restrict__ Wf,
                           const float* __restrict__ bf, float* __restrict__ out) {
    int j = threadIdx.x;  // 128
    float s = bf[j];
    for (int c = 0; c < 256; ++c) s += g[c] * Wf[c * NOUT + j];
    out[j] = s;
}

// =======================================================================================
extern "C" void kernel_launch(void* const* d_in, const int* in_sizes, int n_in,
                              void* d_out, int out_size, void* d_ws, size_t ws_size,
                              hipStream_t stream) {
    const float* x      = (const float*)d_in[0];
    const int*   ei     = (const int*)d_in[1];
    const float* W1     = (const float*)d_in[2];
    const float* b1     = (const float*)d_in[3];
    const float* ln1w   = (const float*)d_in[4];
    const float* ln1b   = (const float*)d_in[5];
    const float* p1wrel = (const float*)d_in[6];
    const float* p1brel = (const float*)d_in[7];
    const float* p1wroot= (const float*)d_in[8];
    const float* W2     = (const float*)d_in[9];
    const float* b2     = (const float*)d_in[10];
    const float* ln2w   = (const float*)d_in[11];
    const float* ln2b   = (const float*)d_in[12];
    const float* p2wrel = (const float*)d_in[13];
    const float* p2brel = (const float*)d_in[14];
    const float* p2wroot= (const float*)d_in[15];
    const float* Wf     = (const float*)d_in[16];
    const float* bf     = (const float*)d_in[17];
    float* out = (float*)d_out;
    char* ws = (char*)d_ws;

    const int* src1 = ei;
    const int* dst1 = ei + NE;

    // ---- workspace layout (bytes) ----
    const size_t o0     = 0;          // 40.96 MB: h1 f32; later h2 f32 @+0, xW2b bf16 @+10,240,000
    const size_t o1     = 40960000;   // 10.24 MB: aggb bf16; later h1pb bf16
    const size_t oXb    = 51200000;   // 10,240,000 : xb bf16
    const size_t oW1t   = 61440000;
    const size_t oW2t   = 61702144;
    const size_t oSrc2  = 61964288;
    const size_t oDst2  = 63244288;
    const size_t oMask2 = 64524288;
    const size_t oCsr   = 65804288;
    const size_t oRow   = 67084288;
    const size_t oCur   = 67164352;
    const size_t oDeg   = 67244352;
    const size_t oDinv  = 67324352;
    const size_t oR     = 67404352;
    const size_t oScore1= 67484352;
    const size_t oKeyu  = 67564352;
    const size_t oKept  = 67644352;
    const size_t oInv   = 67724352;
    const size_t oScore2= 67804352;
    const size_t oKeyu2 = 67844352;
    const size_t oKept2 = 67884352;
    const size_t oInv2  = 67924352;
    const size_t oS     = 67964352;
    const size_t oSel   = 67964416;
    const size_t oGpart = 67964480;
    const size_t oEpart = 67964736;
    const size_t oG     = 67964992;
    const size_t oHist  = 67970112;   // 262,144
    const size_t oGp    = 68232256;   // 81,920 : colmean partials
    const size_t oSp    = 68314176;   // 32,768 : stats partials (up to 4096 blocks)

    float*  h1    = (float*)(ws + o0);
    float*  h2    = (float*)(ws + o0);
    ushort* xW2b  = (ushort*)(ws + o0 + 10240000);
    ushort* aggb  = (ushort*)(ws + o1);
    ushort* h1pb  = (ushort*)(ws + o1);
    ushort* xb    = (ushort*)(ws + oXb);
    ushort* W1t   = (ushort*)(ws + oW1t);
    ushort* W2t   = (ushort*)(ws + oW2t);
    int*    src2  = (int*)(ws + oSrc2);
    int*    dst2  = (int*)(ws + oDst2);
    int*    mask2 = (int*)(ws + oMask2);
    int*    csr   = (int*)(ws + oCsr);
    int*    row   = (int*)(ws + oRow);
    int*    cur   = (int*)(ws + oCur);
    float*  deg   = (float*)(ws + oDeg);
    float*  dinv  = (float*)(ws + oDinv);
    float*  r     = (float*)(ws + oR);
    float*  score1= (float*)(ws + oScore1);
    unsigned* keyu  = (unsigned*)(ws + oKeyu);
    int*    kept  = (int*)(ws + oKept);
    int*    inv   = (int*)(ws + oInv);
    float*  score2= (float*)(ws + oScore2);
    unsigned* keyu2 = (unsigned*)(ws + oKeyu2);
    int*    kept2 = (int*)(ws + oKept2);
    int*    inv2  = (int*)(ws + oInv2);
    float*  S     = (float*)(ws + oS);
    unsigned* sel  = (unsigned*)(ws + oSel);
    int*    gpart = (int*)(ws + oGpart);
    int*    epart = (int*)(ws + oEpart);
    float*  g     = (float*)(ws + oG);
    unsigned* hist = (unsigned*)(ws + oHist);
    float*  Gp    = (float*)(ws + oGp);
    float*  Sp    = (float*)(ws + oSp);

    const int nb1 = cdiv(N1, 1024);     // 20
    const int nb2 = cdiv(K1, 1024);     // 10
    const int nbc = cdiv(K1, CM_ROWS);  // 79
    const int g1x = cdiv(N1, 128), g1y = C1 / 128;   // 157 x 4 = 628 stat blocks
    const int agg2b = cdiv(K1, 4);      // 2500 stat blocks

    // ================= Stage 1 =================
    f32_to_bf16<<<cdiv(N1 * CIN / 4, 256), 256, 0, stream>>>(x, xb, N1 * CIN / 4);

    fill_i32<<<cdiv(N1, 256), 256, 0, stream>>>(cur, 0, N1);
    fill_i32<<<cdiv(65536, 256), 256, 0, stream>>>((int*)hist, 0, 65536);  // select_thresh self-zeroes after
    count_deg<<<cdiv(NE, 256), 256, 0, stream>>>(dst1, nullptr, NE, cur);
    dp_partial<<<nb1, 256, 0, stream>>>(cur, N1, gpart);
    scan64k<<<1, 64, 0, stream>>>(nb1, gpart, row + N1);
    dp_final<<<nb1, 256, 0, stream>>>(cur, N1, gpart, row, cur, deg, dinv);
    csr_scatter<<<cdiv(NE, 256), 256, 0, stream>>>(src1, dst1, nullptr, NE, cur, csr);

    aggregate_xb<<<cdiv(N1, 4), 256, 0, stream>>>(row, csr, deg, dinv, xb, aggb, N1);

    conv_transpose_bf16<<<cdiv(CIN * C1, 256), 256, 0, stream>>>(W1, W1t, CIN, C1);
    gemm_bf16_mfma<false, true><<<dim3(g1x, g1y), 256, 0, stream>>>(
        aggb, W1t, b1, h1, nullptr, Sp, N1, C1, CIN);
    reduce_final<<<1, 256, 0, stream>>>(Sp, g1x * g1y, S);

    norm_scores<C1><<<cdiv(N1, 4), 256, 0, stream>>>(h1, N1, S, 1.f / ((float)N1 * C1),
                                                     ln1w, ln1b, p1wrel, p1brel, p1wroot, r, score1);
    gather_score_key<<<cdiv(N1, 256), 256, 0, stream>>>(row, csr, r, score1, keyu, N1);

    hist_hi<<<cdiv(N1, 256), 256, 0, stream>>>(keyu, N1, hist);
    select_thresh<<<1, 1024, 0, stream>>>(keyu, N1, K1, hist, sel);
    sc_partial<<<nb1, 256, 0, stream>>>(keyu, N1, sel, gpart, epart);
    sc_final<<<nb1, 256, 0, stream>>>(keyu, N1, sel, gpart, epart, kept, inv);

    pool_apply_rows<<<cdiv(N1, 4), 256, 0, stream>>>(h1, score1, kept, inv, N1, S,
                                                     1.f / ((float)N1 * C1), ln1w, ln1b, h1pb);
    edge_relabel<<<cdiv(NE, 256), 256, 0, stream>>>(src1, dst1, NE, kept, inv, src2, dst2, mask2);

    // ================= Stage 2 =================
    conv_transpose_bf16<<<cdiv(C1 * C2, 256), 256, 0, stream>>>(W2, W2t, C1, C2);
    gemm_bf16_mfma<true, false><<<dim3(cdiv(K1, 128), C2 / 128), 256, 0, stream>>>(
        h1pb, W2t, nullptr, nullptr, xW2b, nullptr, K1, C2, C1);

    fill_i32<<<cdiv(K1, 256), 256, 0, stream>>>(cur, 0, K1);
    count_deg<<<cdiv(NE, 256), 256, 0, stream>>>(dst2, mask2, NE, cur);
    dp_partial<<<nb2, 256, 0, stream>>>(cur, K1, gpart);
    scan64k<<<1, 64, 0, stream>>>(nb2, gpart, row + K1);
    dp_final<<<nb2, 256, 0, stream>>>(cur, K1, gpart, row, cur, deg, dinv);
    csr_scatter<<<cdiv(NE, 256), 256, 0, stream>>>(src2, dst2, mask2, NE, cur, csr);

    aggregate_csr_bf<<<agg2b, 256, 0, stream>>>(row, csr, deg, dinv, xW2b, b2, h2, Sp, K1);
    reduce_final<<<1, 256, 0, stream>>>(Sp, agg2b, S);

    norm_scores<C2><<<cdiv(K1, 4), 256, 0, stream>>>(h2, K1, S, 1.f / ((float)K1 * C2),
                                                     ln2w, ln2b, p2wrel, p2brel, p2wroot, r, score2);
    gather_score_key<<<cdiv(K1, 256), 256, 0, stream>>>(row, csr, r, score2, keyu2, K1);

    hist_hi<<<cdiv(K1, 256), 256, 0, stream>>>(keyu2, K1, hist);
    select_thresh<<<1, 1024, 0, stream>>>(keyu2, K1, K2, hist, sel);
    sc_partial<<<nb2, 256, 0, stream>>>(keyu2, K1, sel, gpart, epart);
    sc_final<<<nb2, 256, 0, stream>>>(keyu2, K1, sel, gpart, epart, kept2, inv2);

    // ================= readout =================
    colmean_part<<<nbc, 256, 0, stream>>>(h2, score2, kept2, K1, S, 1.f / ((float)K1 * C2),
                                          ln2w, ln2b, Gp);
    colmean_final<<<1, 256, 0, stream>>>(Gp, nbc, 1.f / (float)K2, g);
    final_gemv<<<1, NOUT, 0, stream>>>(g, Wf, bf, out);
}

// Round 10
// 370.709 us; speedup vs baseline: 8.3463x; 1.0410x over previous
//
#include <hip/hip_runtime.h>
#include <math.h>

#define N1 20000
#define NE 320000
#define CIN 256
#define C1 512
#define C2 256
#define K1 10000
#define K2 5000
#define NOUT 128
#define EPSV 1e-5f
#define CM_ROWS 128

typedef __attribute__((ext_vector_type(8))) short bf16x8;
typedef __attribute__((ext_vector_type(4))) float f32x4;

static inline unsigned cdiv(unsigned a, unsigned b) { return (a + b - 1) / b; }

__device__ inline ushort f2bf(float f) {
    unsigned u = __float_as_uint(f);
    unsigned r = u + 0x7FFFu + ((u >> 16) & 1u);
    return (ushort)(r >> 16);
}
__device__ inline float bf2f(ushort u) { return __uint_as_float(((unsigned)u) << 16); }

// ---------------- fills ----------------
__global__ void fill_i32(int* __restrict__ p, int v, int n) {
    int i = blockIdx.x * blockDim.x + threadIdx.x;
    if (i < n) p[i] = v;
}

// ---------------- f32 -> bf16 ----------------
__global__ void f32_to_bf16(const float* __restrict__ in, ushort* __restrict__ out, int n4) {
    int i = blockIdx.x * blockDim.x + threadIdx.x;
    if (i >= n4) return;
    float4 v = reinterpret_cast<const float4*>(in)[i];
    ushort4 o;
    o.x = f2bf(v.x); o.y = f2bf(v.y); o.z = f2bf(v.z); o.w = f2bf(v.w);
    reinterpret_cast<ushort4*>(out)[i] = o;
}

// ---------------- weight convert+transpose ----------------
__global__ void conv_transpose_bf16(const float* __restrict__ W, ushort* __restrict__ Wt,
                                    int K, int N) {
    int i = blockIdx.x * blockDim.x + threadIdx.x;
    if (i >= K * N) return;
    int k = i / N, n = i % N;
    Wt[(size_t)n * K + k] = f2bf(W[i]);
}

// ---------------- MFMA bf16 GEMM (optional fused sum/sumsq stats) ----------------
template <bool BF16OUT, bool STATS>
__global__ __launch_bounds__(256)
void gemm_bf16_mfma(const ushort* __restrict__ A, const ushort* __restrict__ Bt,
                    const float* __restrict__ bias, float* __restrict__ C,
                    ushort* __restrict__ Cb, float* __restrict__ Sp, int M, int N, int K) {
    constexpr int BM = 128, BN = 128, BK = 32;
    constexpr int LDK = BK + 8;
    __shared__ ushort As[BM * LDK];
    __shared__ ushort Bs[BN * LDK];
    int tid = threadIdx.x;
    int wid = tid >> 6, lane = tid & 63;
    int wr = wid >> 1, wc = wid & 1;
    int bm = blockIdx.x * BM, bn = blockIdx.y * BN;
    int lg = lane >> 4, lm = lane & 15;
    f32x4 zero = {0.f, 0.f, 0.f, 0.f};
    f32x4 acc[4][4];
#pragma unroll
    for (int m = 0; m < 4; ++m)
#pragma unroll
        for (int n = 0; n < 4; ++n) acc[m][n] = zero;

    for (int k0 = 0; k0 < K; k0 += BK) {
#pragma unroll
        for (int it = 0; it < 2; ++it) {
            int task = tid * 2 + it;
            int row = task >> 2, c8 = (task & 3) * 8;
            int gm = bm + row;
            bf16x8 v = {0, 0, 0, 0, 0, 0, 0, 0};
            if (gm < M) v = *(const bf16x8*)&A[(size_t)gm * K + k0 + c8];
            *(bf16x8*)&As[row * LDK + c8] = v;
            int gn = bn + row;
            bf16x8 w = {0, 0, 0, 0, 0, 0, 0, 0};
            if (gn < N) w = *(const bf16x8*)&Bt[(size_t)gn * K + k0 + c8];
            *(bf16x8*)&Bs[row * LDK + c8] = w;
        }
        __syncthreads();
        bf16x8 af[4], bfr[4];
#pragma unroll
        for (int m = 0; m < 4; ++m)
            af[m] = *(bf16x8*)&As[(wr * 64 + m * 16 + lm) * LDK + lg * 8];
#pragma unroll
        for (int n = 0; n < 4; ++n)
            bfr[n] = *(bf16x8*)&Bs[(wc * 64 + n * 16 + lm) * LDK + lg * 8];
#pragma unroll
        for (int m = 0; m < 4; ++m)
#pragma unroll
            for (int n = 0; n < 4; ++n)
                acc[m][n] = __builtin_amdgcn_mfma_f32_16x16x32_bf16(af[m], bfr[n], acc[m][n], 0, 0, 0);
        __syncthreads();
    }
    float ls = 0.f, lq = 0.f;
#pragma unroll
    for (int m = 0; m < 4; ++m) {
#pragma unroll
        for (int n = 0; n < 4; ++n) {
            int col = bn + wc * 64 + n * 16 + lm;
            float bv = bias ? bias[col] : 0.f;
#pragma unroll
            for (int r = 0; r < 4; ++r) {
                int row = bm + wr * 64 + m * 16 + lg * 4 + r;
                if (row < M) {
                    float val = acc[m][n][r] + bv;
                    if (BF16OUT) Cb[(size_t)row * N + col] = f2bf(val);
                    else         C[(size_t)row * N + col] = val;
                    if (STATS) { ls += val; lq += val * val; }
                }
            }
        }
    }
    if (STATS) {
        __shared__ float rs[256], rq[256];
        rs[tid] = ls; rq[tid] = lq;
        __syncthreads();
        for (int off = 128; off > 0; off >>= 1) {
            if (tid < off) { rs[tid] += rs[tid + off]; rq[tid] += rq[tid + off]; }
            __syncthreads();
        }
        if (tid == 0) {
            int b = blockIdx.y * gridDim.x + blockIdx.x;
            Sp[2 * b] = rs[0];
            Sp[2 * b + 1] = rq[0];
        }
    }
}

// ---------------- CSR build ----------------
__global__ void count_deg(const int* __restrict__ dst, const int* __restrict__ mask, int E,
                          int* __restrict__ cnt) {
    int e = blockIdx.x * blockDim.x + threadIdx.x;
    if (e >= E) return;
    if (mask && !mask[e]) return;
    atomicAdd(&cnt[dst[e]], 1);
}

__global__ void dp_partial(const int* __restrict__ cnt, int n, int* __restrict__ part) {
    int base = blockIdx.x * 1024 + (int)threadIdx.x * 4;
    int s = 0;
#pragma unroll
    for (int t = 0; t < 4; ++t) {
        int i = base + t;
        if (i < n) s += cnt[i];
    }
    for (int off = 32; off > 0; off >>= 1) s += __shfl_down(s, off);
    __shared__ int sg[4];
    int wid = threadIdx.x >> 6;
    if ((threadIdx.x & 63) == 0) sg[wid] = s;
    __syncthreads();
    if (threadIdx.x == 0) part[blockIdx.x] = sg[0] + sg[1] + sg[2] + sg[3];
}

__global__ void scan64k(int nb, int* __restrict__ part, int* __restrict__ row_n) {
    int lane = threadIdx.x;
    int v0 = (lane < nb) ? part[lane] : 0;
    int v = v0;
    for (int off = 1; off < 64; off <<= 1) {
        int vv = __shfl_up(v, off);
        if (lane >= off) v += vv;
    }
    if (lane == nb - 1) row_n[0] = v;
    if (lane < nb) part[lane] = v - v0;
}

__global__ void dp_final(const int* __restrict__ cnt, int n, const int* __restrict__ part,
                         int* __restrict__ rowstart, int* __restrict__ cursor,
                         float* __restrict__ deg, float* __restrict__ dinv) {
    int base = blockIdx.x * 1024 + (int)threadIdx.x * 4;
    int c[4];
    int s = 0;
#pragma unroll
    for (int t = 0; t < 4; ++t) {
        int i = base + t;
        c[t] = (i < n) ? cnt[i] : 0;
        s += c[t];
    }
    int lane = threadIdx.x & 63, wid = threadIdx.x >> 6;
    int si = s;
    for (int off = 1; off < 64; off <<= 1) {
        int vv = __shfl_up(si, off);
        if (lane >= off) si += vv;
    }
    __shared__ int wg[4];
    if (lane == 63) wg[wid] = si;
    __syncthreads();
    int woff = 0;
    for (int w = 0; w < wid; ++w) woff += wg[w];
    int excl = part[blockIdx.x] + (si - s) + woff;
#pragma unroll
    for (int t = 0; t < 4; ++t) {
        int i = base + t;
        if (i < n) {
            rowstart[i] = excl;
            cursor[i] = excl;
            float dg = (float)c[t] + 2.0f;
            deg[i] = dg;
            dinv[i] = rsqrtf(dg);
        }
        excl += c[t];
    }
}

__global__ void csr_scatter(const int* __restrict__ src, const int* __restrict__ dst,
                            const int* __restrict__ mask, int E,
                            int* __restrict__ cursor, int* __restrict__ csr_src) {
    int e = blockIdx.x * blockDim.x + threadIdx.x;
    if (e >= E) return;
    if (mask && !mask[e]) return;
    int pos = atomicAdd(&cursor[dst[e]], 1);
    csr_src[pos] = src[e];
}

// ---------------- stage-1 aggregation: 8-deep pipelined gather (bf16 in/out) ----------------
__global__ void aggregate_xb(const int* __restrict__ rowstart, const int* __restrict__ csr_src,
                             const float* __restrict__ deg, const float* __restrict__ dinv,
                             const ushort* __restrict__ xb, ushort* __restrict__ out, int n) {
    int node = blockIdx.x * (blockDim.x >> 6) + ((int)threadIdx.x >> 6);
    if (node >= n) return;
    int lane = threadIdx.x & 63;
    int beg = rowstart[node], end = rowstart[node + 1];
    float di = dinv[node];
    float4 acc = make_float4(0.f, 0.f, 0.f, 0.f);
    int j = beg;
    for (; j + 8 <= end; j += 8) {
        int s[8];
#pragma unroll
        for (int u = 0; u < 8; ++u) s[u] = csr_src[j + u];
        float c[8];
#pragma unroll
        for (int u = 0; u < 8; ++u) c[u] = dinv[s[u]] * di;
        ushort4 t[8];
#pragma unroll
        for (int u = 0; u < 8; ++u)
            t[u] = reinterpret_cast<const ushort4*>(&xb[(size_t)s[u] * CIN])[lane];
#pragma unroll
        for (int u = 0; u < 8; ++u) {
            acc.x += c[u] * bf2f(t[u].x);
            acc.y += c[u] * bf2f(t[u].y);
            acc.z += c[u] * bf2f(t[u].z);
            acc.w += c[u] * bf2f(t[u].w);
        }
    }
    for (; j < end; ++j) {
        int s = csr_src[j];
        float coef = dinv[s] * di;
        ushort4 t = reinterpret_cast<const ushort4*>(&xb[(size_t)s * CIN])[lane];
        acc.x += coef * bf2f(t.x);
        acc.y += coef * bf2f(t.y);
        acc.z += coef * bf2f(t.z);
        acc.w += coef * bf2f(t.w);
    }
    float self = 2.0f / deg[node];
    ushort4 t = reinterpret_cast<const ushort4*>(&xb[(size_t)node * CIN])[lane];
    acc.x += self * bf2f(t.x);
    acc.y += self * bf2f(t.y);
    acc.z += self * bf2f(t.z);
    acc.w += self * bf2f(t.w);
    ushort4 o;
    o.x = f2bf(acc.x); o.y = f2bf(acc.y); o.z = f2bf(acc.z); o.w = f2bf(acc.w);
    reinterpret_cast<ushort4*>(&out[(size_t)node * CIN])[lane] = o;
}

// ---------------- stage-2 aggregation: 8-deep gather, f32 out + bias + self + fused stats ----------------
__global__ void aggregate_csr_bf(const int* __restrict__ rowstart, const int* __restrict__ csr_src,
                                 const float* __restrict__ deg, const float* __restrict__ dinv,
                                 const ushort* __restrict__ xWb, const float* __restrict__ b,
                                 float* __restrict__ out, float* __restrict__ Sp, int n) {
    int node = blockIdx.x * (blockDim.x >> 6) + ((int)threadIdx.x >> 6);
    bool valid = node < n;
    int lane = threadIdx.x & 63;
    float ls = 0.f, lq = 0.f;
    if (valid) {
        int beg = rowstart[node], end = rowstart[node + 1];
        float di = dinv[node];
        float4 acc = make_float4(0.f, 0.f, 0.f, 0.f);
        int j = beg;
        for (; j + 8 <= end; j += 8) {
            int s[8];
#pragma unroll
            for (int u = 0; u < 8; ++u) s[u] = csr_src[j + u];
            float c[8];
#pragma unroll
            for (int u = 0; u < 8; ++u) c[u] = dinv[s[u]] * di;
            ushort4 t[8];
#pragma unroll
            for (int u = 0; u < 8; ++u)
                t[u] = reinterpret_cast<const ushort4*>(&xWb[(size_t)s[u] * C2])[lane];
#pragma unroll
            for (int u = 0; u < 8; ++u) {
                acc.x += c[u] * bf2f(t[u].x);
                acc.y += c[u] * bf2f(t[u].y);
                acc.z += c[u] * bf2f(t[u].z);
                acc.w += c[u] * bf2f(t[u].w);
            }
        }
        for (; j < end; ++j) {
            int s = csr_src[j];
            float coef = dinv[s] * di;
            ushort4 t = reinterpret_cast<const ushort4*>(&xWb[(size_t)s * C2])[lane];
            acc.x += coef * bf2f(t.x);
            acc.y += coef * bf2f(t.y);
            acc.z += coef * bf2f(t.z);
            acc.w += coef * bf2f(t.w);
        }
        float self = 2.0f / deg[node];
        ushort4 t = reinterpret_cast<const ushort4*>(&xWb[(size_t)node * C2])[lane];
        float4 bb = reinterpret_cast<const float4*>(b)[lane];
        float4 o;
        o.x = acc.x + self * bf2f(t.x) + bb.x;
        o.y = acc.y + self * bf2f(t.y) + bb.y;
        o.z = acc.z + self * bf2f(t.z) + bb.z;
        o.w = acc.w + self * bf2f(t.w) + bb.w;
        reinterpret_cast<float4*>(&out[(size_t)node * C2])[lane] = o;
        ls = o.x + o.y + o.z + o.w;
        lq = o.x * o.x + o.y * o.y + o.z * o.z + o.w * o.w;
    }
    __shared__ float rs[256], rq[256];
    rs[threadIdx.x] = ls; rq[threadIdx.x] = lq;
    __syncthreads();
    for (int off = 128; off > 0; off >>= 1) {
        if ((int)threadIdx.x < off) {
            rs[threadIdx.x] += rs[threadIdx.x + off];
            rq[threadIdx.x] += rq[threadIdx.x + off];
        }
        __syncthreads();
    }
    if (threadIdx.x == 0) {
        Sp[2 * blockIdx.x] = rs[0];
        Sp[2 * blockIdx.x + 1] = rq[0];
    }
}

// ---------------- final stats fold ----------------
__global__ void reduce_final(const float* __restrict__ Sp, int nb, float* __restrict__ S) {
    float s = 0.f, q = 0.f;
    for (int i = threadIdx.x; i < nb; i += 256) {
        s += Sp[2 * i];
        q += Sp[2 * i + 1];
    }
    __shared__ float ls[256], lq[256];
    ls[threadIdx.x] = s; lq[threadIdx.x] = q;
    __syncthreads();
    for (int off = 128; off > 0; off >>= 1) {
        if ((int)threadIdx.x < off) {
            ls[threadIdx.x] += ls[threadIdx.x + off];
            lq[threadIdx.x] += lq[threadIdx.x + off];
        }
        __syncthreads();
    }
    if (threadIdx.x == 0) { S[0] = ls[0]; S[1] = lq[0]; }
}

// ---------------- norm+relu scores (READ-ONLY h; norm re-applied by consumers) ----------------
template <int C>
__global__ void norm_scores(const float* __restrict__ h, int n, const float* __restrict__ S,
                            float inv_cnt, const float* __restrict__ lnw,
                            const float* __restrict__ lnb, const float* __restrict__ wrel,
                            const float* __restrict__ brel, const float* __restrict__ wroot,
                            float* __restrict__ r, float* __restrict__ score) {
    int node = blockIdx.x * (blockDim.x >> 6) + ((int)threadIdx.x >> 6);
    if (node >= n) return;
    int lane = threadIdx.x & 63;
    float mean = S[0] * inv_cnt;
    float var = S[1] * inv_cnt - mean * mean;
    float istd = 1.f / (sqrtf(fmaxf(var, 0.f)) + EPSV);
    const float4* row = reinterpret_cast<const float4*>(&h[(size_t)node * C]);
    float sr = 0.f, st = 0.f;
#pragma unroll
    for (int kk = 0; kk < C / 256; ++kk) {
        int idx = lane + 64 * kk;
        float4 v = row[idx];
        float4 w = reinterpret_cast<const float4*>(lnw)[idx];
        float4 bb = reinterpret_cast<const float4*>(lnb)[idx];
        float4 w4 = reinterpret_cast<const float4*>(wrel)[idx];
        float4 o4 = reinterpret_cast<const float4*>(wroot)[idx];
        v.x = fmaxf((v.x - mean) * istd * w.x + bb.x, 0.f);
        v.y = fmaxf((v.y - mean) * istd * w.y + bb.y, 0.f);
        v.z = fmaxf((v.z - mean) * istd * w.z + bb.z, 0.f);
        v.w = fmaxf((v.w - mean) * istd * w.w + bb.w, 0.f);
        sr += v.x * w4.x + v.y * w4.y + v.z * w4.z + v.w * w4.w;
        st += v.x * o4.x + v.y * o4.y + v.z * o4.z + v.w * o4.w;
    }
    for (int off = 32; off > 0; off >>= 1) {
        sr += __shfl_down(sr, off);
        st += __shfl_down(st, off);
    }
    if (lane == 0) {
        r[node] = sr;
        score[node] = st + brel[0];
    }
}

// ---------------- gather score over CSR + keyify + hi-16 histogram ----------------
__global__ void gather_score_key(const int* __restrict__ rowstart, const int* __restrict__ csr_src,
                                 const float* __restrict__ r, float* __restrict__ score,
                                 unsigned* __restrict__ key, unsigned* __restrict__ hist, int n) {
    int i = blockIdx.x * blockDim.x + threadIdx.x;
    if (i >= n) return;
    float s = score[i];
    int beg = rowstart[i], end = rowstart[i + 1];
    int j = beg;
    for (; j + 4 <= end; j += 4) {
        int s0 = csr_src[j], s1 = csr_src[j + 1], s2 = csr_src[j + 2], s3 = csr_src[j + 3];
        s += r[s0] + r[s1] + r[s2] + r[s3];
    }
    for (; j < end; ++j) s += r[csr_src[j]];
    score[i] = s;
    unsigned u = __float_as_uint(s);
    unsigned kk = (u & 0x80000000u) ? ~u : (u | 0x80000000u);
    key[i] = kk;
    atomicAdd(&hist[(~kk) >> 16], 1u);
}

// ---------------- fused two-pass 16-bit threshold select (single block, wave-scan) ----------------
// 1024 threads, each owns 64 consecutive bins. Wave shfl-scan + 16 wave totals (2 barriers/phase).
// Self-zeroes hist for the next stage.
__global__ void select_thresh(const unsigned* __restrict__ key, int n, unsigned k,
                              unsigned* __restrict__ hist, unsigned* __restrict__ sel) {
    __shared__ unsigned wsum[16];
    __shared__ unsigned s_hi, s_rem;
    int t = threadIdx.x;
    int lane = t & 63, w = t >> 6;
    const uint4* hp = reinterpret_cast<const uint4*>(hist) + t * 16;
    uint4* hpw = reinterpret_cast<uint4*>(hist) + t * 16;
    uint4 z = make_uint4(0u, 0u, 0u, 0u);

    // ---- phase A: pick hi-16 bin ----
    unsigned s = 0;
#pragma unroll
    for (int i = 0; i < 16; ++i) {
        uint4 v = hp[i];
        s += v.x + v.y + v.z + v.w;
    }
    unsigned si = s;
#pragma unroll
    for (int off = 1; off < 64; off <<= 1) {
        unsigned vv = __shfl_up(si, off);
        if (lane >= off) si += vv;
    }
    if (lane == 63) wsum[w] = si;
    __syncthreads();
    unsigned wpre = 0;
    for (int i = 0; i < w; ++i) wpre += wsum[i];
    unsigned excl = wpre + si - s;
    if (excl < k && k <= excl + s) {
        unsigned cum = excl;
        int bsel = -1;
#pragma unroll
        for (int i = 0; i < 16; ++i) {
            uint4 v = hp[i];
            unsigned b4[4] = {v.x, v.y, v.z, v.w};
#pragma unroll
            for (int jj = 0; jj < 4; ++jj) {
                if (bsel < 0) {
                    if (cum + b4[jj] >= k) bsel = 4 * i + jj;
                    else cum += b4[jj];
                }
            }
        }
        s_hi = 0xFFFFu ^ (unsigned)(t * 64 + bsel);
        s_rem = k - cum;
    }
    __syncthreads();
    unsigned hi = s_hi, rem = s_rem;
    // zero own bins before lo-hist accumulation
#pragma unroll
    for (int i = 0; i < 16; ++i) hpw[i] = z;
    __syncthreads();

    // ---- phase B: lo-16 histogram of keys in the hi bin ----
    for (int i = t; i < n; i += 1024) {
        unsigned u = key[i];
        if ((u >> 16) == hi) atomicAdd(&hist[0xFFFFu ^ (u & 0xFFFFu)], 1u);
    }
    __syncthreads();

    // ---- phase C: pick lo-16 bin ----
    s = 0;
#pragma unroll
    for (int i = 0; i < 16; ++i) {
        uint4 v = hp[i];
        s += v.x + v.y + v.z + v.w;
    }
    si = s;
#pragma unroll
    for (int off = 1; off < 64; off <<= 1) {
        unsigned vv = __shfl_up(si, off);
        if (lane >= off) si += vv;
    }
    if (lane == 63) wsum[w] = si;
    __syncthreads();
    wpre = 0;
    for (int i = 0; i < w; ++i) wpre += wsum[i];
    excl = wpre + si - s;
    if (excl < rem && rem <= excl + s) {
        unsigned cum = excl;
        int bsel = -1;
#pragma unroll
        for (int i = 0; i < 16; ++i) {
            uint4 v = hp[i];
            unsigned b4[4] = {v.x, v.y, v.z, v.w};
#pragma unroll
            for (int jj = 0; jj < 4; ++jj) {
                if (bsel < 0) {
                    if (cum + b4[jj] >= rem) bsel = 4 * i + jj;
                    else cum += b4[jj];
                }
            }
        }
        sel[0] = (hi << 16) | (0xFFFFu ^ (unsigned)(t * 64 + bsel));
        sel[1] = rem - cum;
    }
    __syncthreads();
    // zero for next stage
#pragma unroll
    for (int i = 0; i < 16; ++i) hpw[i] = z;
}

// ---------------- multi-block deterministic select + compact ----------------
__global__ void sc_partial(const unsigned* __restrict__ key, int n, const unsigned* __restrict__ sel,
                           int* __restrict__ gpart, int* __restrict__ epart) {
    unsigned thr = sel[0];
    int base = blockIdx.x * 1024 + (int)threadIdx.x * 4;
    int gs = 0, es = 0;
#pragma unroll
    for (int t = 0; t < 4; ++t) {
        int i = base + t;
        if (i < n) {
            unsigned u = key[i];
            gs += (u > thr); es += (u == thr);
        }
    }
    for (int off = 32; off > 0; off >>= 1) {
        gs += __shfl_down(gs, off);
        es += __shfl_down(es, off);
    }
    __shared__ int sg[4], se[4];
    int wid = threadIdx.x >> 6;
    if ((threadIdx.x & 63) == 0) { sg[wid] = gs; se[wid] = es; }
    __syncthreads();
    if (threadIdx.x == 0) {
        gpart[blockIdx.x] = sg[0] + sg[1] + sg[2] + sg[3];
        epart[blockIdx.x] = se[0] + se[1] + se[2] + se[3];
    }
}

// reads RAW per-block totals; each block sums its prefix inline (nb <= 20)
__global__ void sc_final(const unsigned* __restrict__ key, int n, const unsigned* __restrict__ sel,
                         const int* __restrict__ gpart, const int* __restrict__ epart,
                         int* __restrict__ kept, int* __restrict__ inv) {
    unsigned thr = sel[0];
    int tie = (int)sel[1];
    int gp0 = 0, ep0 = 0;
    for (int b = 0; b < (int)blockIdx.x; ++b) { gp0 += gpart[b]; ep0 += epart[b]; }
    int base = blockIdx.x * 1024 + (int)threadIdx.x * 4;
    int gl[4], el[4];
    int gs = 0, es = 0;
#pragma unroll
    for (int t = 0; t < 4; ++t) {
        int i = base + t;
        gl[t] = 0; el[t] = 0;
        if (i < n) {
            unsigned u = key[i];
            gl[t] = (u > thr); el[t] = (u == thr);
        }
        gs += gl[t]; es += el[t];
    }
    int lane = threadIdx.x & 63, wid = threadIdx.x >> 6;
    int gi = gs, ei = es;
    for (int off = 1; off < 64; off <<= 1) {
        int gg = __shfl_up(gi, off), ee = __shfl_up(ei, off);
        if (lane >= off) { gi += gg; ei += ee; }
    }
    __shared__ int wg[4], we[4];
    if (lane == 63) { wg[wid] = gi; we[wid] = ei; }
    __syncthreads();
    int wgo = 0, weo = 0;
    for (int w = 0; w < wid; ++w) { wgo += wg[w]; weo += we[w]; }
    int gp = gp0 + (gi - gs) + wgo;
    int ep = ep0 + (ei - es) + weo;
#pragma unroll
    for (int t = 0; t < 4; ++t) {
        int i = base + t;
        if (i < n) {
            int keep = gl[t] | (el[t] & ((ep < tie) ? 1 : 0));
            kept[i] = keep;
            inv[i] = gp + ((ep < tie) ? ep : tie);
        }
        gp += gl[t]; ep += el[t];
    }
}

// ---------------- pool apply: wave per node, applies norm+relu on the fly, bf16 out (C=512) ----------------
__global__ void pool_apply_rows(const float* __restrict__ h, const float* __restrict__ score,
                                const int* __restrict__ kept, const int* __restrict__ inv,
                                int n, const float* __restrict__ S, float inv_cnt,
                                const float* __restrict__ lnw, const float* __restrict__ lnb,
                                ushort* __restrict__ hp) {
    int node = blockIdx.x * (blockDim.x >> 6) + ((int)threadIdx.x >> 6);
    if (node >= n) return;
    if (!kept[node]) return;
    int lane = threadIdx.x & 63;
    float mean = S[0] * inv_cnt;
    float var = S[1] * inv_cnt - mean * mean;
    float istd = 1.f / (sqrtf(fmaxf(var, 0.f)) + EPSV);
    float tw = tanhf(score[node]);
    const float4* src = reinterpret_cast<const float4*>(&h[(size_t)node * C1]);
    ushort4* dst = reinterpret_cast<ushort4*>(&hp[(size_t)inv[node] * C1]);
#pragma unroll
    for (int v = 0; v < 2; ++v) {
        int idx = lane + 64 * v;
        float4 a = src[idx];
        float4 w = reinterpret_cast<const float4*>(lnw)[idx];
        float4 bb = reinterpret_cast<const float4*>(lnb)[idx];
        ushort4 o;
        o.x = f2bf(fmaxf((a.x - mean) * istd * w.x + bb.x, 0.f) * tw);
        o.y = f2bf(fmaxf((a.y - mean) * istd * w.y + bb.y, 0.f) * tw);
        o.z = f2bf(fmaxf((a.z - mean) * istd * w.z + bb.z, 0.f) * tw);
        o.w = f2bf(fmaxf((a.w - mean) * istd * w.w + bb.w, 0.f) * tw);
        dst[idx] = o;
    }
}

// ---------------- edge relabel ----------------
__global__ void edge_relabel(const int* __restrict__ src, const int* __restrict__ dst, int E,
                             const int* __restrict__ kept, const int* __restrict__ inv,
                             int* __restrict__ src2, int* __restrict__ dst2,
                             int* __restrict__ mask2) {
    int e = blockIdx.x * blockDim.x + threadIdx.x;
    if (e >= E) return;
    int s = src[e], d = dst[e];
    int m = kept[s] & kept[d];
    mask2[e] = m;
    src2[e] = m ? inv[s] : 0;
    dst2[e] = m ? inv[d] : 0;
}

// ---------------- masked weighted column mean (norm+relu applied on the fly) ----------------
__global__ void colmean_part(const float* __restrict__ h, const float* __restrict__ score,
                             const int* __restrict__ kept, int n, const float* __restrict__ S,
                             float inv_cnt, const float* __restrict__ lnw,
                             const float* __restrict__ lnb, float* __restrict__ Gp) {
    __shared__ float w[CM_ROWS];
    int i0 = blockIdx.x * CM_ROWS;
    int t = threadIdx.x;
    float mean = S[0] * inv_cnt;
    float var = S[1] * inv_cnt - mean * mean;
    float istd = 1.f / (sqrtf(fmaxf(var, 0.f)) + EPSV);
    float wn = lnw[t] * istd;
    float bn = lnb[t] - mean * wn;
    for (int i = t; i < CM_ROWS; i += 256) {
        int idx = i0 + i;
        w[i] = (idx < n && kept[idx]) ? tanhf(score[idx]) : 0.f;
    }
    __syncthreads();
    float acc = 0.f;
    int rows = min(CM_ROWS, n - i0);
#pragma unroll 8
    for (int ri = 0; ri < rows; ++ri)
        acc = fmaf(w[ri], fmaxf(fmaf(h[(size_t)(i0 + ri) * C2 + t], wn, bn), 0.f), acc);
    Gp[blockIdx.x * 256 + t] = acc;
}

__global__ void colmean_final(const float* __restrict__ Gp, int nb, float invk,
                              float* __restrict__ g) {
    int t = threadIdx.x;  // 256
    float s = 0.f;
    for (int b = 0; b < nb; ++b) s += Gp[b * 256 + t];
    g[t] = s * invk;
}

__global__ void final_gemv(const float* __restrict__ g, const float* __restrict__ Wf,
                           const float* __restrict__ bf, float* __restrict__ out) {
    int j = threadIdx.x;  // 128
    float s = bf[j];
    for (int c = 0; c < 256; ++c) s += g[c] * Wf[c * NOUT + j];
    out[j] = s;
}

// =======================================================================================
extern "C" void kernel_launch(void* const* d_in, const int* in_sizes, int n_in,
                              void* d_out, int out_size, void* d_ws, size_t ws_size,
                              hipStream_t stream) {
    const float* x      = (const float*)d_in[0];
    const int*   ei     = (const int*)d_in[1];
    const float* W1     = (const float*)d_in[2];
    const float* b1     = (const float*)d_in[3];
    const float* ln1w   = (const float*)d_in[4];
    const float* ln1b   = (const float*)d_in[5];
    const float* p1wrel = (const float*)d_in[6];
    const float* p1brel = (const float*)d_in[7];
    const float* p1wroot= (const float*)d_in[8];
    const float* W2     = (const float*)d_in[9];
    const float* b2     = (const float*)d_in[10];
    const float* ln2w   = (const float*)d_in[11];
    const float* ln2b   = (const float*)d_in[12];
    const float* p2wrel = (const float*)d_in[13];
    const float* p2brel = (const float*)d_in[14];
    const float* p2wroot= (const float*)d_in[15];
    const float* Wf     = (const float*)d_in[16];
    const float* bf     = (const float*)d_in[17];
    float* out = (float*)d_out;
    char* ws = (char*)d_ws;

    const int* src1 = ei;
    const int* dst1 = ei + NE;

    // ---- workspace layout (bytes) ----
    const size_t o0     = 0;          // 40.96 MB: h1 f32; later h2 f32 @+0, xW2b bf16 @+10,240,000
    const size_t o1     = 40960000;   // 10.24 MB: aggb bf16; later h1pb bf16
    const size_t oXb    = 51200000;   // 10,240,000 : xb bf16
    const size_t oW1t   = 61440000;
    const size_t oW2t   = 61702144;
    const size_t oSrc2  = 61964288;
    const size_t oDst2  = 63244288;
    const size_t oMask2 = 64524288;
    const size_t oCsr   = 65804288;
    const size_t oRow   = 67084288;
    const size_t oCur   = 67164352;
    const size_t oDeg   = 67244352;
    const size_t oDinv  = 67324352;
    const size_t oR     = 67404352;
    const size_t oScore1= 67484352;
    const size_t oKeyu  = 67564352;
    const size_t oKept  = 67644352;
    const size_t oInv   = 67724352;
    const size_t oScore2= 67804352;
    const size_t oKeyu2 = 67844352;
    const size_t oKept2 = 67884352;
    const size_t oInv2  = 67924352;
    const size_t oS     = 67964352;
    const size_t oSel   = 67964416;
    const size_t oGpart = 67964480;
    const size_t oEpart = 67964736;
    const size_t oG     = 67964992;
    const size_t oHist  = 67970112;   // 262,144
    const size_t oGp    = 68232256;   // 81,920 : colmean partials
    const size_t oSp    = 68314176;   // 32,768 : stats partials

    float*  h1    = (float*)(ws + o0);
    float*  h2    = (float*)(ws + o0);
    ushort* xW2b  = (ushort*)(ws + o0 + 10240000);
    ushort* aggb  = (ushort*)(ws + o1);
    ushort* h1pb  = (ushort*)(ws + o1);
    ushort* xb    = (ushort*)(ws + oXb);
    ushort* W1t   = (ushort*)(ws + oW1t);
    ushort* W2t   = (ushort*)(ws + oW2t);
    int*    src2  = (int*)(ws + oSrc2);
    int*    dst2  = (int*)(ws + oDst2);
    int*    mask2 = (int*)(ws + oMask2);
    int*    csr   = (int*)(ws + oCsr);
    int*    row   = (int*)(ws + oRow);
    int*    cur   = (int*)(ws + oCur);
    float*  deg   = (float*)(ws + oDeg);
    float*  dinv  = (float*)(ws + oDinv);
    float*  r     = (float*)(ws + oR);
    float*  score1= (float*)(ws + oScore1);
    unsigned* keyu  = (unsigned*)(ws + oKeyu);
    int*    kept  = (int*)(ws + oKept);
    int*    inv   = (int*)(ws + oInv);
    float*  score2= (float*)(ws + oScore2);
    unsigned* keyu2 = (unsigned*)(ws + oKeyu2);
    int*    kept2 = (int*)(ws + oKept2);
    int*    inv2  = (int*)(ws + oInv2);
    float*  S     = (float*)(ws + oS);
    unsigned* sel  = (unsigned*)(ws + oSel);
    int*    gpart = (int*)(ws + oGpart);
    int*    epart = (int*)(ws + oEpart);
    float*  g     = (float*)(ws + oG);
    unsigned* hist = (unsigned*)(ws + oHist);
    float*  Gp    = (float*)(ws + oGp);
    float*  Sp    = (float*)(ws + oSp);

    const int nb1 = cdiv(N1, 1024);     // 20
    const int nb2 = cdiv(K1, 1024);     // 10
    const int nbc = cdiv(K1, CM_ROWS);  // 79
    const int g1x = cdiv(N1, 128), g1y = C1 / 128;   // 157 x 4 stat blocks
    const int agg2b = cdiv(K1, 4);      // 2500 stat blocks

    // ================= Stage 1 =================
    f32_to_bf16<<<cdiv(N1 * CIN / 4, 256), 256, 0, stream>>>(x, xb, N1 * CIN / 4);

    fill_i32<<<cdiv(N1, 256), 256, 0, stream>>>(cur, 0, N1);
    fill_i32<<<cdiv(65536, 256), 256, 0, stream>>>((int*)hist, 0, 65536);  // select_thresh self-zeroes after
    count_deg<<<cdiv(NE, 256), 256, 0, stream>>>(dst1, nullptr, NE, cur);
    dp_partial<<<nb1, 256, 0, stream>>>(cur, N1, gpart);
    scan64k<<<1, 64, 0, stream>>>(nb1, gpart, row + N1);
    dp_final<<<nb1, 256, 0, stream>>>(cur, N1, gpart, row, cur, deg, dinv);
    csr_scatter<<<cdiv(NE, 256), 256, 0, stream>>>(src1, dst1, nullptr, NE, cur, csr);

    aggregate_xb<<<cdiv(N1, 4), 256, 0, stream>>>(row, csr, deg, dinv, xb, aggb, N1);

    conv_transpose_bf16<<<cdiv(CIN * C1, 256), 256, 0, stream>>>(W1, W1t, CIN, C1);
    gemm_bf16_mfma<false, true><<<dim3(g1x, g1y), 256, 0, stream>>>(
        aggb, W1t, b1, h1, nullptr, Sp, N1, C1, CIN);
    reduce_final<<<1, 256, 0, stream>>>(Sp, g1x * g1y, S);

    norm_scores<C1><<<cdiv(N1, 4), 256, 0, stream>>>(h1, N1, S, 1.f / ((float)N1 * C1),
                                                     ln1w, ln1b, p1wrel, p1brel, p1wroot, r, score1);
    gather_score_key<<<cdiv(N1, 256), 256, 0, stream>>>(row, csr, r, score1, keyu, hist, N1);

    select_thresh<<<1, 1024, 0, stream>>>(keyu, N1, K1, hist, sel);
    sc_partial<<<nb1, 256, 0, stream>>>(keyu, N1, sel, gpart, epart);
    sc_final<<<nb1, 256, 0, stream>>>(keyu, N1, sel, gpart, epart, kept, inv);

    pool_apply_rows<<<cdiv(N1, 4), 256, 0, stream>>>(h1, score1, kept, inv, N1, S,
                                                     1.f / ((float)N1 * C1), ln1w, ln1b, h1pb);
    edge_relabel<<<cdiv(NE, 256), 256, 0, stream>>>(src1, dst1, NE, kept, inv, src2, dst2, mask2);

    // ================= Stage 2 =================
    conv_transpose_bf16<<<cdiv(C1 * C2, 256), 256, 0, stream>>>(W2, W2t, C1, C2);
    gemm_bf16_mfma<true, false><<<dim3(cdiv(K1, 128), C2 / 128), 256, 0, stream>>>(
        h1pb, W2t, nullptr, nullptr, xW2b, nullptr, K1, C2, C1);

    fill_i32<<<cdiv(K1, 256), 256, 0, stream>>>(cur, 0, K1);
    count_deg<<<cdiv(NE, 256), 256, 0, stream>>>(dst2, mask2, NE, cur);
    dp_partial<<<nb2, 256, 0, stream>>>(cur, K1, gpart);
    scan64k<<<1, 64, 0, stream>>>(nb2, gpart, row + K1);
    dp_final<<<nb2, 256, 0, stream>>>(cur, K1, gpart, row, cur, deg, dinv);
    csr_scatter<<<cdiv(NE, 256), 256, 0, stream>>>(src2, dst2, mask2, NE, cur, csr);

    aggregate_csr_bf<<<agg2b, 256, 0, stream>>>(row, csr, deg, dinv, xW2b, b2, h2, Sp, K1);
    reduce_final<<<1, 256, 0, stream>>>(Sp, agg2b, S);

    norm_scores<C2><<<cdiv(K1, 4), 256, 0, stream>>>(h2, K1, S, 1.f / ((float)K1 * C2),
                                                     ln2w, ln2b, p2wrel, p2brel, p2wroot, r, score2);
    gather_score_key<<<cdiv(K1, 256), 256, 0, stream>>>(row, csr, r, score2, keyu2, hist, K1);

    select_thresh<<<1, 1024, 0, stream>>>(keyu2, K1, K2, hist, sel);
    sc_partial<<<nb2, 256, 0, stream>>>(keyu2, K1, sel, gpart, epart);
    sc_final<<<nb2, 256, 0, stream>>>(keyu2, K1, sel, gpart, epart, kept2, inv2);

    // ================= readout =================
    colmean_part<<<nbc, 256, 0, stream>>>(h2, score2, kept2, K1, S, 1.f / ((float)K1 * C2),
                                          ln2w, ln2b, Gp);
    colmean_final<<<1, 256, 0, stream>>>(Gp, nbc, 1.f / (float)K2, g);
    final_gemv<<<1, NOUT, 0, stream>>>(g, Wf, bf, out);
}

// Round 11
// 297.865 us; speedup vs baseline: 10.3874x; 1.2446x over previous
//
#include <hip/hip_runtime.h>
#include <math.h>

#define N1 20000
#define NE 320000
#define CIN 256
#define C1 512
#define C2 256
#define K1 10000
#define K2 5000
#define NOUT 128
#define EPSV 1e-5f
#define CM_ROWS 128

typedef __attribute__((ext_vector_type(8))) short bf16x8;
typedef __attribute__((ext_vector_type(4))) float f32x4;

static inline unsigned cdiv(unsigned a, unsigned b) { return (a + b - 1) / b; }

__device__ inline ushort f2bf(float f) {
    unsigned u = __float_as_uint(f);
    unsigned r = u + 0x7FFFu + ((u >> 16) & 1u);
    return (ushort)(r >> 16);
}
__device__ inline float bf2f(ushort u) { return __uint_as_float(((unsigned)u) << 16); }

// ---------------- fills ----------------
__global__ void fill_i32(int* __restrict__ p, int v, int n) {
    int i = blockIdx.x * blockDim.x + threadIdx.x;
    if (i < n) p[i] = v;
}

// ---------------- f32 -> bf16 ----------------
__global__ void f32_to_bf16(const float* __restrict__ in, ushort* __restrict__ out, int n4) {
    int i = blockIdx.x * blockDim.x + threadIdx.x;
    if (i >= n4) return;
    float4 v = reinterpret_cast<const float4*>(in)[i];
    ushort4 o;
    o.x = f2bf(v.x); o.y = f2bf(v.y); o.z = f2bf(v.z); o.w = f2bf(v.w);
    reinterpret_cast<ushort4*>(out)[i] = o;
}

// ---------------- weight convert+transpose ----------------
__global__ void conv_transpose_bf16(const float* __restrict__ W, ushort* __restrict__ Wt,
                                    int K, int N) {
    int i = blockIdx.x * blockDim.x + threadIdx.x;
    if (i >= K * N) return;
    int k = i / N, n = i % N;
    Wt[(size_t)n * K + k] = f2bf(W[i]);
}

// ---------------- MFMA bf16 GEMM (optional fused sum/sumsq stats) ----------------
template <bool BF16OUT, bool STATS>
__global__ __launch_bounds__(256)
void gemm_bf16_mfma(const ushort* __restrict__ A, const ushort* __restrict__ Bt,
                    const float* __restrict__ bias, float* __restrict__ C,
                    ushort* __restrict__ Cb, float* __restrict__ Sp, int M, int N, int K) {
    constexpr int BM = 128, BN = 128, BK = 32;
    constexpr int LDK = BK + 8;
    __shared__ ushort As[BM * LDK];
    __shared__ ushort Bs[BN * LDK];
    int tid = threadIdx.x;
    int wid = tid >> 6, lane = tid & 63;
    int wr = wid >> 1, wc = wid & 1;
    int bm = blockIdx.x * BM, bn = blockIdx.y * BN;
    int lg = lane >> 4, lm = lane & 15;
    f32x4 zero = {0.f, 0.f, 0.f, 0.f};
    f32x4 acc[4][4];
#pragma unroll
    for (int m = 0; m < 4; ++m)
#pragma unroll
        for (int n = 0; n < 4; ++n) acc[m][n] = zero;

    for (int k0 = 0; k0 < K; k0 += BK) {
#pragma unroll
        for (int it = 0; it < 2; ++it) {
            int task = tid * 2 + it;
            int row = task >> 2, c8 = (task & 3) * 8;
            int gm = bm + row;
            bf16x8 v = {0, 0, 0, 0, 0, 0, 0, 0};
            if (gm < M) v = *(const bf16x8*)&A[(size_t)gm * K + k0 + c8];
            *(bf16x8*)&As[row * LDK + c8] = v;
            int gn = bn + row;
            bf16x8 w = {0, 0, 0, 0, 0, 0, 0, 0};
            if (gn < N) w = *(const bf16x8*)&Bt[(size_t)gn * K + k0 + c8];
            *(bf16x8*)&Bs[row * LDK + c8] = w;
        }
        __syncthreads();
        bf16x8 af[4], bfr[4];
#pragma unroll
        for (int m = 0; m < 4; ++m)
            af[m] = *(bf16x8*)&As[(wr * 64 + m * 16 + lm) * LDK + lg * 8];
#pragma unroll
        for (int n = 0; n < 4; ++n)
            bfr[n] = *(bf16x8*)&Bs[(wc * 64 + n * 16 + lm) * LDK + lg * 8];
#pragma unroll
        for (int m = 0; m < 4; ++m)
#pragma unroll
            for (int n = 0; n < 4; ++n)
                acc[m][n] = __builtin_amdgcn_mfma_f32_16x16x32_bf16(af[m], bfr[n], acc[m][n], 0, 0, 0);
        __syncthreads();
    }
    float ls = 0.f, lq = 0.f;
#pragma unroll
    for (int m = 0; m < 4; ++m) {
#pragma unroll
        for (int n = 0; n < 4; ++n) {
            int col = bn + wc * 64 + n * 16 + lm;
            float bv = bias ? bias[col] : 0.f;
#pragma unroll
            for (int r = 0; r < 4; ++r) {
                int row = bm + wr * 64 + m * 16 + lg * 4 + r;
                if (row < M) {
                    float val = acc[m][n][r] + bv;
                    if (BF16OUT) Cb[(size_t)row * N + col] = f2bf(val);
                    else         C[(size_t)row * N + col] = val;
                    if (STATS) { ls += val; lq += val * val; }
                }
            }
        }
    }
    if (STATS) {
        __shared__ float rs[256], rq[256];
        rs[tid] = ls; rq[tid] = lq;
        __syncthreads();
        for (int off = 128; off > 0; off >>= 1) {
            if (tid < off) { rs[tid] += rs[tid + off]; rq[tid] += rq[tid + off]; }
            __syncthreads();
        }
        if (tid == 0) {
            int b = blockIdx.y * gridDim.x + blockIdx.x;
            Sp[2 * b] = rs[0];
            Sp[2 * b + 1] = rq[0];
        }
    }
}

// ---------------- CSR build ----------------
__global__ void count_deg(const int* __restrict__ dst, const int* __restrict__ mask, int E,
                          int* __restrict__ cnt) {
    int e = blockIdx.x * blockDim.x + threadIdx.x;
    if (e >= E) return;
    if (mask && !mask[e]) return;
    atomicAdd(&cnt[dst[e]], 1);
}

__global__ void dp_partial(const int* __restrict__ cnt, int n, int* __restrict__ part) {
    int base = blockIdx.x * 1024 + (int)threadIdx.x * 4;
    int s = 0;
#pragma unroll
    for (int t = 0; t < 4; ++t) {
        int i = base + t;
        if (i < n) s += cnt[i];
    }
    for (int off = 32; off > 0; off >>= 1) s += __shfl_down(s, off);
    __shared__ int sg[4];
    int wid = threadIdx.x >> 6;
    if ((threadIdx.x & 63) == 0) sg[wid] = s;
    __syncthreads();
    if (threadIdx.x == 0) part[blockIdx.x] = sg[0] + sg[1] + sg[2] + sg[3];
}

__global__ void scan64k(int nb, int* __restrict__ part, int* __restrict__ row_n) {
    int lane = threadIdx.x;
    int v0 = (lane < nb) ? part[lane] : 0;
    int v = v0;
    for (int off = 1; off < 64; off <<= 1) {
        int vv = __shfl_up(v, off);
        if (lane >= off) v += vv;
    }
    if (lane == nb - 1) row_n[0] = v;
    if (lane < nb) part[lane] = v - v0;
}

__global__ void dp_final(const int* __restrict__ cnt, int n, const int* __restrict__ part,
                         int* __restrict__ rowstart, int* __restrict__ cursor,
                         float* __restrict__ deg, float* __restrict__ dinv) {
    int base = blockIdx.x * 1024 + (int)threadIdx.x * 4;
    int c[4];
    int s = 0;
#pragma unroll
    for (int t = 0; t < 4; ++t) {
        int i = base + t;
        c[t] = (i < n) ? cnt[i] : 0;
        s += c[t];
    }
    int lane = threadIdx.x & 63, wid = threadIdx.x >> 6;
    int si = s;
    for (int off = 1; off < 64; off <<= 1) {
        int vv = __shfl_up(si, off);
        if (lane >= off) si += vv;
    }
    __shared__ int wg[4];
    if (lane == 63) wg[wid] = si;
    __syncthreads();
    int woff = 0;
    for (int w = 0; w < wid; ++w) woff += wg[w];
    int excl = part[blockIdx.x] + (si - s) + woff;
#pragma unroll
    for (int t = 0; t < 4; ++t) {
        int i = base + t;
        if (i < n) {
            rowstart[i] = excl;
            cursor[i] = excl;
            float dg = (float)c[t] + 2.0f;
            deg[i] = dg;
            dinv[i] = rsqrtf(dg);
        }
        excl += c[t];
    }
}

__global__ void csr_scatter(const int* __restrict__ src, const int* __restrict__ dst,
                            const int* __restrict__ mask, int E,
                            int* __restrict__ cursor, int* __restrict__ csr_src) {
    int e = blockIdx.x * blockDim.x + threadIdx.x;
    if (e >= E) return;
    if (mask && !mask[e]) return;
    int pos = atomicAdd(&cursor[dst[e]], 1);
    csr_src[pos] = src[e];
}

// ---------------- stage-1 aggregation: 8-deep pipelined gather (bf16 in/out) ----------------
__global__ void aggregate_xb(const int* __restrict__ rowstart, const int* __restrict__ csr_src,
                             const float* __restrict__ deg, const float* __restrict__ dinv,
                             const ushort* __restrict__ xb, ushort* __restrict__ out, int n) {
    int node = blockIdx.x * (blockDim.x >> 6) + ((int)threadIdx.x >> 6);
    if (node >= n) return;
    int lane = threadIdx.x & 63;
    int beg = rowstart[node], end = rowstart[node + 1];
    float di = dinv[node];
    float4 acc = make_float4(0.f, 0.f, 0.f, 0.f);
    int j = beg;
    for (; j + 8 <= end; j += 8) {
        int s[8];
#pragma unroll
        for (int u = 0; u < 8; ++u) s[u] = csr_src[j + u];
        float c[8];
#pragma unroll
        for (int u = 0; u < 8; ++u) c[u] = dinv[s[u]] * di;
        ushort4 t[8];
#pragma unroll
        for (int u = 0; u < 8; ++u)
            t[u] = reinterpret_cast<const ushort4*>(&xb[(size_t)s[u] * CIN])[lane];
#pragma unroll
        for (int u = 0; u < 8; ++u) {
            acc.x += c[u] * bf2f(t[u].x);
            acc.y += c[u] * bf2f(t[u].y);
            acc.z += c[u] * bf2f(t[u].z);
            acc.w += c[u] * bf2f(t[u].w);
        }
    }
    for (; j < end; ++j) {
        int s = csr_src[j];
        float coef = dinv[s] * di;
        ushort4 t = reinterpret_cast<const ushort4*>(&xb[(size_t)s * CIN])[lane];
        acc.x += coef * bf2f(t.x);
        acc.y += coef * bf2f(t.y);
        acc.z += coef * bf2f(t.z);
        acc.w += coef * bf2f(t.w);
    }
    float self = 2.0f / deg[node];
    ushort4 t = reinterpret_cast<const ushort4*>(&xb[(size_t)node * CIN])[lane];
    acc.x += self * bf2f(t.x);
    acc.y += self * bf2f(t.y);
    acc.z += self * bf2f(t.z);
    acc.w += self * bf2f(t.w);
    ushort4 o;
    o.x = f2bf(acc.x); o.y = f2bf(acc.y); o.z = f2bf(acc.z); o.w = f2bf(acc.w);
    reinterpret_cast<ushort4*>(&out[(size_t)node * CIN])[lane] = o;
}

// ---------------- stage-2 aggregation: 8-deep gather, f32 out + bias + self + fused stats ----------------
__global__ void aggregate_csr_bf(const int* __restrict__ rowstart, const int* __restrict__ csr_src,
                                 const float* __restrict__ deg, const float* __restrict__ dinv,
                                 const ushort* __restrict__ xWb, const float* __restrict__ b,
                                 float* __restrict__ out, float* __restrict__ Sp, int n) {
    int node = blockIdx.x * (blockDim.x >> 6) + ((int)threadIdx.x >> 6);
    bool valid = node < n;
    int lane = threadIdx.x & 63;
    float ls = 0.f, lq = 0.f;
    if (valid) {
        int beg = rowstart[node], end = rowstart[node + 1];
        float di = dinv[node];
        float4 acc = make_float4(0.f, 0.f, 0.f, 0.f);
        int j = beg;
        for (; j + 8 <= end; j += 8) {
            int s[8];
#pragma unroll
            for (int u = 0; u < 8; ++u) s[u] = csr_src[j + u];
            float c[8];
#pragma unroll
            for (int u = 0; u < 8; ++u) c[u] = dinv[s[u]] * di;
            ushort4 t[8];
#pragma unroll
            for (int u = 0; u < 8; ++u)
                t[u] = reinterpret_cast<const ushort4*>(&xWb[(size_t)s[u] * C2])[lane];
#pragma unroll
            for (int u = 0; u < 8; ++u) {
                acc.x += c[u] * bf2f(t[u].x);
                acc.y += c[u] * bf2f(t[u].y);
                acc.z += c[u] * bf2f(t[u].z);
                acc.w += c[u] * bf2f(t[u].w);
            }
        }
        for (; j < end; ++j) {
            int s = csr_src[j];
            float coef = dinv[s] * di;
            ushort4 t = reinterpret_cast<const ushort4*>(&xWb[(size_t)s * C2])[lane];
            acc.x += coef * bf2f(t.x);
            acc.y += coef * bf2f(t.y);
            acc.z += coef * bf2f(t.z);
            acc.w += coef * bf2f(t.w);
        }
        float self = 2.0f / deg[node];
        ushort4 t = reinterpret_cast<const ushort4*>(&xWb[(size_t)node * C2])[lane];
        float4 bb = reinterpret_cast<const float4*>(b)[lane];
        float4 o;
        o.x = acc.x + self * bf2f(t.x) + bb.x;
        o.y = acc.y + self * bf2f(t.y) + bb.y;
        o.z = acc.z + self * bf2f(t.z) + bb.z;
        o.w = acc.w + self * bf2f(t.w) + bb.w;
        reinterpret_cast<float4*>(&out[(size_t)node * C2])[lane] = o;
        ls = o.x + o.y + o.z + o.w;
        lq = o.x * o.x + o.y * o.y + o.z * o.z + o.w * o.w;
    }
    __shared__ float rs[256], rq[256];
    rs[threadIdx.x] = ls; rq[threadIdx.x] = lq;
    __syncthreads();
    for (int off = 128; off > 0; off >>= 1) {
        if ((int)threadIdx.x < off) {
            rs[threadIdx.x] += rs[threadIdx.x + off];
            rq[threadIdx.x] += rq[threadIdx.x + off];
        }
        __syncthreads();
    }
    if (threadIdx.x == 0) {
        Sp[2 * blockIdx.x] = rs[0];
        Sp[2 * blockIdx.x + 1] = rq[0];
    }
}

// ---------------- final stats fold ----------------
__global__ void reduce_final(const float* __restrict__ Sp, int nb, float* __restrict__ S) {
    float s = 0.f, q = 0.f;
    for (int i = threadIdx.x; i < nb; i += 256) {
        s += Sp[2 * i];
        q += Sp[2 * i + 1];
    }
    __shared__ float ls[256], lq[256];
    ls[threadIdx.x] = s; lq[threadIdx.x] = q;
    __syncthreads();
    for (int off = 128; off > 0; off >>= 1) {
        if ((int)threadIdx.x < off) {
            ls[threadIdx.x] += ls[threadIdx.x + off];
            lq[threadIdx.x] += lq[threadIdx.x + off];
        }
        __syncthreads();
    }
    if (threadIdx.x == 0) { S[0] = ls[0]; S[1] = lq[0]; }
}

// ---------------- norm+relu scores (READ-ONLY h; norm re-applied by consumers) ----------------
template <int C>
__global__ void norm_scores(const float* __restrict__ h, int n, const float* __restrict__ S,
                            float inv_cnt, const float* __restrict__ lnw,
                            const float* __restrict__ lnb, const float* __restrict__ wrel,
                            const float* __restrict__ brel, const float* __restrict__ wroot,
                            float* __restrict__ r, float* __restrict__ score) {
    int node = blockIdx.x * (blockDim.x >> 6) + ((int)threadIdx.x >> 6);
    if (node >= n) return;
    int lane = threadIdx.x & 63;
    float mean = S[0] * inv_cnt;
    float var = S[1] * inv_cnt - mean * mean;
    float istd = 1.f / (sqrtf(fmaxf(var, 0.f)) + EPSV);
    const float4* row = reinterpret_cast<const float4*>(&h[(size_t)node * C]);
    float sr = 0.f, st = 0.f;
#pragma unroll
    for (int kk = 0; kk < C / 256; ++kk) {
        int idx = lane + 64 * kk;
        float4 v = row[idx];
        float4 w = reinterpret_cast<const float4*>(lnw)[idx];
        float4 bb = reinterpret_cast<const float4*>(lnb)[idx];
        float4 w4 = reinterpret_cast<const float4*>(wrel)[idx];
        float4 o4 = reinterpret_cast<const float4*>(wroot)[idx];
        v.x = fmaxf((v.x - mean) * istd * w.x + bb.x, 0.f);
        v.y = fmaxf((v.y - mean) * istd * w.y + bb.y, 0.f);
        v.z = fmaxf((v.z - mean) * istd * w.z + bb.z, 0.f);
        v.w = fmaxf((v.w - mean) * istd * w.w + bb.w, 0.f);
        sr += v.x * w4.x + v.y * w4.y + v.z * w4.z + v.w * w4.w;
        st += v.x * o4.x + v.y * o4.y + v.z * o4.z + v.w * o4.w;
    }
    for (int off = 32; off > 0; off >>= 1) {
        sr += __shfl_down(sr, off);
        st += __shfl_down(st, off);
    }
    if (lane == 0) {
        r[node] = sr;
        score[node] = st + brel[0];
    }
}

// ---------------- gather score over CSR + keyify ----------------
__global__ void gather_score_key(const int* __restrict__ rowstart, const int* __restrict__ csr_src,
                                 const float* __restrict__ r, float* __restrict__ score,
                                 unsigned* __restrict__ key, int n) {
    int i = blockIdx.x * blockDim.x + threadIdx.x;
    if (i >= n) return;
    float s = score[i];
    int beg = rowstart[i], end = rowstart[i + 1];
    int j = beg;
    for (; j + 4 <= end; j += 4) {
        int s0 = csr_src[j], s1 = csr_src[j + 1], s2 = csr_src[j + 2], s3 = csr_src[j + 3];
        s += r[s0] + r[s1] + r[s2] + r[s3];
    }
    for (; j < end; ++j) s += r[csr_src[j]];
    score[i] = s;
    unsigned u = __float_as_uint(s);
    key[i] = (u & 0x80000000u) ? ~u : (u | 0x80000000u);
}

// ---------------- register-resident 4x8-bit radix threshold select ----------------
// One 1024-thread block. Keys loaded once to registers (KPT=20 max -> n<=20480).
// Four passes of 256-bin LDS histogram + descending scan. No global histogram.
__global__ void select_thresh_reg(const unsigned* __restrict__ key, int n, unsigned k,
                                  unsigned* __restrict__ sel) {
    __shared__ unsigned hist[256];
    __shared__ unsigned wsum[16];
    __shared__ unsigned s_pref, s_rem;
    int t = threadIdx.x;
    int lane = t & 63, w = t >> 6;

    unsigned kv[20];
#pragma unroll
    for (int i = 0; i < 20; ++i) {
        int idx = t + 1024 * i;
        kv[i] = (idx < n) ? key[idx] : 0u;
    }

    if (t < 256) hist[t] = 0u;
    if (t == 0) { s_pref = 0u; s_rem = k; }
    __syncthreads();

    unsigned pref = 0u, msk = 0u, rem = k;
#pragma unroll
    for (int pass = 0; pass < 4; ++pass) {
        int shift = 24 - 8 * pass;
        // fill histogram from registers
#pragma unroll
        for (int i = 0; i < 20; ++i) {
            int idx = t + 1024 * i;
            if (idx < n && (kv[i] & msk) == pref)
                atomicAdd(&hist[(kv[i] >> shift) & 255u], 1u);
        }
        __syncthreads();
        // descending scan: thread t<256 owns bin (255-t)
        unsigned val = (t < 256) ? hist[255 - t] : 0u;
        unsigned si = val;
#pragma unroll
        for (int off = 1; off < 64; off <<= 1) {
            unsigned vv = __shfl_up(si, off);
            if (lane >= off) si += vv;
        }
        if (lane == 63 && w < 4) wsum[w] = si;
        __syncthreads();
        if (t < 256) hist[t] = 0u;  // all reads done; ready for next pass
        if (t < 256) {
            unsigned wpre = 0u;
            for (int i = 0; i < w; ++i) wpre += wsum[i];
            unsigned incl = wpre + si;
            unsigned excl = incl - val;
            if (excl < rem && rem <= incl) {
                s_pref = pref | ((unsigned)(255 - t) << shift);
                s_rem = rem - excl;
            }
        }
        __syncthreads();
        pref = s_pref;
        rem = s_rem;
        msk = 0xFFFFFFFFu << shift;
    }
    if (t == 0) { sel[0] = pref; sel[1] = rem; }
}

// ---------------- multi-block deterministic select + compact ----------------
__global__ void sc_partial(const unsigned* __restrict__ key, int n, const unsigned* __restrict__ sel,
                           int* __restrict__ gpart, int* __restrict__ epart) {
    unsigned thr = sel[0];
    int base = blockIdx.x * 1024 + (int)threadIdx.x * 4;
    int gs = 0, es = 0;
#pragma unroll
    for (int t = 0; t < 4; ++t) {
        int i = base + t;
        if (i < n) {
            unsigned u = key[i];
            gs += (u > thr); es += (u == thr);
        }
    }
    for (int off = 32; off > 0; off >>= 1) {
        gs += __shfl_down(gs, off);
        es += __shfl_down(es, off);
    }
    __shared__ int sg[4], se[4];
    int wid = threadIdx.x >> 6;
    if ((threadIdx.x & 63) == 0) { sg[wid] = gs; se[wid] = es; }
    __syncthreads();
    if (threadIdx.x == 0) {
        gpart[blockIdx.x] = sg[0] + sg[1] + sg[2] + sg[3];
        epart[blockIdx.x] = se[0] + se[1] + se[2] + se[3];
    }
}

// reads RAW per-block totals; each block sums its prefix inline (nb <= 20)
__global__ void sc_final(const unsigned* __restrict__ key, int n, const unsigned* __restrict__ sel,
                         const int* __restrict__ gpart, const int* __restrict__ epart,
                         int* __restrict__ kept, int* __restrict__ inv) {
    unsigned thr = sel[0];
    int tie = (int)sel[1];
    int gp0 = 0, ep0 = 0;
    for (int b = 0; b < (int)blockIdx.x; ++b) { gp0 += gpart[b]; ep0 += epart[b]; }
    int base = blockIdx.x * 1024 + (int)threadIdx.x * 4;
    int gl[4], el[4];
    int gs = 0, es = 0;
#pragma unroll
    for (int t = 0; t < 4; ++t) {
        int i = base + t;
        gl[t] = 0; el[t] = 0;
        if (i < n) {
            unsigned u = key[i];
            gl[t] = (u > thr); el[t] = (u == thr);
        }
        gs += gl[t]; es += el[t];
    }
    int lane = threadIdx.x & 63, wid = threadIdx.x >> 6;
    int gi = gs, ei = es;
    for (int off = 1; off < 64; off <<= 1) {
        int gg = __shfl_up(gi, off), ee = __shfl_up(ei, off);
        if (lane >= off) { gi += gg; ei += ee; }
    }
    __shared__ int wg[4], we[4];
    if (lane == 63) { wg[wid] = gi; we[wid] = ei; }
    __syncthreads();
    int wgo = 0, weo = 0;
    for (int w = 0; w < wid; ++w) { wgo += wg[w]; weo += we[w]; }
    int gp = gp0 + (gi - gs) + wgo;
    int ep = ep0 + (ei - es) + weo;
#pragma unroll
    for (int t = 0; t < 4; ++t) {
        int i = base + t;
        if (i < n) {
            int keep = gl[t] | (el[t] & ((ep < tie) ? 1 : 0));
            kept[i] = keep;
            inv[i] = gp + ((ep < tie) ? ep : tie);
        }
        gp += gl[t]; ep += el[t];
    }
}

// ---------------- pool apply: wave per node, applies norm+relu on the fly, bf16 out (C=512) ----------------
__global__ void pool_apply_rows(const float* __restrict__ h, const float* __restrict__ score,
                                const int* __restrict__ kept, const int* __restrict__ inv,
                                int n, const float* __restrict__ S, float inv_cnt,
                                const float* __restrict__ lnw, const float* __restrict__ lnb,
                                ushort* __restrict__ hp) {
    int node = blockIdx.x * (blockDim.x >> 6) + ((int)threadIdx.x >> 6);
    if (node >= n) return;
    if (!kept[node]) return;
    int lane = threadIdx.x & 63;
    float mean = S[0] * inv_cnt;
    float var = S[1] * inv_cnt - mean * mean;
    float istd = 1.f / (sqrtf(fmaxf(var, 0.f)) + EPSV);
    float tw = tanhf(score[node]);
    const float4* src = reinterpret_cast<const float4*>(&h[(size_t)node * C1]);
    ushort4* dst = reinterpret_cast<ushort4*>(&hp[(size_t)inv[node] * C1]);
#pragma unroll
    for (int v = 0; v < 2; ++v) {
        int idx = lane + 64 * v;
        float4 a = src[idx];
        float4 w = reinterpret_cast<const float4*>(lnw)[idx];
        float4 bb = reinterpret_cast<const float4*>(lnb)[idx];
        ushort4 o;
        o.x = f2bf(fmaxf((a.x - mean) * istd * w.x + bb.x, 0.f) * tw);
        o.y = f2bf(fmaxf((a.y - mean) * istd * w.y + bb.y, 0.f) * tw);
        o.z = f2bf(fmaxf((a.z - mean) * istd * w.z + bb.z, 0.f) * tw);
        o.w = f2bf(fmaxf((a.w - mean) * istd * w.w + bb.w, 0.f) * tw);
        dst[idx] = o;
    }
}

// ---------------- edge relabel ----------------
__global__ void edge_relabel(const int* __restrict__ src, const int* __restrict__ dst, int E,
                             const int* __restrict__ kept, const int* __restrict__ inv,
                             int* __restrict__ src2, int* __restrict__ dst2,
                             int* __restrict__ mask2) {
    int e = blockIdx.x * blockDim.x + threadIdx.x;
    if (e >= E) return;
    int s = src[e], d = dst[e];
    int m = kept[s] & kept[d];
    mask2[e] = m;
    src2[e] = m ? inv[s] : 0;
    dst2[e] = m ? inv[d] : 0;
}

// ---------------- masked weighted column mean (norm+relu applied on the fly) ----------------
__global__ void colmean_part(const float* __restrict__ h, const float* __restrict__ score,
                             const int* __restrict__ kept, int n, const float* __restrict__ S,
                             float inv_cnt, const float* __restrict__ lnw,
                             const float* __restrict__ lnb, float* __restrict__ Gp) {
    __shared__ float w[CM_ROWS];
    int i0 = blockIdx.x * CM_ROWS;
    int t = threadIdx.x;
    float mean = S[0] * inv_cnt;
    float var = S[1] * inv_cnt - mean * mean;
    float istd = 1.f / (sqrtf(fmaxf(var, 0.f)) + EPSV);
    float wn = lnw[t] * istd;
    float bn = lnb[t] - mean * wn;
    for (int i = t; i < CM_ROWS; i += 256) {
        int idx = i0 + i;
        w[i] = (idx < n && kept[idx]) ? tanhf(score[idx]) : 0.f;
    }
    __syncthreads();
    float acc = 0.f;
    int rows = min(CM_ROWS, n - i0);
#pragma unroll 8
    for (int ri = 0; ri < rows; ++ri)
        acc = fmaf(w[ri], fmaxf(fmaf(h[(size_t)(i0 + ri) * C2 + t], wn, bn), 0.f), acc);
    Gp[blockIdx.x * 256 + t] = acc;
}

__global__ void colmean_final(const float* __restrict__ Gp, int nb, float invk,
                              float* __restrict__ g) {
    int t = threadIdx.x;  // 256
    float s = 0.f;
    for (int b = 0; b < nb; ++b) s += Gp[b * 256 + t];
    g[t] = s * invk;
}

__global__ void final_gemv(const float* __restrict__ g, const float* __restrict__ Wf,
                           const float* __restrict__ bf, float* __restrict__ out) {
    int j = threadIdx.x;  // 128
    float s = bf[j];
    for (int c = 0; c < 256; ++c) s += g[c] * Wf[c * NOUT + j];
    out[j] = s;
}

// =======================================================================================
extern "C" void kernel_launch(void* const* d_in, const int* in_sizes, int n_in,
                              void* d_out, int out_size, void* d_ws, size_t ws_size,
                              hipStream_t stream) {
    const float* x      = (const float*)d_in[0];
    const int*   ei     = (const int*)d_in[1];
    const float* W1     = (const float*)d_in[2];
    const float* b1     = (const float*)d_in[3];
    const float* ln1w   = (const float*)d_in[4];
    const float* ln1b   = (const float*)d_in[5];
    const float* p1wrel = (const float*)d_in[6];
    const float* p1brel = (const float*)d_in[7];
    const float* p1wroot= (const float*)d_in[8];
    const float* W2     = (const float*)d_in[9];
    const float* b2     = (const float*)d_in[10];
    const float* ln2w   = (const float*)d_in[11];
    const float* ln2b   = (const float*)d_in[12];
    const float* p2wrel = (const float*)d_in[13];
    const float* p2brel = (const float*)d_in[14];
    const float* p2wroot= (const float*)d_in[15];
    const float* Wf     = (const float*)d_in[16];
    const float* bf     = (const float*)d_in[17];
    float* out = (float*)d_out;
    char* ws = (char*)d_ws;

    const int* src1 = ei;
    const int* dst1 = ei + NE;

    // ---- workspace layout (bytes) ----
    const size_t o0     = 0;          // 40.96 MB: h1 f32; later h2 f32 @+0, xW2b bf16 @+10,240,000
    const size_t o1     = 40960000;   // 10.24 MB: aggb bf16; later h1pb bf16
    const size_t oXb    = 51200000;   // 10,240,000 : xb bf16
    const size_t oW1t   = 61440000;
    const size_t oW2t   = 61702144;
    const size_t oSrc2  = 61964288;
    const size_t oDst2  = 63244288;
    const size_t oMask2 = 64524288;
    const size_t oCsr   = 65804288;
    const size_t oRow   = 67084288;
    const size_t oCur   = 67164352;
    const size_t oDeg   = 67244352;
    const size_t oDinv  = 67324352;
    const size_t oR     = 67404352;
    const size_t oScore1= 67484352;
    const size_t oKeyu  = 67564352;
    const size_t oKept  = 67644352;
    const size_t oInv   = 67724352;
    const size_t oScore2= 67804352;
    const size_t oKeyu2 = 67844352;
    const size_t oKept2 = 67884352;
    const size_t oInv2  = 67924352;
    const size_t oS     = 67964352;
    const size_t oSel   = 67964416;
    const size_t oGpart = 67964480;
    const size_t oEpart = 67964736;
    const size_t oG     = 67964992;
    const size_t oGp    = 68232256;   // 81,920 : colmean partials
    const size_t oSp    = 68314176;   // 32,768 : stats partials

    float*  h1    = (float*)(ws + o0);
    float*  h2    = (float*)(ws + o0);
    ushort* xW2b  = (ushort*)(ws + o0 + 10240000);
    ushort* aggb  = (ushort*)(ws + o1);
    ushort* h1pb  = (ushort*)(ws + o1);
    ushort* xb    = (ushort*)(ws + oXb);
    ushort* W1t   = (ushort*)(ws + oW1t);
    ushort* W2t   = (ushort*)(ws + oW2t);
    int*    src2  = (int*)(ws + oSrc2);
    int*    dst2  = (int*)(ws + oDst2);
    int*    mask2 = (int*)(ws + oMask2);
    int*    csr   = (int*)(ws + oCsr);
    int*    row   = (int*)(ws + oRow);
    int*    cur   = (int*)(ws + oCur);
    float*  deg   = (float*)(ws + oDeg);
    float*  dinv  = (float*)(ws + oDinv);
    float*  r     = (float*)(ws + oR);
    float*  score1= (float*)(ws + oScore1);
    unsigned* keyu  = (unsigned*)(ws + oKeyu);
    int*    kept  = (int*)(ws + oKept);
    int*    inv   = (int*)(ws + oInv);
    float*  score2= (float*)(ws + oScore2);
    unsigned* keyu2 = (unsigned*)(ws + oKeyu2);
    int*    kept2 = (int*)(ws + oKept2);
    int*    inv2  = (int*)(ws + oInv2);
    float*  S     = (float*)(ws + oS);
    unsigned* sel  = (unsigned*)(ws + oSel);
    int*    gpart = (int*)(ws + oGpart);
    int*    epart = (int*)(ws + oEpart);
    float*  g     = (float*)(ws + oG);
    float*  Gp    = (float*)(ws + oGp);
    float*  Sp    = (float*)(ws + oSp);

    const int nb1 = cdiv(N1, 1024);     // 20
    const int nb2 = cdiv(K1, 1024);     // 10
    const int nbc = cdiv(K1, CM_ROWS);  // 79
    const int g1x = cdiv(N1, 128), g1y = C1 / 128;   // stat blocks
    const int agg2b = cdiv(K1, 4);      // 2500 stat blocks

    // ================= Stage 1 =================
    f32_to_bf16<<<cdiv(N1 * CIN / 4, 256), 256, 0, stream>>>(x, xb, N1 * CIN / 4);

    fill_i32<<<cdiv(N1, 256), 256, 0, stream>>>(cur, 0, N1);
    count_deg<<<cdiv(NE, 256), 256, 0, stream>>>(dst1, nullptr, NE, cur);
    dp_partial<<<nb1, 256, 0, stream>>>(cur, N1, gpart);
    scan64k<<<1, 64, 0, stream>>>(nb1, gpart, row + N1);
    dp_final<<<nb1, 256, 0, stream>>>(cur, N1, gpart, row, cur, deg, dinv);
    csr_scatter<<<cdiv(NE, 256), 256, 0, stream>>>(src1, dst1, nullptr, NE, cur, csr);

    aggregate_xb<<<cdiv(N1, 4), 256, 0, stream>>>(row, csr, deg, dinv, xb, aggb, N1);

    conv_transpose_bf16<<<cdiv(CIN * C1, 256), 256, 0, stream>>>(W1, W1t, CIN, C1);
    gemm_bf16_mfma<false, true><<<dim3(g1x, g1y), 256, 0, stream>>>(
        aggb, W1t, b1, h1, nullptr, Sp, N1, C1, CIN);
    reduce_final<<<1, 256, 0, stream>>>(Sp, g1x * g1y, S);

    norm_scores<C1><<<cdiv(N1, 4), 256, 0, stream>>>(h1, N1, S, 1.f / ((float)N1 * C1),
                                                     ln1w, ln1b, p1wrel, p1brel, p1wroot, r, score1);
    gather_score_key<<<cdiv(N1, 256), 256, 0, stream>>>(row, csr, r, score1, keyu, N1);

    select_thresh_reg<<<1, 1024, 0, stream>>>(keyu, N1, K1, sel);
    sc_partial<<<nb1, 256, 0, stream>>>(keyu, N1, sel, gpart, epart);
    sc_final<<<nb1, 256, 0, stream>>>(keyu, N1, sel, gpart, epart, kept, inv);

    pool_apply_rows<<<cdiv(N1, 4), 256, 0, stream>>>(h1, score1, kept, inv, N1, S,
                                                     1.f / ((float)N1 * C1), ln1w, ln1b, h1pb);
    edge_relabel<<<cdiv(NE, 256), 256, 0, stream>>>(src1, dst1, NE, kept, inv, src2, dst2, mask2);

    // ================= Stage 2 =================
    conv_transpose_bf16<<<cdiv(C1 * C2, 256), 256, 0, stream>>>(W2, W2t, C1, C2);
    gemm_bf16_mfma<true, false><<<dim3(cdiv(K1, 128), C2 / 128), 256, 0, stream>>>(
        h1pb, W2t, nullptr, nullptr, xW2b, nullptr, K1, C2, C1);

    fill_i32<<<cdiv(K1, 256), 256, 0, stream>>>(cur, 0, K1);
    count_deg<<<cdiv(NE, 256), 256, 0, stream>>>(dst2, mask2, NE, cur);
    dp_partial<<<nb2, 256, 0, stream>>>(cur, K1, gpart);
    scan64k<<<1, 64, 0, stream>>>(nb2, gpart, row + K1);
    dp_final<<<nb2, 256, 0, stream>>>(cur, K1, gpart, row, cur, deg, dinv);
    csr_scatter<<<cdiv(NE, 256), 256, 0, stream>>>(src2, dst2, mask2, NE, cur, csr);

    aggregate_csr_bf<<<agg2b, 256, 0, stream>>>(row, csr, deg, dinv, xW2b, b2, h2, Sp, K1);
    reduce_final<<<1, 256, 0, stream>>>(Sp, agg2b, S);

    norm_scores<C2><<<cdiv(K1, 4), 256, 0, stream>>>(h2, K1, S, 1.f / ((float)K1 * C2),
                                                     ln2w, ln2b, p2wrel, p2brel, p2wroot, r, score2);
    gather_score_key<<<cdiv(K1, 256), 256, 0, stream>>>(row, csr, r, score2, keyu2, K1);

    select_thresh_reg<<<1, 1024, 0, stream>>>(keyu2, K1, K2, sel);
    sc_partial<<<nb2, 256, 0, stream>>>(keyu2, K1, sel, gpart, epart);
    sc_final<<<nb2, 256, 0, stream>>>(keyu2, K1, sel, gpart, epart, kept2, inv2);

    // ================= readout =================
    colmean_part<<<nbc, 256, 0, stream>>>(h2, score2, kept2, K1, S, 1.f / ((float)K1 * C2),
                                          ln2w, ln2b, Gp);
    colmean_final<<<1, 256, 0, stream>>>(Gp, nbc, 1.f / (float)K2, g);
    final_gemv<<<1, NOUT, 0, stream>>>(g, Wf, bf, out);
}